// Round 7
// baseline (199.645 us; speedup 1.0000x reference)
//
#include <hip/hip_runtime.h>
#include <math.h>

#define NQ        14
#define DIM       16384      // 2^14
#define BATCHN    128
#define NGATES    13
#define NGEN      15
#define NOBSN     13
#define DEPTHN    4
#define INDIM     256
#define HIDDIM    256
#define ENCDIM    195
#define TCIRC     1024

// Pauli 2x2 matrices (real, imag parts). Order: I, X, Y, Z.
__constant__ float c_PR[4][2][2] = {
  {{1.f, 0.f}, {0.f, 1.f}},   // I
  {{0.f, 1.f}, {1.f, 0.f}},   // X
  {{0.f, 0.f}, {0.f, 0.f}},   // Y (real part)
  {{1.f, 0.f}, {0.f,-1.f}},   // Z
};
__constant__ float c_PI[4][2][2] = {
  {{0.f, 0.f}, {0.f, 0.f}},
  {{0.f, 0.f}, {0.f, 0.f}},
  {{0.f,-1.f}, {1.f, 0.f}},   // Y (imag part)
  {{0.f, 0.f}, {0.f, 0.f}},
};

// ---------------- encoder: enc = silu(x W1^T + b1) W2^T + b2 ----------------
__global__ void encoder_kernel(const float* __restrict__ x,
                               const float* __restrict__ W1,
                               const float* __restrict__ b1,
                               const float* __restrict__ W2,
                               const float* __restrict__ b2,
                               float* __restrict__ enc) {
  __shared__ float xrow[INDIM];
  __shared__ float hrow[HIDDIM];
  const int b = blockIdx.x, t = threadIdx.x;
  xrow[t] = x[b * INDIM + t];
  __syncthreads();
  float acc = b1[t];
  const float* w = W1 + t * INDIM;
  for (int k = 0; k < INDIM; ++k) acc = fmaf(w[k], xrow[k], acc);
  hrow[t] = acc / (1.f + expf(-acc));       // silu
  __syncthreads();
  if (t < ENCDIM) {
    float a2 = b2[t];
    const float* w2 = W2 + t * HIDDIM;
    for (int k = 0; k < HIDDIM; ++k) a2 = fmaf(w2[k], hrow[k], a2);
    enc[b * ENCDIM + t] = a2;
  }
}

// ---------------- build U = exp(i * sum_g theta_g G_g), one thread each -----
__global__ void build_u_kernel(const float* __restrict__ enc,
                               float2* __restrict__ Umats) {
  const int idx = blockIdx.x * blockDim.x + threadIdx.x;
  if (idx >= BATCHN * NGATES) return;
  const int b = idx / NGATES, g = idx % NGATES;
  const float* th = enc + b * ENCDIM + g * NGEN;

  float Ar[16], Ai[16];
  for (int i = 0; i < 16; ++i) { Ar[i] = 0.f; Ai[i] = 0.f; }
  for (int t = 0; t < NGEN; ++t) {
    const int p = t + 1;
    const int pa = p >> 2, pb = p & 3;
    const float theta = th[t];
    for (int i = 0; i < 4; ++i)
      for (int j = 0; j < 4; ++j) {
        const float ar = c_PR[pa][i >> 1][j >> 1], ai = c_PI[pa][i >> 1][j >> 1];
        const float br = c_PR[pb][i & 1][j & 1],  bi = c_PI[pb][i & 1][j & 1];
        Ar[i * 4 + j] = fmaf(theta, ar * br - ai * bi, Ar[i * 4 + j]);
        Ai[i * 4 + j] = fmaf(theta, ar * bi + ai * br, Ai[i * 4 + j]);
      }
  }

  float nrm = 0.f;
  for (int i = 0; i < 4; ++i) {
    float rs = 0.f;
    for (int j = 0; j < 4; ++j)
      rs += sqrtf(Ar[i * 4 + j] * Ar[i * 4 + j] + Ai[i * 4 + j] * Ai[i * 4 + j]);
    nrm = fmaxf(nrm, rs);
  }
  int sct = 0;
  float scale = 1.f;
  while (nrm * scale > 0.4f && sct < 30) { scale *= 0.5f; ++sct; }

  float Mr[16], Mi[16];
  for (int i = 0; i < 16; ++i) { Mr[i] = -Ai[i] * scale; Mi[i] = Ar[i] * scale; }

  float Rr[16], Ri[16];
  for (int i = 0; i < 16; ++i) { Rr[i] = (i % 5 == 0) ? 1.f : 0.f; Ri[i] = 0.f; }
  for (int k = 12; k >= 1; --k) {
    float Tr[16], Ti[16];
    const float inv = 1.f / (float)k;
    for (int i = 0; i < 4; ++i)
      for (int j = 0; j < 4; ++j) {
        float tr = 0.f, ti = 0.f;
        for (int l = 0; l < 4; ++l) {
          const float mr = Mr[i * 4 + l], mi = Mi[i * 4 + l];
          const float rr = Rr[l * 4 + j], ri = Ri[l * 4 + j];
          tr += mr * rr - mi * ri;
          ti += mr * ri + mi * rr;
        }
        Tr[i * 4 + j] = ((i == j) ? 1.f : 0.f) + inv * tr;
        Ti[i * 4 + j] = inv * ti;
      }
    for (int i = 0; i < 16; ++i) { Rr[i] = Tr[i]; Ri[i] = Ti[i]; }
  }
  for (int it = 0; it < sct; ++it) {
    float Tr[16], Ti[16];
    for (int i = 0; i < 4; ++i)
      for (int j = 0; j < 4; ++j) {
        float tr = 0.f, ti = 0.f;
        for (int l = 0; l < 4; ++l) {
          const float ar = Rr[i * 4 + l], ai = Ri[i * 4 + l];
          const float br = Rr[l * 4 + j], bi = Ri[l * 4 + j];
          tr += ar * br - ai * bi;
          ti += ar * bi + ai * br;
        }
        Tr[i * 4 + j] = tr; Ti[i * 4 + j] = ti;
      }
    for (int i = 0; i < 16; ++i) { Rr[i] = Tr[i]; Ri[i] = Ti[i]; }
  }
  for (int i = 0; i < 16; ++i)
    Umats[idx * 16 + i] = make_float2(Rr[i], Ri[i]);
}

// ============ circuit kernel: 8 amps/thread, 2 chunks/pass, SoA =============
// R6 post-mortem: 16-amp live set (~70+ regs) never fits the immovable 64-VGPR
// budget -> persistent scratch spill. Restructure: every pass works on a 3-bit
// window (8 amps = 16 VGPR) and loops 2 chunks over the state. Worst case
// (staged perm pass) is 32 amp regs with no matrix temps. Zero spill by
// construction.
__device__ __forceinline__ float rfl(float x) {
  return __int_as_float(__builtin_amdgcn_readfirstlane(__float_as_int(x)));
}

// LDS element swizzle, per-bit XOR chosen so that EVERY window W in 0..11,
// with and without the sigma-composed read, is conflict-free (<=2 lanes/bank):
//   bank0 ^= y5; bank1 ^= y6; bank2 ^= y5^y7; bank3 ^= y8; bank4 ^= y7
__device__ __forceinline__ int Ef(int y) {
  const int t = y >> 5;
  int x = (t & 1) * 5;            // y5 -> bits 0,2
  x ^= ((t >> 2) & 1) * 20;       // y7 -> bits 2,4
  x |= (t & 2) | (t & 8);         // y6 -> bit 1, y8 -> bit 3
  return y ^ x;
}
// Composed CNOT-chain permutation: bit b ^= bit b+1 (bits 0..12).
__device__ __forceinline__ int sigf(int y) { return y ^ ((y >> 1) & 8191); }

template<int W, bool PERM>
__device__ __forceinline__ void load8(const float* __restrict__ stR,
                                      const float* __restrict__ stI,
                                      int g, float vr[8], float vi[8]) {
  const int m = (1 << W) - 1;
  const int B = ((g & ~m) << 3) | (g & m);
  #pragma unroll
  for (int k = 0; k < 8; ++k) {
    const int y = B | (k << W);
    const int a = Ef(PERM ? sigf(y) : y);
    vr[k] = stR[a]; vi[k] = stI[a];
  }
}

template<int W>
__device__ __forceinline__ void store8(float* __restrict__ stR,
                                       float* __restrict__ stI,
                                       int g, const float vr[8], const float vi[8]) {
  const int m = (1 << W) - 1;
  const int B = ((g & ~m) << 3) | (g & m);
  #pragma unroll
  for (int k = 0; k < 8; ++k) {
    const int a = Ef(B | (k << W));
    stR[a] = vr[k]; stI[a] = vi[k];
  }
}

// MODE 0 ("mid"):  gate field = k-bits (2,1), spectator = k-bit 0 -> k=(i<<1)|sp
// MODE 1 ("low"):  gate field = k-bits (1,0), spectator = k-bit 2 -> k=(sp<<2)|i
template<int MODE>
__device__ __forceinline__ void apply_g(const float ur[16], const float ui_[16],
                                        float vr[8], float vi[8]) {
  #pragma unroll
  for (int sp = 0; sp < 2; ++sp) {
    float ar[4], ai[4];
    #pragma unroll
    for (int i = 0; i < 4; ++i) {
      float sr = 0.f, si = 0.f;
      #pragma unroll
      for (int l = 0; l < 4; ++l) {
        const int kl = (MODE == 0) ? ((l << 1) | sp) : ((sp << 2) | l);
        sr = fmaf(ur[i * 4 + l], vr[kl], fmaf(-ui_[i * 4 + l], vi[kl], sr));
        si = fmaf(ur[i * 4 + l], vi[kl], fmaf(ui_[i * 4 + l], vr[kl], si));
      }
      ar[i] = sr; ai[i] = si;
    }
    #pragma unroll
    for (int i = 0; i < 4; ++i) {
      const int ki = (MODE == 0) ? ((i << 1) | sp) : ((sp << 2) | i);
      vr[ki] = ar[i]; vi[ki] = ai[i];
    }
  }
}

template<int W, int MODE>
__device__ __forceinline__ void su4_pass(float* stR, float* stI,
                                         const float2* __restrict__ ug, int tid) {
  float ur[16], ui_[16];
  #pragma unroll
  for (int i = 0; i < 16; ++i) { ur[i] = rfl(ug[i].x); ui_[i] = rfl(ug[i].y); }
  #pragma unroll
  for (int c = 0; c < 2; ++c) {
    float vr[8], vi[8];
    const int g = tid + (c << 10);
    load8<W, false>(stR, stI, g, vr, vi);
    apply_g<MODE>(ur, ui_, vr, vi);
    store8<W>(stR, stI, g, vr, vi);
  }
  __syncthreads();
}

template<int J>
__device__ __forceinline__ void ry_bit8(float c, float s, float vr[8], float vi[8]) {
  #pragma unroll
  for (int k = 0; k < 8; ++k) {
    if ((k & (1 << J)) == 0) {
      const int k1 = k | (1 << J);
      const float ar = vr[k], ai = vi[k], br = vr[k1], bi = vi[k1];
      vr[k]  = fmaf(c, ar, -(s * br));
      vi[k]  = fmaf(c, ai, -(s * bi));
      vr[k1] = fmaf(s, ar, c * br);
      vi[k1] = fmaf(s, ai, c * bi);
    }
  }
}

// Non-perm RY pass: window bits (W+NB-1 .. W); angle for k-bit J = rc[13-W-J].
template<int W, int NB>
__device__ __forceinline__ void ry_pass8(float* stR, float* stI,
                                         const float* __restrict__ rc,
                                         const float* __restrict__ rs, int tid) {
  const float c0 = rfl(rc[13 - W]),     s0 = rfl(rs[13 - W]);
  const float c1 = rfl(rc[12 - W]),     s1 = rfl(rs[12 - W]);
  float c2 = 0.f, s2 = 0.f;
  if (NB == 3) { c2 = rfl(rc[11 - W]); s2 = rfl(rs[11 - W]); }
  #pragma unroll
  for (int c = 0; c < 2; ++c) {
    float vr[8], vi[8];
    const int g = tid + (c << 10);
    load8<W, false>(stR, stI, g, vr, vi);
    if (NB == 3) ry_bit8<2>(c2, s2, vr, vi);
    ry_bit8<1>(c1, s1, vr, vi);
    ry_bit8<0>(c0, s0, vr, vi);
    store8<W>(stR, stI, g, vr, vi);
  }
  __syncthreads();
}

// Perm (sigma-folded) RY pass at W=11: reads are scattered across chunks, so
// stage BOTH chunks in regs, barrier (all reads done), then compute + store.
__device__ __forceinline__ void ry_perm_pass(float* stR, float* stI,
                                             const float* __restrict__ rc,
                                             const float* __restrict__ rs, int tid) {
  float vr0[8], vi0[8], vr1[8], vi1[8];
  load8<11, true>(stR, stI, tid,        vr0, vi0);
  load8<11, true>(stR, stI, tid + 1024, vr1, vi1);
  __syncthreads();
  const float c2 = rfl(rc[0]), s2 = rfl(rs[0]);   // bit 13 -> qubit 0
  const float c1 = rfl(rc[1]), s1 = rfl(rs[1]);   // bit 12 -> qubit 1
  const float c0 = rfl(rc[2]), s0 = rfl(rs[2]);   // bit 11 -> qubit 2
  ry_bit8<2>(c2, s2, vr0, vi0); ry_bit8<1>(c1, s1, vr0, vi0); ry_bit8<0>(c0, s0, vr0, vi0);
  store8<11>(stR, stI, tid, vr0, vi0);
  ry_bit8<2>(c2, s2, vr1, vi1); ry_bit8<1>(c1, s1, vr1, vi1); ry_bit8<0>(c0, s0, vr1, vi1);
  store8<11>(stR, stI, tid + 1024, vr1, vi1);
  __syncthreads();
}

// Quadratic form <v|H|v> restricted to the window field.
// MODE 0: field k-bits (2,1);  MODE 1: field k-bits (1,0).
template<int MODE>
__device__ __forceinline__ float qform(const float2* __restrict__ hp,
                                       const float vr[8], const float vi[8]) {
  float hr[16], hi[16];
  #pragma unroll
  for (int i = 0; i < 16; ++i) { hr[i] = rfl(hp[i].x); hi[i] = rfl(hp[i].y); }
  float acc = 0.f;
  #pragma unroll
  for (int sp = 0; sp < 2; ++sp) {
    #pragma unroll
    for (int i = 0; i < 4; ++i) {
      float wr = 0.f, wi = 0.f;
      #pragma unroll
      for (int l = 0; l < 4; ++l) {
        const int kl = (MODE == 0) ? ((l << 1) | sp) : ((sp << 2) | l);
        wr = fmaf(hr[i * 4 + l], vr[kl], fmaf(-hi[i * 4 + l], vi[kl], wr));
        wi = fmaf(hr[i * 4 + l], vi[kl], fmaf(hi[i * 4 + l], vr[kl], wi));
      }
      const int ki = (MODE == 0) ? ((i << 1) | sp) : ((sp << 2) | i);
      acc = fmaf(vr[ki], wr, fmaf(vi[ki], wi, acc));
    }
  }
  return acc;
}

__device__ __forceinline__ void reduce_store(float a, float* slot, int lane, int wid) {
  #pragma unroll
  for (int off = 32; off > 0; off >>= 1)
    a += __shfl_down(a, off, 64);
  if (lane == 0) slot[wid] = a;
}

__launch_bounds__(TCIRC)
__global__ void circuit_kernel(const float2* __restrict__ Umats,
                               const float* __restrict__ vp,
                               const float* __restrict__ oA,
                               const float* __restrict__ oB,
                               const float* __restrict__ oD,
                               float* __restrict__ out) {
  __shared__ float stR[DIM];                 // 64 KiB
  __shared__ float stI[DIM];                 // 64 KiB
  __shared__ float2 Ush[NGATES * 16];
  __shared__ float2 Hsh[NOBSN * 16];
  __shared__ float  ryc[DEPTHN * NQ];
  __shared__ float  rys[DEPTHN * NQ];
  __shared__ float  red[NOBSN][TCIRC / 64];

  const int b = blockIdx.x;
  const int tid = threadIdx.x;

  for (int i = tid; i < NGATES * 16; i += TCIRC)
    Ush[i] = Umats[b * NGATES * 16 + i];
  for (int i = tid; i < DEPTHN * NQ; i += TCIRC) {
    const float h = 0.5f * vp[i];
    ryc[i] = cosf(h);
    rys[i] = sinf(h);
  }
  if (tid < NOBSN) {
    const int rr[6] = {1, 2, 2, 3, 3, 3};
    const int cc[6] = {0, 0, 1, 0, 1, 2};
    float2 H[16];
    #pragma unroll
    for (int i = 0; i < 16; ++i) H[i] = make_float2(0.f, 0.f);
    for (int m = 0; m < 6; ++m) {
      const float a = oA[tid * 6 + m], bb = oB[tid * 6 + m];
      H[rr[m] * 4 + cc[m]] = make_float2(a, bb);
      H[cc[m] * 4 + rr[m]] = make_float2(a, -bb);
    }
    H[0]  = make_float2(2.f * oD[tid * 4 + 1], 0.f);
    H[5]  = make_float2(2.f * oD[tid * 4 + 2], 0.f);
    H[10] = make_float2(2.f * oD[tid * 4 + 3], 0.f);
    for (int i = 0; i < 16; ++i) Hsh[tid * 16 + i] = H[i];
  }
  for (int y = tid; y < DIM; y += TCIRC) {
    stR[y] = (y == 0) ? 1.f : 0.f;   // Ef(0)==0
    stI[y] = 0.f;
  }
  __syncthreads();

  // ---- SU(4) brick layer. Gate on start qubit q -> field low bit L = 12-q.
  // Even layer (q even, gate idx q/2), then odd layer (gate idx 7+(q-1)/2).
  su4_pass<11, 0>(stR, stI, Ush + 0 * 16, tid);   // q=0  L=12
  su4_pass< 9, 0>(stR, stI, Ush + 1 * 16, tid);   // q=2  L=10
  su4_pass< 7, 0>(stR, stI, Ush + 2 * 16, tid);   // q=4  L=8
  su4_pass< 5, 0>(stR, stI, Ush + 3 * 16, tid);   // q=6  L=6
  su4_pass< 3, 0>(stR, stI, Ush + 4 * 16, tid);   // q=8  L=4
  su4_pass< 1, 0>(stR, stI, Ush + 5 * 16, tid);   // q=10 L=2
  su4_pass< 0, 1>(stR, stI, Ush + 6 * 16, tid);   // q=12 L=0 (low mode)
  su4_pass<10, 0>(stR, stI, Ush + 7 * 16, tid);   // q=1  L=11
  su4_pass< 8, 0>(stR, stI, Ush + 8 * 16, tid);   // q=3  L=9
  su4_pass< 6, 0>(stR, stI, Ush + 9 * 16, tid);   // q=5  L=7
  su4_pass< 4, 0>(stR, stI, Ush + 10 * 16, tid);  // q=7  L=5
  su4_pass< 2, 0>(stR, stI, Ush + 11 * 16, tid);  // q=9  L=3
  su4_pass< 0, 0>(stR, stI, Ush + 12 * 16, tid);  // q=11 L=1 (mid mode)

  // ---- variational depths; CNOT chain folded into the NEXT depth's first
  // pass (and the obs reads) as the sigma address permutation.
  ry_pass8<11, 3>(stR, stI, ryc, rys, tid);                 // depth 0
  ry_pass8< 8, 3>(stR, stI, ryc, rys, tid);
  ry_pass8< 5, 3>(stR, stI, ryc, rys, tid);
  ry_pass8< 2, 3>(stR, stI, ryc, rys, tid);
  ry_pass8< 0, 2>(stR, stI, ryc, rys, tid);
  #pragma unroll 1
  for (int d = 1; d < DEPTHN; ++d) {
    const float* rc = ryc + d * NQ;
    const float* rs = rys + d * NQ;
    ry_perm_pass(stR, stI, rc, rs, tid);                    // carries perm of d-1
    ry_pass8< 8, 3>(stR, stI, rc, rs, tid);
    ry_pass8< 5, 3>(stR, stI, rc, rs, tid);
    ry_pass8< 2, 3>(stR, stI, rc, rs, tid);
    ry_pass8< 0, 2>(stR, stI, rc, rs, tid);
  }

  // ---- observables (read-only, perm-folded reads of the final state).
  // Pass W covers obs o=11-W (field k-bits 2,1) and o=12-W (field k-bits 1,0).
  const int lane = tid & 63, wid = tid >> 6;
  {
    #define OBS_PASS(W, DOMID)                                              \
      { float vr0[8], vi0[8], vr1[8], vi1[8];                               \
        load8<W, true>(stR, stI, tid,        vr0, vi0);                     \
        load8<W, true>(stR, stI, tid + 1024, vr1, vi1);                     \
        if (DOMID) {                                                        \
          float aM = qform<0>(Hsh + (11 - W) * 16, vr0, vi0)                \
                   + qform<0>(Hsh + (11 - W) * 16, vr1, vi1);               \
          reduce_store(aM, red[11 - W], lane, wid);                         \
        }                                                                   \
        float aL = qform<1>(Hsh + (12 - W) * 16, vr0, vi0)                  \
                 + qform<1>(Hsh + (12 - W) * 16, vr1, vi1);                 \
        reduce_store(aL, red[12 - W], lane, wid); }
    OBS_PASS(11, true)    // o=0, o=1
    OBS_PASS( 9, true)    // o=2, o=3
    OBS_PASS( 7, true)    // o=4, o=5
    OBS_PASS( 5, true)    // o=6, o=7
    OBS_PASS( 3, true)    // o=8, o=9
    OBS_PASS( 1, true)    // o=10, o=11
    OBS_PASS( 0, false)   // o=12
    #undef OBS_PASS
  }
  __syncthreads();
  if (tid < NOBSN) {
    float s = 0.f;
    #pragma unroll
    for (int w = 0; w < TCIRC / 64; ++w) s += red[tid][w];
    out[b * NOBSN + tid] = s;
  }
}

extern "C" void kernel_launch(void* const* d_in, const int* in_sizes, int n_in,
                              void* d_out, int out_size, void* d_ws, size_t ws_size,
                              hipStream_t stream) {
  const float* x  = (const float*)d_in[0];
  const float* W1 = (const float*)d_in[1];
  const float* b1 = (const float*)d_in[2];
  const float* W2 = (const float*)d_in[3];
  const float* b2 = (const float*)d_in[4];
  const float* vp = (const float*)d_in[5];
  const float* oA = (const float*)d_in[6];
  const float* oB = (const float*)d_in[7];
  const float* oD = (const float*)d_in[8];
  float* out = (float*)d_out;

  float* enc = (float*)d_ws;
  const size_t enc_bytes = (size_t)BATCHN * ENCDIM * sizeof(float);
  float2* U = (float2*)((char*)d_ws + ((enc_bytes + 255) & ~(size_t)255));

  encoder_kernel<<<BATCHN, 256, 0, stream>>>(x, W1, b1, W2, b2, enc);
  build_u_kernel<<<(BATCHN * NGATES + 255) / 256, 256, 0, stream>>>(enc, U);
  circuit_kernel<<<BATCHN, TCIRC, 0, stream>>>(U, vp, oA, oB, oD, out);
}

// Round 8
// 169.619 us; speedup vs baseline: 1.1770x; 1.1770x over previous
//
#include <hip/hip_runtime.h>
#include <math.h>

#define NQ        14
#define DIM       16384      // 2^14
#define BATCHN    128
#define NGATES    13
#define NGEN      15
#define NOBSN     13
#define DEPTHN    4
#define INDIM     256
#define HIDDIM    256
#define ENCDIM    195
#define TCIRC     1024

// Pauli 2x2 matrices (real, imag parts). Order: I, X, Y, Z.
__constant__ float c_PR[4][2][2] = {
  {{1.f, 0.f}, {0.f, 1.f}},   // I
  {{0.f, 1.f}, {1.f, 0.f}},   // X
  {{0.f, 0.f}, {0.f, 0.f}},   // Y (real part)
  {{1.f, 0.f}, {0.f,-1.f}},   // Z
};
__constant__ float c_PI[4][2][2] = {
  {{0.f, 0.f}, {0.f, 0.f}},
  {{0.f, 0.f}, {0.f, 0.f}},
  {{0.f,-1.f}, {1.f, 0.f}},   // Y (imag part)
  {{0.f, 0.f}, {0.f, 0.f}},
};

// ---------------- encoder: enc = silu(x W1^T + b1) W2^T + b2 ----------------
__global__ void encoder_kernel(const float* __restrict__ x,
                               const float* __restrict__ W1,
                               const float* __restrict__ b1,
                               const float* __restrict__ W2,
                               const float* __restrict__ b2,
                               float* __restrict__ enc) {
  __shared__ float xrow[INDIM];
  __shared__ float hrow[HIDDIM];
  const int b = blockIdx.x, t = threadIdx.x;
  xrow[t] = x[b * INDIM + t];
  __syncthreads();
  float acc = b1[t];
  const float* w = W1 + t * INDIM;
  for (int k = 0; k < INDIM; ++k) acc = fmaf(w[k], xrow[k], acc);
  hrow[t] = acc / (1.f + expf(-acc));       // silu
  __syncthreads();
  if (t < ENCDIM) {
    float a2 = b2[t];
    const float* w2 = W2 + t * HIDDIM;
    for (int k = 0; k < HIDDIM; ++k) a2 = fmaf(w2[k], hrow[k], a2);
    enc[b * ENCDIM + t] = a2;
  }
}

// ---------------- build U = exp(i * sum_g theta_g G_g), one thread each -----
__global__ void build_u_kernel(const float* __restrict__ enc,
                               float2* __restrict__ Umats) {
  const int idx = blockIdx.x * blockDim.x + threadIdx.x;
  if (idx >= BATCHN * NGATES) return;
  const int b = idx / NGATES, g = idx % NGATES;
  const float* th = enc + b * ENCDIM + g * NGEN;

  float Ar[16], Ai[16];
  for (int i = 0; i < 16; ++i) { Ar[i] = 0.f; Ai[i] = 0.f; }
  for (int t = 0; t < NGEN; ++t) {
    const int p = t + 1;
    const int pa = p >> 2, pb = p & 3;
    const float theta = th[t];
    for (int i = 0; i < 4; ++i)
      for (int j = 0; j < 4; ++j) {
        const float ar = c_PR[pa][i >> 1][j >> 1], ai = c_PI[pa][i >> 1][j >> 1];
        const float br = c_PR[pb][i & 1][j & 1],  bi = c_PI[pb][i & 1][j & 1];
        Ar[i * 4 + j] = fmaf(theta, ar * br - ai * bi, Ar[i * 4 + j]);
        Ai[i * 4 + j] = fmaf(theta, ar * bi + ai * br, Ai[i * 4 + j]);
      }
  }

  float nrm = 0.f;
  for (int i = 0; i < 4; ++i) {
    float rs = 0.f;
    for (int j = 0; j < 4; ++j)
      rs += sqrtf(Ar[i * 4 + j] * Ar[i * 4 + j] + Ai[i * 4 + j] * Ai[i * 4 + j]);
    nrm = fmaxf(nrm, rs);
  }
  int sct = 0;
  float scale = 1.f;
  while (nrm * scale > 0.4f && sct < 30) { scale *= 0.5f; ++sct; }

  float Mr[16], Mi[16];
  for (int i = 0; i < 16; ++i) { Mr[i] = -Ai[i] * scale; Mi[i] = Ar[i] * scale; }

  float Rr[16], Ri[16];
  for (int i = 0; i < 16; ++i) { Rr[i] = (i % 5 == 0) ? 1.f : 0.f; Ri[i] = 0.f; }
  for (int k = 12; k >= 1; --k) {
    float Tr[16], Ti[16];
    const float inv = 1.f / (float)k;
    for (int i = 0; i < 4; ++i)
      for (int j = 0; j < 4; ++j) {
        float tr = 0.f, ti = 0.f;
        for (int l = 0; l < 4; ++l) {
          const float mr = Mr[i * 4 + l], mi = Mi[i * 4 + l];
          const float rr = Rr[l * 4 + j], ri = Ri[l * 4 + j];
          tr += mr * rr - mi * ri;
          ti += mr * ri + mi * rr;
        }
        Tr[i * 4 + j] = ((i == j) ? 1.f : 0.f) + inv * tr;
        Ti[i * 4 + j] = inv * ti;
      }
    for (int i = 0; i < 16; ++i) { Rr[i] = Tr[i]; Ri[i] = Ti[i]; }
  }
  for (int it = 0; it < sct; ++it) {
    float Tr[16], Ti[16];
    for (int i = 0; i < 4; ++i)
      for (int j = 0; j < 4; ++j) {
        float tr = 0.f, ti = 0.f;
        for (int l = 0; l < 4; ++l) {
          const float ar = Rr[i * 4 + l], ai = Ri[i * 4 + l];
          const float br = Rr[l * 4 + j], bi = Ri[l * 4 + j];
          tr += ar * br - ai * bi;
          ti += ar * bi + ai * br;
        }
        Tr[i * 4 + j] = tr; Ti[i * 4 + j] = ti;
      }
    for (int i = 0; i < 16; ++i) { Rr[i] = Tr[i]; Ri[i] = Ti[i]; }
  }
  for (int i = 0; i < 16; ++i)
    Umats[idx * 16 + i] = make_float2(Rr[i], Ri[i]);
}

// ========== circuit kernel: R0 envelope (4 amps/thread) + SoA/swizzle =======
// R7 post-mortem: every >=8-amp structure spills at the immovable 64-VGPR cap
// (scheduler hoists chunk loads pre-regalloc). Only proven-clean envelope is
// R0's: 4 amps/thread, runtime chunk loop, launch_bounds(1024,1) -> VGPR 52,
// FETCH 0.2 MB. This kernel = R0 + SoA state + linear XOR bank swizzle
// (R0's only diagnosed cost was 6.9M conflicts on low-sh passes).
__device__ __forceinline__ float rfl(float x) {
  return __int_as_float(__builtin_amdgcn_readfirstlane(__float_as_int(x)));
}

// Bank swizzle, fully GF(2)-linear: bank bits b0^=y5, b1^=y6, b2^=y5^y7,
// b3^=y7^y8, b4^=y6. Rank-5 (2 lanes/bank = free) verified for all windows
// sh=0..12, sigma-composed reads, and contiguous access.
constexpr int ef_c(int y) {
  return y ^ (((y >> 5) & 1) * 5)      // y5 -> bits 0,2
           ^ (((y >> 6) & 1) * 18)     // y6 -> bits 1,4
           ^ (((y >> 7) & 1) * 12)     // y7 -> bits 2,3
           ^ (((y >> 8) & 1) * 8);     // y8 -> bit 3
}
// Composed CNOT-chain permutation (proven through R1-R7): bit b ^= bit b+1.
constexpr int sig_c(int y) { return y ^ ((y >> 1) & 8191); }

// ---- SU(4) gate pass: window bits (SH+1, SH), 4 amps/thread, 4 chunks ----
template<int SH>
__device__ __forceinline__ void su4_pass(float* __restrict__ stR,
                                         float* __restrict__ stI,
                                         const float2* __restrict__ ug, int tid) {
  float ur[16], ui_[16];
  #pragma unroll
  for (int i = 0; i < 16; ++i) { ur[i] = rfl(ug[i].x); ui_[i] = rfl(ug[i].y); }
  constexpr int m  = (1 << SH) - 1;
  constexpr int e1 = ef_c(1 << SH);
  constexpr int e2 = ef_c(2 << SH);
  constexpr int e3 = e1 ^ e2;
  for (int G = tid; G < DIM / 4; G += TCIRC) {
    const int a0 = ef_c(((G & ~m) << 2) | (G & m));
    const int a1 = a0 ^ e1, a2 = a0 ^ e2, a3 = a0 ^ e3;
    float vr[4], vi[4];
    vr[0] = stR[a0]; vr[1] = stR[a1]; vr[2] = stR[a2]; vr[3] = stR[a3];
    vi[0] = stI[a0]; vi[1] = stI[a1]; vi[2] = stI[a2]; vi[3] = stI[a3];
    float tr[4], ti_[4];
    #pragma unroll
    for (int i = 0; i < 4; ++i) {
      float sr = 0.f, si = 0.f;
      #pragma unroll
      for (int l = 0; l < 4; ++l) {
        sr = fmaf(ur[i * 4 + l], vr[l], fmaf(-ui_[i * 4 + l], vi[l], sr));
        si = fmaf(ur[i * 4 + l], vi[l], fmaf(ui_[i * 4 + l], vr[l], si));
      }
      tr[i] = sr; ti_[i] = si;
    }
    stR[a0] = tr[0]; stR[a1] = tr[1]; stR[a2] = tr[2]; stR[a3] = tr[3];
    stI[a0] = ti_[0]; stI[a1] = ti_[1]; stI[a2] = ti_[2]; stI[a3] = ti_[3];
  }
  __syncthreads();
}

// ---- RY pair pass: qubits (12-SH, 13-SH) on window bits (SH+1, SH) ----
template<int SH>
__device__ __forceinline__ void ry_pass(float* __restrict__ stR,
                                        float* __restrict__ stI,
                                        const float* __restrict__ rc,
                                        const float* __restrict__ rs, int tid) {
  const float c1 = rfl(rc[12 - SH]), s1 = rfl(rs[12 - SH]);   // bit SH+1
  const float c0 = rfl(rc[13 - SH]), s0 = rfl(rs[13 - SH]);   // bit SH
  constexpr int m  = (1 << SH) - 1;
  constexpr int e1 = ef_c(1 << SH);
  constexpr int e2 = ef_c(2 << SH);
  constexpr int e3 = e1 ^ e2;
  for (int G = tid; G < DIM / 4; G += TCIRC) {
    const int a0 = ef_c(((G & ~m) << 2) | (G & m));
    const int a1 = a0 ^ e1, a2 = a0 ^ e2, a3 = a0 ^ e3;
    float vr[4], vi[4];
    vr[0] = stR[a0]; vr[1] = stR[a1]; vr[2] = stR[a2]; vr[3] = stR[a3];
    vi[0] = stI[a0]; vi[1] = stI[a1]; vi[2] = stI[a2]; vi[3] = stI[a3];
    // bit1 butterflies: pairs (0,2),(1,3)
    #pragma unroll
    for (int k = 0; k < 2; ++k) {
      const float ar = vr[k], ai = vi[k], br = vr[k + 2], bi = vi[k + 2];
      vr[k]     = fmaf(c1, ar, -(s1 * br));
      vi[k]     = fmaf(c1, ai, -(s1 * bi));
      vr[k + 2] = fmaf(s1, ar, c1 * br);
      vi[k + 2] = fmaf(s1, ai, c1 * bi);
    }
    // bit0 butterflies: pairs (0,1),(2,3)
    #pragma unroll
    for (int k = 0; k < 4; k += 2) {
      const float ar = vr[k], ai = vi[k], br = vr[k + 1], bi = vi[k + 1];
      vr[k]     = fmaf(c0, ar, -(s0 * br));
      vi[k]     = fmaf(c0, ai, -(s0 * bi));
      vr[k + 1] = fmaf(s0, ar, c0 * br);
      vi[k + 1] = fmaf(s0, ai, c0 * bi);
    }
    stR[a0] = vr[0]; stR[a1] = vr[1]; stR[a2] = vr[2]; stR[a3] = vr[3];
    stI[a0] = vi[0]; stI[a1] = vi[1]; stI[a2] = vi[2]; stI[a3] = vi[3];
  }
  __syncthreads();
}

// ---- CNOT chain as one staged permutation pass (R0-proven shape) ----
__device__ __forceinline__ void perm_pass(float* __restrict__ stR,
                                          float* __restrict__ stI, int tid) {
  const int Es = ef_c(sig_c(tid));
  const int Et = ef_c(tid);
  float pr[16], pi_[16];
  #pragma unroll
  for (int i = 0; i < 16; ++i) {
    const int a = Es ^ ef_c(sig_c(i << 10));   // folds to a constant
    pr[i] = stR[a]; pi_[i] = stI[a];
  }
  __syncthreads();
  #pragma unroll
  for (int i = 0; i < 16; ++i) {
    const int a = Et ^ ef_c(i << 10);          // folds to a constant
    stR[a] = pr[i]; stI[a] = pi_[i];
  }
  __syncthreads();
}

// ---- observable pass (read-only): <v|H|v> on window bits (SH+1, SH) ----
template<int SH>
__device__ __forceinline__ float obs_pass(const float* __restrict__ stR,
                                          const float* __restrict__ stI,
                                          const float2* __restrict__ hp, int tid) {
  float hr[16], hi_[16];
  #pragma unroll
  for (int i = 0; i < 16; ++i) { hr[i] = rfl(hp[i].x); hi_[i] = rfl(hp[i].y); }
  constexpr int m  = (1 << SH) - 1;
  constexpr int e1 = ef_c(1 << SH);
  constexpr int e2 = ef_c(2 << SH);
  constexpr int e3 = e1 ^ e2;
  float acc = 0.f;
  for (int G = tid; G < DIM / 4; G += TCIRC) {
    const int a0 = ef_c(((G & ~m) << 2) | (G & m));
    const int a1 = a0 ^ e1, a2 = a0 ^ e2, a3 = a0 ^ e3;
    float vr[4], vi[4];
    vr[0] = stR[a0]; vr[1] = stR[a1]; vr[2] = stR[a2]; vr[3] = stR[a3];
    vi[0] = stI[a0]; vi[1] = stI[a1]; vi[2] = stI[a2]; vi[3] = stI[a3];
    #pragma unroll
    for (int i = 0; i < 4; ++i) {
      float wr = 0.f, wi = 0.f;
      #pragma unroll
      for (int l = 0; l < 4; ++l) {
        wr = fmaf(hr[i * 4 + l], vr[l], fmaf(-hi_[i * 4 + l], vi[l], wr));
        wi = fmaf(hr[i * 4 + l], vi[l], fmaf(hi_[i * 4 + l], vr[l], wi));
      }
      acc = fmaf(vr[i], wr, fmaf(vi[i], wi, acc));
    }
  }
  return acc;
}

__device__ __forceinline__ void reduce_store(float a, float* slot, int lane, int wid) {
  #pragma unroll
  for (int off = 32; off > 0; off >>= 1)
    a += __shfl_down(a, off, 64);
  if (lane == 0) slot[wid] = a;
}

__launch_bounds__(TCIRC, 1)
__global__ void circuit_kernel(const float2* __restrict__ Umats,
                               const float* __restrict__ vp,
                               const float* __restrict__ oA,
                               const float* __restrict__ oB,
                               const float* __restrict__ oD,
                               float* __restrict__ out) {
  __shared__ float stR[DIM];                 // 64 KiB
  __shared__ float stI[DIM];                 // 64 KiB
  __shared__ float2 Ush[NGATES * 16];
  __shared__ float2 Hsh[NOBSN * 16];
  __shared__ float  ryc[DEPTHN * NQ];
  __shared__ float  rys[DEPTHN * NQ];
  __shared__ float  red[NOBSN][TCIRC / 64];

  const int b = blockIdx.x;
  const int tid = threadIdx.x;

  for (int i = tid; i < NGATES * 16; i += TCIRC)
    Ush[i] = Umats[b * NGATES * 16 + i];
  for (int i = tid; i < DEPTHN * NQ; i += TCIRC) {
    const float h = 0.5f * vp[i];
    ryc[i] = cosf(h);
    rys[i] = sinf(h);
  }
  if (tid < NOBSN) {
    const int rr[6] = {1, 2, 2, 3, 3, 3};
    const int cc[6] = {0, 0, 1, 0, 1, 2};
    float2 H[16];
    #pragma unroll
    for (int i = 0; i < 16; ++i) H[i] = make_float2(0.f, 0.f);
    for (int m = 0; m < 6; ++m) {
      const float a = oA[tid * 6 + m], bb = oB[tid * 6 + m];
      H[rr[m] * 4 + cc[m]] = make_float2(a, bb);
      H[cc[m] * 4 + rr[m]] = make_float2(a, -bb);
    }
    H[0]  = make_float2(2.f * oD[tid * 4 + 1], 0.f);
    H[5]  = make_float2(2.f * oD[tid * 4 + 2], 0.f);
    H[10] = make_float2(2.f * oD[tid * 4 + 3], 0.f);
    for (int i = 0; i < 16; ++i) Hsh[tid * 16 + i] = H[i];
  }
  for (int y = tid; y < DIM; y += TCIRC) {
    stR[y] = (y == 0) ? 1.f : 0.f;   // ef_c(0)==0
    stI[y] = 0.f;
  }
  __syncthreads();

  // ---- SU(4) brick layer: even starts (gates 0-6), then odd (gates 7-12).
  su4_pass<12>(stR, stI, Ush + 0 * 16, tid);   // q=0
  su4_pass<10>(stR, stI, Ush + 1 * 16, tid);   // q=2
  su4_pass< 8>(stR, stI, Ush + 2 * 16, tid);   // q=4
  su4_pass< 6>(stR, stI, Ush + 3 * 16, tid);   // q=6
  su4_pass< 4>(stR, stI, Ush + 4 * 16, tid);   // q=8
  su4_pass< 2>(stR, stI, Ush + 5 * 16, tid);   // q=10
  su4_pass< 0>(stR, stI, Ush + 6 * 16, tid);   // q=12
  su4_pass<11>(stR, stI, Ush + 7 * 16, tid);   // q=1
  su4_pass< 9>(stR, stI, Ush + 8 * 16, tid);   // q=3
  su4_pass< 7>(stR, stI, Ush + 9 * 16, tid);   // q=5
  su4_pass< 5>(stR, stI, Ush + 10 * 16, tid);  // q=7
  su4_pass< 3>(stR, stI, Ush + 11 * 16, tid);  // q=9
  su4_pass< 1>(stR, stI, Ush + 12 * 16, tid);  // q=11

  // ---- variational depths: 7 RY-pair passes + 1 perm pass per depth ----
  #pragma unroll 1
  for (int d = 0; d < DEPTHN; ++d) {
    const float* rc = ryc + d * NQ;
    const float* rs = rys + d * NQ;
    ry_pass<12>(stR, stI, rc, rs, tid);   // qubits 0,1
    ry_pass<10>(stR, stI, rc, rs, tid);   // 2,3
    ry_pass< 8>(stR, stI, rc, rs, tid);   // 4,5
    ry_pass< 6>(stR, stI, rc, rs, tid);   // 6,7
    ry_pass< 4>(stR, stI, rc, rs, tid);   // 8,9
    ry_pass< 2>(stR, stI, rc, rs, tid);   // 10,11
    ry_pass< 0>(stR, stI, rc, rs, tid);   // 12,13
    perm_pass(stR, stI, tid);             // CNOT chain
  }

  // ---- observables (read-only; no barriers between passes) ----
  const int lane = tid & 63, wid = tid >> 6;
  reduce_store(obs_pass<12>(stR, stI, Hsh + 0 * 16, tid), red[0], lane, wid);
  reduce_store(obs_pass<11>(stR, stI, Hsh + 1 * 16, tid), red[1], lane, wid);
  reduce_store(obs_pass<10>(stR, stI, Hsh + 2 * 16, tid), red[2], lane, wid);
  reduce_store(obs_pass< 9>(stR, stI, Hsh + 3 * 16, tid), red[3], lane, wid);
  reduce_store(obs_pass< 8>(stR, stI, Hsh + 4 * 16, tid), red[4], lane, wid);
  reduce_store(obs_pass< 7>(stR, stI, Hsh + 5 * 16, tid), red[5], lane, wid);
  reduce_store(obs_pass< 6>(stR, stI, Hsh + 6 * 16, tid), red[6], lane, wid);
  reduce_store(obs_pass< 5>(stR, stI, Hsh + 7 * 16, tid), red[7], lane, wid);
  reduce_store(obs_pass< 4>(stR, stI, Hsh + 8 * 16, tid), red[8], lane, wid);
  reduce_store(obs_pass< 3>(stR, stI, Hsh + 9 * 16, tid), red[9], lane, wid);
  reduce_store(obs_pass< 2>(stR, stI, Hsh + 10 * 16, tid), red[10], lane, wid);
  reduce_store(obs_pass< 1>(stR, stI, Hsh + 11 * 16, tid), red[11], lane, wid);
  reduce_store(obs_pass< 0>(stR, stI, Hsh + 12 * 16, tid), red[12], lane, wid);

  __syncthreads();
  if (tid < NOBSN) {
    float s = 0.f;
    #pragma unroll
    for (int w = 0; w < TCIRC / 64; ++w) s += red[tid][w];
    out[b * NOBSN + tid] = s;
  }
}

extern "C" void kernel_launch(void* const* d_in, const int* in_sizes, int n_in,
                              void* d_out, int out_size, void* d_ws, size_t ws_size,
                              hipStream_t stream) {
  const float* x  = (const float*)d_in[0];
  const float* W1 = (const float*)d_in[1];
  const float* b1 = (const float*)d_in[2];
  const float* W2 = (const float*)d_in[3];
  const float* b2 = (const float*)d_in[4];
  const float* vp = (const float*)d_in[5];
  const float* oA = (const float*)d_in[6];
  const float* oB = (const float*)d_in[7];
  const float* oD = (const float*)d_in[8];
  float* out = (float*)d_out;

  float* enc = (float*)d_ws;
  const size_t enc_bytes = (size_t)BATCHN * ENCDIM * sizeof(float);
  float2* U = (float2*)((char*)d_ws + ((enc_bytes + 255) & ~(size_t)255));

  encoder_kernel<<<BATCHN, 256, 0, stream>>>(x, W1, b1, W2, b2, enc);
  build_u_kernel<<<(BATCHN * NGATES + 255) / 256, 256, 0, stream>>>(enc, U);
  circuit_kernel<<<BATCHN, TCIRC, 0, stream>>>(U, vp, oA, oB, oD, out);
}

// Round 9
// 133.470 us; speedup vs baseline: 1.4958x; 1.2708x over previous
//
#include <hip/hip_runtime.h>
#include <math.h>

#define NQ        14
#define DIM       16384      // 2^14
#define BATCHN    128
#define NGATES    13
#define NGEN      15
#define NOBSN     13
#define DEPTHN    4
#define INDIM     256
#define HIDDIM    256
#define ENCDIM    195
#define TCIRC     1024

// Pauli 2x2 matrices (real, imag parts). Order: I, X, Y, Z.
__constant__ float c_PR[4][2][2] = {
  {{1.f, 0.f}, {0.f, 1.f}},   // I
  {{0.f, 1.f}, {1.f, 0.f}},   // X
  {{0.f, 0.f}, {0.f, 0.f}},   // Y (real part)
  {{1.f, 0.f}, {0.f,-1.f}},   // Z
};
__constant__ float c_PI[4][2][2] = {
  {{0.f, 0.f}, {0.f, 0.f}},
  {{0.f, 0.f}, {0.f, 0.f}},
  {{0.f,-1.f}, {1.f, 0.f}},   // Y (imag part)
  {{0.f, 0.f}, {0.f, 0.f}},
};

// ---------------- encoder: enc = silu(x W1^T + b1) W2^T + b2 ----------------
__global__ void encoder_kernel(const float* __restrict__ x,
                               const float* __restrict__ W1,
                               const float* __restrict__ b1,
                               const float* __restrict__ W2,
                               const float* __restrict__ b2,
                               float* __restrict__ enc) {
  __shared__ float xrow[INDIM];
  __shared__ float hrow[HIDDIM];
  const int b = blockIdx.x, t = threadIdx.x;
  xrow[t] = x[b * INDIM + t];
  __syncthreads();
  float acc = b1[t];
  const float* w = W1 + t * INDIM;
  for (int k = 0; k < INDIM; ++k) acc = fmaf(w[k], xrow[k], acc);
  hrow[t] = acc / (1.f + expf(-acc));       // silu
  __syncthreads();
  if (t < ENCDIM) {
    float a2 = b2[t];
    const float* w2 = W2 + t * HIDDIM;
    for (int k = 0; k < HIDDIM; ++k) a2 = fmaf(w2[k], hrow[k], a2);
    enc[b * ENCDIM + t] = a2;
  }
}

// ---------------- build U = exp(i * sum_g theta_g G_g), one thread each -----
__global__ void build_u_kernel(const float* __restrict__ enc,
                               float2* __restrict__ Umats) {
  const int idx = blockIdx.x * blockDim.x + threadIdx.x;
  if (idx >= BATCHN * NGATES) return;
  const int b = idx / NGATES, g = idx % NGATES;
  const float* th = enc + b * ENCDIM + g * NGEN;

  float Ar[16], Ai[16];
  for (int i = 0; i < 16; ++i) { Ar[i] = 0.f; Ai[i] = 0.f; }
  for (int t = 0; t < NGEN; ++t) {
    const int p = t + 1;
    const int pa = p >> 2, pb = p & 3;
    const float theta = th[t];
    for (int i = 0; i < 4; ++i)
      for (int j = 0; j < 4; ++j) {
        const float ar = c_PR[pa][i >> 1][j >> 1], ai = c_PI[pa][i >> 1][j >> 1];
        const float br = c_PR[pb][i & 1][j & 1],  bi = c_PI[pb][i & 1][j & 1];
        Ar[i * 4 + j] = fmaf(theta, ar * br - ai * bi, Ar[i * 4 + j]);
        Ai[i * 4 + j] = fmaf(theta, ar * bi + ai * br, Ai[i * 4 + j]);
      }
  }

  float nrm = 0.f;
  for (int i = 0; i < 4; ++i) {
    float rs = 0.f;
    for (int j = 0; j < 4; ++j)
      rs += sqrtf(Ar[i * 4 + j] * Ar[i * 4 + j] + Ai[i * 4 + j] * Ai[i * 4 + j]);
    nrm = fmaxf(nrm, rs);
  }
  int sct = 0;
  float scale = 1.f;
  while (nrm * scale > 0.4f && sct < 30) { scale *= 0.5f; ++sct; }

  float Mr[16], Mi[16];
  for (int i = 0; i < 16; ++i) { Mr[i] = -Ai[i] * scale; Mi[i] = Ar[i] * scale; }

  float Rr[16], Ri[16];
  for (int i = 0; i < 16; ++i) { Rr[i] = (i % 5 == 0) ? 1.f : 0.f; Ri[i] = 0.f; }
  for (int k = 12; k >= 1; --k) {
    float Tr[16], Ti[16];
    const float inv = 1.f / (float)k;
    for (int i = 0; i < 4; ++i)
      for (int j = 0; j < 4; ++j) {
        float tr = 0.f, ti = 0.f;
        for (int l = 0; l < 4; ++l) {
          const float mr = Mr[i * 4 + l], mi = Mi[i * 4 + l];
          const float rr = Rr[l * 4 + j], ri = Ri[l * 4 + j];
          tr += mr * rr - mi * ri;
          ti += mr * ri + mi * rr;
        }
        Tr[i * 4 + j] = ((i == j) ? 1.f : 0.f) + inv * tr;
        Ti[i * 4 + j] = inv * ti;
      }
    for (int i = 0; i < 16; ++i) { Rr[i] = Tr[i]; Ri[i] = Ti[i]; }
  }
  for (int it = 0; it < sct; ++it) {
    float Tr[16], Ti[16];
    for (int i = 0; i < 4; ++i)
      for (int j = 0; j < 4; ++j) {
        float tr = 0.f, ti = 0.f;
        for (int l = 0; l < 4; ++l) {
          const float ar = Rr[i * 4 + l], ai = Ri[i * 4 + l];
          const float br = Rr[l * 4 + j], bi = Ri[l * 4 + j];
          tr += ar * br - ai * bi;
          ti += ar * bi + ai * br;
        }
        Tr[i * 4 + j] = tr; Ti[i * 4 + j] = ti;
      }
    for (int i = 0; i < 16; ++i) { Rr[i] = Tr[i]; Ri[i] = Ti[i]; }
  }
  for (int i = 0; i < 16; ++i)
    Umats[idx * 16 + i] = make_float2(Rr[i], Ri[i]);
}

// ====== circuit kernel: R8 envelope (4 amps/thread, 52 VGPR) + pass fusion ==
// R8 proved: no spill, conflicts ~6us (not binding). Cost = 59 barrier-
// separated passes of LDS+VALU. This round: (1) even SU4 layer -> product-
// state init (state after even layer is a tensor product over 7 pair-vectors);
// (2) RY(q0..3) folded into the perm pass (its 16 staged amps index bits
// 13..10 = qubits 0..3 in-register; gather->scatter with sigma^-1);
// (3) observables paired via 3-bit windows (one 8-amp read serves 2 obs).
__device__ __forceinline__ float rfl(float x) {
  return __int_as_float(__builtin_amdgcn_readfirstlane(__float_as_int(x)));
}

// Bank swizzle (R8-proven): b0^=y5, b1^=y6, b2^=y5^y7, b3^=y7^y8, b4^=y6.
constexpr int ef_c(int y) {
  return y ^ (((y >> 5) & 1) * 5)
           ^ (((y >> 6) & 1) * 18)
           ^ (((y >> 7) & 1) * 12)
           ^ (((y >> 8) & 1) * 8);
}
// CNOT-chain permutation (proven R1-R8): sigma(y) = y ^ ((y>>1)&8191).
// Inverse: suffix-xor fold.
constexpr int siginv_c(int z) {
  int t = z;
  t ^= t >> 1; t ^= t >> 2; t ^= t >> 4; t ^= t >> 8;
  return t & 16383;
}

// ---- SU(4) gate pass (odd layer only now): window bits (SH+1, SH) ----
template<int SH>
__device__ __forceinline__ void su4_pass(float* __restrict__ stR,
                                         float* __restrict__ stI,
                                         const float2* __restrict__ ug, int tid) {
  float ur[16], ui_[16];
  #pragma unroll
  for (int i = 0; i < 16; ++i) { ur[i] = rfl(ug[i].x); ui_[i] = rfl(ug[i].y); }
  constexpr int m  = (1 << SH) - 1;
  constexpr int e1 = ef_c(1 << SH);
  constexpr int e2 = ef_c(2 << SH);
  constexpr int e3 = e1 ^ e2;
  for (int G = tid; G < DIM / 4; G += TCIRC) {
    const int a0 = ef_c(((G & ~m) << 2) | (G & m));
    const int a1 = a0 ^ e1, a2 = a0 ^ e2, a3 = a0 ^ e3;
    float vr[4], vi[4];
    vr[0] = stR[a0]; vr[1] = stR[a1]; vr[2] = stR[a2]; vr[3] = stR[a3];
    vi[0] = stI[a0]; vi[1] = stI[a1]; vi[2] = stI[a2]; vi[3] = stI[a3];
    float tr[4], ti_[4];
    #pragma unroll
    for (int i = 0; i < 4; ++i) {
      float sr = 0.f, si = 0.f;
      #pragma unroll
      for (int l = 0; l < 4; ++l) {
        sr = fmaf(ur[i * 4 + l], vr[l], fmaf(-ui_[i * 4 + l], vi[l], sr));
        si = fmaf(ur[i * 4 + l], vi[l], fmaf(ui_[i * 4 + l], vr[l], si));
      }
      tr[i] = sr; ti_[i] = si;
    }
    stR[a0] = tr[0]; stR[a1] = tr[1]; stR[a2] = tr[2]; stR[a3] = tr[3];
    stI[a0] = ti_[0]; stI[a1] = ti_[1]; stI[a2] = ti_[2]; stI[a3] = ti_[3];
  }
  __syncthreads();
}

// ---- product-state init: replaces init + the 7 even-layer SU4 passes ----
// After even gates on |0..0>: psi_y = prod_m U_m[k_m(y), 0],
// k_m = (y >> (12-2m)) & 3. With y = 4G+k, G = tid + c*1024:
// k_0 = c (wave-uniform), k_1..k_5 from tid bits (hoisted), k_6 = k.
__device__ __forceinline__ void init_product(float* __restrict__ stR,
                                             float* __restrict__ stI,
                                             const float2* __restrict__ Ush,
                                             int tid) {
  const int k1 = (tid >> 8) & 3, k2 = (tid >> 6) & 3, k3 = (tid >> 4) & 3,
            k4 = (tid >> 2) & 3, k5 = tid & 3;
  const float2 f1 = Ush[1 * 16 + k1 * 4], f2 = Ush[2 * 16 + k2 * 4],
               f3 = Ush[3 * 16 + k3 * 4], f4 = Ush[4 * 16 + k4 * 4],
               f5 = Ush[5 * 16 + k5 * 4];
  float hr = f1.x, hi = f1.y, tr, ti;
  tr = hr * f2.x - hi * f2.y; ti = hr * f2.y + hi * f2.x; hr = tr; hi = ti;
  tr = hr * f3.x - hi * f3.y; ti = hr * f3.y + hi * f3.x; hr = tr; hi = ti;
  tr = hr * f4.x - hi * f4.y; ti = hr * f4.y + hi * f4.x; hr = tr; hi = ti;
  tr = hr * f5.x - hi * f5.y; ti = hr * f5.y + hi * f5.x; hr = tr; hi = ti;
  float c6r[4], c6i[4];
  #pragma unroll
  for (int k = 0; k < 4; ++k) {
    c6r[k] = rfl(Ush[6 * 16 + k * 4].x);
    c6i[k] = rfl(Ush[6 * 16 + k * 4].y);
  }
  #pragma unroll
  for (int c = 0; c < 4; ++c) {
    const float f0r = rfl(Ush[0 * 16 + c * 4].x);
    const float f0i = rfl(Ush[0 * 16 + c * 4].y);
    const float gr = hr * f0r - hi * f0i;
    const float gi = hr * f0i + hi * f0r;
    const int G = tid + (c << 10);
    const int a0 = ef_c(G << 2);
    #pragma unroll
    for (int k = 0; k < 4; ++k) {
      const int a = a0 ^ ef_c(k);
      stR[a] = gr * c6r[k] - gi * c6i[k];
      stI[a] = gr * c6i[k] + gi * c6r[k];
    }
  }
  __syncthreads();
}

// ---- RY pair pass: qubits (12-SH, 13-SH) on window bits (SH+1, SH) ----
template<int SH>
__device__ __forceinline__ void ry_pass(float* __restrict__ stR,
                                        float* __restrict__ stI,
                                        const float* __restrict__ rc,
                                        const float* __restrict__ rs, int tid) {
  const float c1 = rfl(rc[12 - SH]), s1 = rfl(rs[12 - SH]);
  const float c0 = rfl(rc[13 - SH]), s0 = rfl(rs[13 - SH]);
  constexpr int m  = (1 << SH) - 1;
  constexpr int e1 = ef_c(1 << SH);
  constexpr int e2 = ef_c(2 << SH);
  constexpr int e3 = e1 ^ e2;
  for (int G = tid; G < DIM / 4; G += TCIRC) {
    const int a0 = ef_c(((G & ~m) << 2) | (G & m));
    const int a1 = a0 ^ e1, a2 = a0 ^ e2, a3 = a0 ^ e3;
    float vr[4], vi[4];
    vr[0] = stR[a0]; vr[1] = stR[a1]; vr[2] = stR[a2]; vr[3] = stR[a3];
    vi[0] = stI[a0]; vi[1] = stI[a1]; vi[2] = stI[a2]; vi[3] = stI[a3];
    #pragma unroll
    for (int k = 0; k < 2; ++k) {
      const float ar = vr[k], ai = vi[k], br = vr[k + 2], bi = vi[k + 2];
      vr[k]     = fmaf(c1, ar, -(s1 * br));
      vi[k]     = fmaf(c1, ai, -(s1 * bi));
      vr[k + 2] = fmaf(s1, ar, c1 * br);
      vi[k + 2] = fmaf(s1, ai, c1 * bi);
    }
    #pragma unroll
    for (int k = 0; k < 4; k += 2) {
      const float ar = vr[k], ai = vi[k], br = vr[k + 1], bi = vi[k + 1];
      vr[k]     = fmaf(c0, ar, -(s0 * br));
      vi[k]     = fmaf(c0, ai, -(s0 * bi));
      vr[k + 1] = fmaf(s0, ar, c0 * br);
      vi[k + 1] = fmaf(s0, ai, c0 * bi);
    }
    stR[a0] = vr[0]; stR[a1] = vr[1]; stR[a2] = vr[2]; stR[a3] = vr[3];
    stI[a0] = vi[0]; stI[a1] = vi[1]; stI[a2] = vi[2]; stI[a3] = vi[3];
  }
  __syncthreads();
}

template<int J>
__device__ __forceinline__ void bfly16(float c, float s, float pr[16], float pi_[16]) {
  #pragma unroll
  for (int i = 0; i < 16; ++i) {
    if ((i & (1 << J)) == 0) {
      const int j = i | (1 << J);
      const float ar = pr[i], ai = pi_[i], br = pr[j], bi = pi_[j];
      pr[i]  = fmaf(c, ar, -(s * br));
      pi_[i] = fmaf(c, ai, -(s * bi));
      pr[j]  = fmaf(s, ar, c * br);
      pi_[j] = fmaf(s, ai, c * bi);
    }
  }
}

// ---- fused RY(q0..3) + CNOT-chain pass ----
// Stage plain set z = tid | i<<10 (z bits 13..10 = i = qubits 0..3 in reg),
// apply 4 butterflies, SCATTER to y = sigma^-1(z): state[y] = A[sigma(y)].
__device__ __forceinline__ void perm_ry_pass(float* __restrict__ stR,
                                             float* __restrict__ stI,
                                             const float* __restrict__ rc,
                                             const float* __restrict__ rs,
                                             int tid) {
  const float c0 = rfl(rc[0]), s0 = rfl(rs[0]);   // qubit 0 -> z bit 13 -> i bit 3
  const float c1 = rfl(rc[1]), s1 = rfl(rs[1]);
  const float c2 = rfl(rc[2]), s2 = rfl(rs[2]);
  const float c3 = rfl(rc[3]), s3 = rfl(rs[3]);
  const int Er = ef_c(tid);
  float pr[16], pi_[16];
  #pragma unroll
  for (int i = 0; i < 16; ++i) {
    const int a = Er ^ ef_c(i << 10);
    pr[i] = stR[a]; pi_[i] = stI[a];
  }
  __syncthreads();
  bfly16<3>(c0, s0, pr, pi_);
  bfly16<2>(c1, s1, pr, pi_);
  bfly16<1>(c2, s2, pr, pi_);
  bfly16<0>(c3, s3, pr, pi_);
  const int Ew = ef_c(siginv_c(tid));
  #pragma unroll
  for (int i = 0; i < 16; ++i) {
    const int a = Ew ^ ef_c(siginv_c(i << 10));
    stR[a] = pr[i]; stI[a] = pi_[i];
  }
  __syncthreads();
}

__device__ __forceinline__ void reduce_store(float a, float* slot, int lane, int wid) {
  #pragma unroll
  for (int off = 32; off > 0; off >>= 1)
    a += __shfl_down(a, off, 64);
  if (lane == 0) slot[wid] = a;
}

// ---- paired observables: 3-bit window (SH+2..SH), one 8-amp read, 2 obs.
// Hermitian-compressed H: diag (real) + upper triangle -> 16 uniforms/obs.
// obsA (o): window bits (SH+2,SH+1), spectator bit SH: amp idx (l<<1)|s.
// obsB (o+1): window bits (SH+1,SH), spectator bit SH+2: amp idx (s<<2)|l.
template<int SH>
__device__ __forceinline__ void obs_pair(const float* __restrict__ stR,
                                         const float* __restrict__ stI,
                                         const float2* __restrict__ hpA,
                                         const float2* __restrict__ hpB,
                                         float* redA, float* redB,
                                         int lane, int wid, int tid) {
  // upper-triangle order: (0,1)(0,2)(0,3)(1,2)(1,3)(2,3)
  const int ui[6] = {0, 0, 0, 1, 1, 2};
  const int uj[6] = {1, 2, 3, 2, 3, 3};
  float dA[4], dB[4], oAr[6], oAi[6], oBr[6], oBi[6];
  #pragma unroll
  for (int i = 0; i < 4; ++i) {
    dA[i] = rfl(hpA[i * 5].x);
    dB[i] = rfl(hpB[i * 5].x);
  }
  #pragma unroll
  for (int u = 0; u < 6; ++u) {
    oAr[u] = rfl(2.f * hpA[ui[u] * 4 + uj[u]].x);
    oAi[u] = rfl(2.f * hpA[ui[u] * 4 + uj[u]].y);
    oBr[u] = rfl(2.f * hpB[ui[u] * 4 + uj[u]].x);
    oBi[u] = rfl(2.f * hpB[ui[u] * 4 + uj[u]].y);
  }
  constexpr int m = (1 << SH) - 1;
  float accA = 0.f, accB = 0.f;
  for (int G = tid; G < DIM / 8; G += TCIRC) {
    const int a0 = ef_c(((G & ~m) << 3) | (G & m));
    float vr[8], vi[8];
    #pragma unroll
    for (int k = 0; k < 8; ++k) {
      const int a = a0 ^ ef_c(k << SH);
      vr[k] = stR[a]; vi[k] = stI[a];
    }
    #pragma unroll
    for (int s = 0; s < 2; ++s) {
      // diagonal terms
      #pragma unroll
      for (int i = 0; i < 4; ++i) {
        const int kA = (i << 1) | s, kB = (s << 2) | i;
        accA = fmaf(dA[i], fmaf(vr[kA], vr[kA], vi[kA] * vi[kA]), accA);
        accB = fmaf(dB[i], fmaf(vr[kB], vr[kB], vi[kB] * vi[kB]), accB);
      }
      // off-diagonal: acc += 2*Re(conj(v_i) H_ij v_j)
      #pragma unroll
      for (int u = 0; u < 6; ++u) {
        const int iA = (ui[u] << 1) | s, jA = (uj[u] << 1) | s;
        float p = fmaf(vr[iA], vr[jA], vi[iA] * vi[jA]);
        float q = fmaf(vr[iA], vi[jA], -(vi[iA] * vr[jA]));
        accA = fmaf(oAr[u], p, fmaf(-oAi[u], q, accA));
        const int iB = (s << 2) | ui[u], jB = (s << 2) | uj[u];
        p = fmaf(vr[iB], vr[jB], vi[iB] * vi[jB]);
        q = fmaf(vr[iB], vi[jB], -(vi[iB] * vr[jB]));
        accB = fmaf(oBr[u], p, fmaf(-oBi[u], q, accB));
      }
    }
  }
  reduce_store(accA, redA, lane, wid);
  reduce_store(accB, redB, lane, wid);
}

// single obs (o=12), window (1,0), 4-amp read (R8 form)
__device__ __forceinline__ float obs_single(const float* __restrict__ stR,
                                            const float* __restrict__ stI,
                                            const float2* __restrict__ hp, int tid) {
  float hr[16], hi_[16];
  #pragma unroll
  for (int i = 0; i < 16; ++i) { hr[i] = rfl(hp[i].x); hi_[i] = rfl(hp[i].y); }
  float acc = 0.f;
  for (int G = tid; G < DIM / 4; G += TCIRC) {
    const int a0 = ef_c(G << 2);
    float vr[4], vi[4];
    #pragma unroll
    for (int k = 0; k < 4; ++k) {
      const int a = a0 ^ ef_c(k);
      vr[k] = stR[a]; vi[k] = stI[a];
    }
    #pragma unroll
    for (int i = 0; i < 4; ++i) {
      float wr = 0.f, wi = 0.f;
      #pragma unroll
      for (int l = 0; l < 4; ++l) {
        wr = fmaf(hr[i * 4 + l], vr[l], fmaf(-hi_[i * 4 + l], vi[l], wr));
        wi = fmaf(hr[i * 4 + l], vi[l], fmaf(hi_[i * 4 + l], vr[l], wi));
      }
      acc = fmaf(vr[i], wr, fmaf(vi[i], wi, acc));
    }
  }
  return acc;
}

__launch_bounds__(TCIRC, 1)
__global__ void circuit_kernel(const float2* __restrict__ Umats,
                               const float* __restrict__ vp,
                               const float* __restrict__ oA,
                               const float* __restrict__ oB,
                               const float* __restrict__ oD,
                               float* __restrict__ out) {
  __shared__ float stR[DIM];                 // 64 KiB
  __shared__ float stI[DIM];                 // 64 KiB
  __shared__ float2 Ush[NGATES * 16];
  __shared__ float2 Hsh[NOBSN * 16];
  __shared__ float  ryc[DEPTHN * NQ];
  __shared__ float  rys[DEPTHN * NQ];
  __shared__ float  red[NOBSN][TCIRC / 64];

  const int b = blockIdx.x;
  const int tid = threadIdx.x;

  for (int i = tid; i < NGATES * 16; i += TCIRC)
    Ush[i] = Umats[b * NGATES * 16 + i];
  for (int i = tid; i < DEPTHN * NQ; i += TCIRC) {
    const float h = 0.5f * vp[i];
    ryc[i] = cosf(h);
    rys[i] = sinf(h);
  }
  if (tid < NOBSN) {
    const int rr[6] = {1, 2, 2, 3, 3, 3};
    const int cc[6] = {0, 0, 1, 0, 1, 2};
    float2 H[16];
    #pragma unroll
    for (int i = 0; i < 16; ++i) H[i] = make_float2(0.f, 0.f);
    for (int m = 0; m < 6; ++m) {
      const float a = oA[tid * 6 + m], bb = oB[tid * 6 + m];
      H[rr[m] * 4 + cc[m]] = make_float2(a, bb);
      H[cc[m] * 4 + rr[m]] = make_float2(a, -bb);
    }
    H[0]  = make_float2(2.f * oD[tid * 4 + 1], 0.f);
    H[5]  = make_float2(2.f * oD[tid * 4 + 2], 0.f);
    H[10] = make_float2(2.f * oD[tid * 4 + 3], 0.f);
    for (int i = 0; i < 16; ++i) Hsh[tid * 16 + i] = H[i];
  }
  __syncthreads();

  // ---- even SU4 layer (gates 0..6) as direct product-state init ----
  init_product(stR, stI, Ush, tid);

  // ---- odd SU4 layer (gates 7..12), q = 1,3,5,7,9,11 -> SH = 12-q ----
  su4_pass<11>(stR, stI, Ush + 7 * 16, tid);
  su4_pass< 9>(stR, stI, Ush + 8 * 16, tid);
  su4_pass< 7>(stR, stI, Ush + 9 * 16, tid);
  su4_pass< 5>(stR, stI, Ush + 10 * 16, tid);
  su4_pass< 3>(stR, stI, Ush + 11 * 16, tid);
  su4_pass< 1>(stR, stI, Ush + 12 * 16, tid);

  // ---- variational depths: 5 RY passes (qubits 4..13) + fused perm+RY(0..3)
  #pragma unroll 1
  for (int d = 0; d < DEPTHN; ++d) {
    const float* rc = ryc + d * NQ;
    const float* rs = rys + d * NQ;
    ry_pass< 8>(stR, stI, rc, rs, tid);   // qubits 4,5
    ry_pass< 6>(stR, stI, rc, rs, tid);   // 6,7
    ry_pass< 4>(stR, stI, rc, rs, tid);   // 8,9
    ry_pass< 2>(stR, stI, rc, rs, tid);   // 10,11
    ry_pass< 0>(stR, stI, rc, rs, tid);   // 12,13
    perm_ry_pass(stR, stI, rc, rs, tid);  // RY(0..3) + CNOT chain
  }

  // ---- observables: 6 paired passes + 1 single (read-only, no barriers) ----
  const int lane = tid & 63, wid = tid >> 6;
  obs_pair<11>(stR, stI, Hsh + 0 * 16, Hsh + 1 * 16, red[0], red[1], lane, wid, tid);
  obs_pair< 9>(stR, stI, Hsh + 2 * 16, Hsh + 3 * 16, red[2], red[3], lane, wid, tid);
  obs_pair< 7>(stR, stI, Hsh + 4 * 16, Hsh + 5 * 16, red[4], red[5], lane, wid, tid);
  obs_pair< 5>(stR, stI, Hsh + 6 * 16, Hsh + 7 * 16, red[6], red[7], lane, wid, tid);
  obs_pair< 3>(stR, stI, Hsh + 8 * 16, Hsh + 9 * 16, red[8], red[9], lane, wid, tid);
  obs_pair< 1>(stR, stI, Hsh + 10 * 16, Hsh + 11 * 16, red[10], red[11], lane, wid, tid);
  reduce_store(obs_single(stR, stI, Hsh + 12 * 16, tid), red[12], lane, wid);

  __syncthreads();
  if (tid < NOBSN) {
    float s = 0.f;
    #pragma unroll
    for (int w = 0; w < TCIRC / 64; ++w) s += red[tid][w];
    out[b * NOBSN + tid] = s;
  }
}

extern "C" void kernel_launch(void* const* d_in, const int* in_sizes, int n_in,
                              void* d_out, int out_size, void* d_ws, size_t ws_size,
                              hipStream_t stream) {
  const float* x  = (const float*)d_in[0];
  const float* W1 = (const float*)d_in[1];
  const float* b1 = (const float*)d_in[2];
  const float* W2 = (const float*)d_in[3];
  const float* b2 = (const float*)d_in[4];
  const float* vp = (const float*)d_in[5];
  const float* oA = (const float*)d_in[6];
  const float* oB = (const float*)d_in[7];
  const float* oD = (const float*)d_in[8];
  float* out = (float*)d_out;

  float* enc = (float*)d_ws;
  const size_t enc_bytes = (size_t)BATCHN * ENCDIM * sizeof(float);
  float2* U = (float2*)((char*)d_ws + ((enc_bytes + 255) & ~(size_t)255));

  encoder_kernel<<<BATCHN, 256, 0, stream>>>(x, W1, b1, W2, b2, enc);
  build_u_kernel<<<(BATCHN * NGATES + 255) / 256, 256, 0, stream>>>(enc, U);
  circuit_kernel<<<BATCHN, TCIRC, 0, stream>>>(U, vp, oA, oB, oD, out);
}

// Round 10
// 118.264 us; speedup vs baseline: 1.6881x; 1.1286x over previous
//
#include <hip/hip_runtime.h>
#include <math.h>

#define NQ        14
#define DIM       16384      // 2^14
#define BATCHN    128
#define NGATES    13
#define NGEN      15
#define NOBSN     13
#define DEPTHN    4
#define INDIM     256
#define HIDDIM    256
#define ENCDIM    195
#define TCIRC     1024

// Pauli 2x2 matrices (real, imag parts). Order: I, X, Y, Z.
__constant__ float c_PR[4][2][2] = {
  {{1.f, 0.f}, {0.f, 1.f}},   // I
  {{0.f, 1.f}, {1.f, 0.f}},   // X
  {{0.f, 0.f}, {0.f, 0.f}},   // Y (real part)
  {{1.f, 0.f}, {0.f,-1.f}},   // Z
};
__constant__ float c_PI[4][2][2] = {
  {{0.f, 0.f}, {0.f, 0.f}},
  {{0.f, 0.f}, {0.f, 0.f}},
  {{0.f,-1.f}, {1.f, 0.f}},   // Y (imag part)
  {{0.f, 0.f}, {0.f, 0.f}},
};

// ---- fused prep: encoder (enc row in LDS) + build 13 U matrices per block --
__global__ void __launch_bounds__(256)
prep_kernel(const float* __restrict__ x,
            const float* __restrict__ W1,
            const float* __restrict__ b1,
            const float* __restrict__ W2,
            const float* __restrict__ b2,
            float2* __restrict__ Umats) {
  __shared__ float xrow[INDIM];
  __shared__ float hrow[HIDDIM];
  __shared__ float encs[ENCDIM];
  const int b = blockIdx.x, t = threadIdx.x;
  xrow[t] = x[b * INDIM + t];
  __syncthreads();
  float acc = b1[t];
  const float* w = W1 + t * INDIM;
  for (int k = 0; k < INDIM; ++k) acc = fmaf(w[k], xrow[k], acc);
  hrow[t] = acc / (1.f + expf(-acc));       // silu
  __syncthreads();
  if (t < ENCDIM) {
    float a2 = b2[t];
    const float* w2 = W2 + t * HIDDIM;
    for (int k = 0; k < HIDDIM; ++k) a2 = fmaf(w2[k], hrow[k], a2);
    encs[t] = a2;
  }
  __syncthreads();

  if (t < NGATES) {
    const float* th = encs + t * NGEN;
    float Ar[16], Ai[16];
    for (int i = 0; i < 16; ++i) { Ar[i] = 0.f; Ai[i] = 0.f; }
    for (int g = 0; g < NGEN; ++g) {
      const int p = g + 1;
      const int pa = p >> 2, pb = p & 3;
      const float theta = th[g];
      for (int i = 0; i < 4; ++i)
        for (int j = 0; j < 4; ++j) {
          const float ar = c_PR[pa][i >> 1][j >> 1], ai = c_PI[pa][i >> 1][j >> 1];
          const float br = c_PR[pb][i & 1][j & 1],  bi = c_PI[pb][i & 1][j & 1];
          Ar[i * 4 + j] = fmaf(theta, ar * br - ai * bi, Ar[i * 4 + j]);
          Ai[i * 4 + j] = fmaf(theta, ar * bi + ai * br, Ai[i * 4 + j]);
        }
    }
    float nrm = 0.f;
    for (int i = 0; i < 4; ++i) {
      float rs = 0.f;
      for (int j = 0; j < 4; ++j)
        rs += sqrtf(Ar[i * 4 + j] * Ar[i * 4 + j] + Ai[i * 4 + j] * Ai[i * 4 + j]);
      nrm = fmaxf(nrm, rs);
    }
    int sct = 0;
    float scale = 1.f;
    while (nrm * scale > 0.5f && sct < 30) { scale *= 0.5f; ++sct; }

    float Mr[16], Mi[16];
    for (int i = 0; i < 16; ++i) { Mr[i] = -Ai[i] * scale; Mi[i] = Ar[i] * scale; }
    float Rr[16], Ri[16];
    for (int i = 0; i < 16; ++i) { Rr[i] = (i % 5 == 0) ? 1.f : 0.f; Ri[i] = 0.f; }
    for (int k = 10; k >= 1; --k) {
      float Tr[16], Ti[16];
      const float inv = 1.f / (float)k;
      for (int i = 0; i < 4; ++i)
        for (int j = 0; j < 4; ++j) {
          float tr = 0.f, ti = 0.f;
          for (int l = 0; l < 4; ++l) {
            const float mr = Mr[i * 4 + l], mi = Mi[i * 4 + l];
            const float rr = Rr[l * 4 + j], ri = Ri[l * 4 + j];
            tr += mr * rr - mi * ri;
            ti += mr * ri + mi * rr;
          }
          Tr[i * 4 + j] = ((i == j) ? 1.f : 0.f) + inv * tr;
          Ti[i * 4 + j] = inv * ti;
        }
      for (int i = 0; i < 16; ++i) { Rr[i] = Tr[i]; Ri[i] = Ti[i]; }
    }
    for (int it = 0; it < sct; ++it) {
      float Tr[16], Ti[16];
      for (int i = 0; i < 4; ++i)
        for (int j = 0; j < 4; ++j) {
          float tr = 0.f, ti = 0.f;
          for (int l = 0; l < 4; ++l) {
            const float ar = Rr[i * 4 + l], ai = Ri[i * 4 + l];
            const float br = Rr[l * 4 + j], bi = Ri[l * 4 + j];
            tr += ar * br - ai * bi;
            ti += ar * bi + ai * br;
          }
          Tr[i * 4 + j] = tr; Ti[i * 4 + j] = ti;
        }
      for (int i = 0; i < 16; ++i) { Rr[i] = Tr[i]; Ri[i] = Ti[i]; }
    }
    for (int i = 0; i < 16; ++i)
      Umats[(b * NGATES + t) * 16 + i] = make_float2(Rr[i], Ri[i]);
  }
}

// ====== circuit kernel: proven envelope + 16-amp fused passes ==============
// R9 proved 16-amp passes with SGPR-uniform matrices fit 64 VGPR (no spill).
// This round: odd SU4 layer 6->3 passes (su4_pair, 4-bit windows); RY 5->3
// passes/depth (ry4 on 4-bit windows). Swizzle gains a y9 term so the new
// windows stay conflict-free (rank-5 verified for every pattern below).
__device__ __forceinline__ float rfl(float x) {
  return __int_as_float(__builtin_amdgcn_readfirstlane(__float_as_int(x)));
}

// Bank swizzle: b0^=y5, b1^=y6^y9, b2^=y5^y7, b3^=y7^y8, b4^=y6.
constexpr int ef_c(int y) {
  return y ^ (((y >> 5) & 1) * 5)
           ^ (((y >> 6) & 1) * 18)
           ^ (((y >> 7) & 1) * 12)
           ^ (((y >> 8) & 1) * 8)
           ^ (((y >> 9) & 1) * 2);
}
// CNOT-chain permutation: sigma(y) = y ^ ((y>>1)&8191); inverse = suffix fold.
constexpr int siginv_c(int z) {
  int t = z;
  t ^= t >> 1; t ^= t >> 2; t ^= t >> 4; t ^= t >> 8;
  return t & 16383;
}

// ---- product-state init: even SU4 layer on |0..0> ----
__device__ __forceinline__ void init_product(float* __restrict__ stR,
                                             float* __restrict__ stI,
                                             const float2* __restrict__ Ush,
                                             int tid) {
  const int k1 = (tid >> 8) & 3, k2 = (tid >> 6) & 3, k3 = (tid >> 4) & 3,
            k4 = (tid >> 2) & 3, k5 = tid & 3;
  const float2 f1 = Ush[1 * 16 + k1 * 4], f2 = Ush[2 * 16 + k2 * 4],
               f3 = Ush[3 * 16 + k3 * 4], f4 = Ush[4 * 16 + k4 * 4],
               f5 = Ush[5 * 16 + k5 * 4];
  float hr = f1.x, hi = f1.y, tr, ti;
  tr = hr * f2.x - hi * f2.y; ti = hr * f2.y + hi * f2.x; hr = tr; hi = ti;
  tr = hr * f3.x - hi * f3.y; ti = hr * f3.y + hi * f3.x; hr = tr; hi = ti;
  tr = hr * f4.x - hi * f4.y; ti = hr * f4.y + hi * f4.x; hr = tr; hi = ti;
  tr = hr * f5.x - hi * f5.y; ti = hr * f5.y + hi * f5.x; hr = tr; hi = ti;
  float c6r[4], c6i[4];
  #pragma unroll
  for (int k = 0; k < 4; ++k) {
    c6r[k] = rfl(Ush[6 * 16 + k * 4].x);
    c6i[k] = rfl(Ush[6 * 16 + k * 4].y);
  }
  #pragma unroll
  for (int c = 0; c < 4; ++c) {
    const float f0r = rfl(Ush[0 * 16 + c * 4].x);
    const float f0i = rfl(Ush[0 * 16 + c * 4].y);
    const float gr = hr * f0r - hi * f0i;
    const float gi = hr * f0i + hi * f0r;
    const int G = tid + (c << 10);
    const int a0 = ef_c(G << 2);
    #pragma unroll
    for (int k = 0; k < 4; ++k) {
      const int a = a0 ^ ef_c(k);
      stR[a] = gr * c6r[k] - gi * c6i[k];
      stI[a] = gr * c6i[k] + gi * c6r[k];
    }
  }
  __syncthreads();
}

// ---- fused SU4 pair pass: gate A on k-bits (3,2), gate B on k-bits (1,0),
// window bits SH..SH+3; DIM/16 == TCIRC so each thread owns one group.
template<int SH>
__device__ __forceinline__ void su4_pair(float* __restrict__ stR,
                                         float* __restrict__ stI,
                                         const float2* __restrict__ ugA,
                                         const float2* __restrict__ ugB,
                                         int tid) {
  constexpr int m = (1 << SH) - 1;
  const int a0 = ef_c(((tid & ~m) << 4) | (tid & m));
  float vr[16], vi[16];
  #pragma unroll
  for (int k = 0; k < 16; ++k) {
    const int a = a0 ^ ef_c(k << SH);
    vr[k] = stR[a]; vi[k] = stI[a];
  }
  {  // gate A (scoped: 32 uniforms live)
    float ur[16], ui_[16];
    #pragma unroll
    for (int i = 0; i < 16; ++i) { ur[i] = rfl(ugA[i].x); ui_[i] = rfl(ugA[i].y); }
    #pragma unroll
    for (int r = 0; r < 4; ++r) {
      float tr[4], ti_[4];
      #pragma unroll
      for (int i = 0; i < 4; ++i) {
        float sr = 0.f, si = 0.f;
        #pragma unroll
        for (int l = 0; l < 4; ++l) {
          const int kl = (l << 2) | r;
          sr = fmaf(ur[i * 4 + l], vr[kl], fmaf(-ui_[i * 4 + l], vi[kl], sr));
          si = fmaf(ur[i * 4 + l], vi[kl], fmaf(ui_[i * 4 + l], vr[kl], si));
        }
        tr[i] = sr; ti_[i] = si;
      }
      #pragma unroll
      for (int i = 0; i < 4; ++i) { vr[(i << 2) | r] = tr[i]; vi[(i << 2) | r] = ti_[i]; }
    }
  }
  {  // gate B
    float ur[16], ui_[16];
    #pragma unroll
    for (int i = 0; i < 16; ++i) { ur[i] = rfl(ugB[i].x); ui_[i] = rfl(ugB[i].y); }
    #pragma unroll
    for (int r = 0; r < 4; ++r) {
      float tr[4], ti_[4];
      #pragma unroll
      for (int i = 0; i < 4; ++i) {
        float sr = 0.f, si = 0.f;
        #pragma unroll
        for (int l = 0; l < 4; ++l) {
          const int kl = (r << 2) | l;
          sr = fmaf(ur[i * 4 + l], vr[kl], fmaf(-ui_[i * 4 + l], vi[kl], sr));
          si = fmaf(ur[i * 4 + l], vi[kl], fmaf(ui_[i * 4 + l], vr[kl], si));
        }
        tr[i] = sr; ti_[i] = si;
      }
      #pragma unroll
      for (int i = 0; i < 4; ++i) { vr[(r << 2) | i] = tr[i]; vi[(r << 2) | i] = ti_[i]; }
    }
  }
  #pragma unroll
  for (int k = 0; k < 16; ++k) {
    const int a = a0 ^ ef_c(k << SH);
    stR[a] = vr[k]; stI[a] = vi[k];
  }
  __syncthreads();
}

template<int J>
__device__ __forceinline__ void bfly16(float c, float s, float pr[16], float pi_[16]) {
  #pragma unroll
  for (int i = 0; i < 16; ++i) {
    if ((i & (1 << J)) == 0) {
      const int j = i | (1 << J);
      const float ar = pr[i], ai = pi_[i], br = pr[j], bi = pi_[j];
      pr[i]  = fmaf(c, ar, -(s * br));
      pi_[i] = fmaf(c, ai, -(s * bi));
      pr[j]  = fmaf(s, ar, c * br);
      pi_[j] = fmaf(s, ai, c * bi);
    }
  }
}

// ---- fused RY pass: 4 qubits on window bits SH..SH+3 (k bit J = qubit 13-SH-J)
template<int SH>
__device__ __forceinline__ void ry4_pass(float* __restrict__ stR,
                                         float* __restrict__ stI,
                                         const float* __restrict__ rc,
                                         const float* __restrict__ rs, int tid) {
  const float c3 = rfl(rc[10 - SH]), s3 = rfl(rs[10 - SH]);
  const float c2 = rfl(rc[11 - SH]), s2 = rfl(rs[11 - SH]);
  const float c1 = rfl(rc[12 - SH]), s1 = rfl(rs[12 - SH]);
  const float c0 = rfl(rc[13 - SH]), s0 = rfl(rs[13 - SH]);
  constexpr int m = (1 << SH) - 1;
  const int a0 = ef_c(((tid & ~m) << 4) | (tid & m));
  float vr[16], vi[16];
  #pragma unroll
  for (int k = 0; k < 16; ++k) {
    const int a = a0 ^ ef_c(k << SH);
    vr[k] = stR[a]; vi[k] = stI[a];
  }
  bfly16<3>(c3, s3, vr, vi);
  bfly16<2>(c2, s2, vr, vi);
  bfly16<1>(c1, s1, vr, vi);
  bfly16<0>(c0, s0, vr, vi);
  #pragma unroll
  for (int k = 0; k < 16; ++k) {
    const int a = a0 ^ ef_c(k << SH);
    stR[a] = vr[k]; stI[a] = vi[k];
  }
  __syncthreads();
}

// ---- RY pair pass at SH=0 (qubits 12,13), 4 amps x 4 chunks ----
__device__ __forceinline__ void ry2_pass(float* __restrict__ stR,
                                         float* __restrict__ stI,
                                         const float* __restrict__ rc,
                                         const float* __restrict__ rs, int tid) {
  const float c1 = rfl(rc[12]), s1 = rfl(rs[12]);
  const float c0 = rfl(rc[13]), s0 = rfl(rs[13]);
  constexpr int e1 = ef_c(1), e2 = ef_c(2), e3 = ef_c(3);
  for (int G = tid; G < DIM / 4; G += TCIRC) {
    const int a0 = ef_c(G << 2);
    const int a1 = a0 ^ e1, a2 = a0 ^ e2, a3 = a0 ^ e3;
    float vr[4], vi[4];
    vr[0] = stR[a0]; vr[1] = stR[a1]; vr[2] = stR[a2]; vr[3] = stR[a3];
    vi[0] = stI[a0]; vi[1] = stI[a1]; vi[2] = stI[a2]; vi[3] = stI[a3];
    #pragma unroll
    for (int k = 0; k < 2; ++k) {
      const float ar = vr[k], ai = vi[k], br = vr[k + 2], bi = vi[k + 2];
      vr[k]     = fmaf(c1, ar, -(s1 * br));
      vi[k]     = fmaf(c1, ai, -(s1 * bi));
      vr[k + 2] = fmaf(s1, ar, c1 * br);
      vi[k + 2] = fmaf(s1, ai, c1 * bi);
    }
    #pragma unroll
    for (int k = 0; k < 4; k += 2) {
      const float ar = vr[k], ai = vi[k], br = vr[k + 1], bi = vi[k + 1];
      vr[k]     = fmaf(c0, ar, -(s0 * br));
      vi[k]     = fmaf(c0, ai, -(s0 * bi));
      vr[k + 1] = fmaf(s0, ar, c0 * br);
      vi[k + 1] = fmaf(s0, ai, c0 * bi);
    }
    stR[a0] = vr[0]; stR[a1] = vr[1]; stR[a2] = vr[2]; stR[a3] = vr[3];
    stI[a0] = vi[0]; stI[a1] = vi[1]; stI[a2] = vi[2]; stI[a3] = vi[3];
  }
  __syncthreads();
}

// ---- fused RY(q0..3) + CNOT-chain pass (R9-proven) ----
__device__ __forceinline__ void perm_ry_pass(float* __restrict__ stR,
                                             float* __restrict__ stI,
                                             const float* __restrict__ rc,
                                             const float* __restrict__ rs,
                                             int tid) {
  const float c0 = rfl(rc[0]), s0 = rfl(rs[0]);
  const float c1 = rfl(rc[1]), s1 = rfl(rs[1]);
  const float c2 = rfl(rc[2]), s2 = rfl(rs[2]);
  const float c3 = rfl(rc[3]), s3 = rfl(rs[3]);
  const int Er = ef_c(tid);
  float pr[16], pi_[16];
  #pragma unroll
  for (int i = 0; i < 16; ++i) {
    const int a = Er ^ ef_c(i << 10);
    pr[i] = stR[a]; pi_[i] = stI[a];
  }
  __syncthreads();
  bfly16<3>(c0, s0, pr, pi_);
  bfly16<2>(c1, s1, pr, pi_);
  bfly16<1>(c2, s2, pr, pi_);
  bfly16<0>(c3, s3, pr, pi_);
  const int Ew = ef_c(siginv_c(tid));
  #pragma unroll
  for (int i = 0; i < 16; ++i) {
    const int a = Ew ^ ef_c(siginv_c(i << 10));
    stR[a] = pr[i]; stI[a] = pi_[i];
  }
  __syncthreads();
}

__device__ __forceinline__ void reduce_store(float a, float* slot, int lane, int wid) {
  #pragma unroll
  for (int off = 32; off > 0; off >>= 1)
    a += __shfl_down(a, off, 64);
  if (lane == 0) slot[wid] = a;
}

// ---- paired observables (R9-proven): 3-bit window, one 8-amp read, 2 obs ----
template<int SH>
__device__ __forceinline__ void obs_pair(const float* __restrict__ stR,
                                         const float* __restrict__ stI,
                                         const float2* __restrict__ hpA,
                                         const float2* __restrict__ hpB,
                                         float* redA, float* redB,
                                         int lane, int wid, int tid) {
  const int ui[6] = {0, 0, 0, 1, 1, 2};
  const int uj[6] = {1, 2, 3, 2, 3, 3};
  float dA[4], dB[4], oAr[6], oAi[6], oBr[6], oBi[6];
  #pragma unroll
  for (int i = 0; i < 4; ++i) {
    dA[i] = rfl(hpA[i * 5].x);
    dB[i] = rfl(hpB[i * 5].x);
  }
  #pragma unroll
  for (int u = 0; u < 6; ++u) {
    oAr[u] = rfl(2.f * hpA[ui[u] * 4 + uj[u]].x);
    oAi[u] = rfl(2.f * hpA[ui[u] * 4 + uj[u]].y);
    oBr[u] = rfl(2.f * hpB[ui[u] * 4 + uj[u]].x);
    oBi[u] = rfl(2.f * hpB[ui[u] * 4 + uj[u]].y);
  }
  constexpr int m = (1 << SH) - 1;
  float accA = 0.f, accB = 0.f;
  for (int G = tid; G < DIM / 8; G += TCIRC) {
    const int a0 = ef_c(((G & ~m) << 3) | (G & m));
    float vr[8], vi[8];
    #pragma unroll
    for (int k = 0; k < 8; ++k) {
      const int a = a0 ^ ef_c(k << SH);
      vr[k] = stR[a]; vi[k] = stI[a];
    }
    #pragma unroll
    for (int s = 0; s < 2; ++s) {
      #pragma unroll
      for (int i = 0; i < 4; ++i) {
        const int kA = (i << 1) | s, kB = (s << 2) | i;
        accA = fmaf(dA[i], fmaf(vr[kA], vr[kA], vi[kA] * vi[kA]), accA);
        accB = fmaf(dB[i], fmaf(vr[kB], vr[kB], vi[kB] * vi[kB]), accB);
      }
      #pragma unroll
      for (int u = 0; u < 6; ++u) {
        const int iA = (ui[u] << 1) | s, jA = (uj[u] << 1) | s;
        float p = fmaf(vr[iA], vr[jA], vi[iA] * vi[jA]);
        float q = fmaf(vr[iA], vi[jA], -(vi[iA] * vr[jA]));
        accA = fmaf(oAr[u], p, fmaf(-oAi[u], q, accA));
        const int iB = (s << 2) | ui[u], jB = (s << 2) | uj[u];
        p = fmaf(vr[iB], vr[jB], vi[iB] * vi[jB]);
        q = fmaf(vr[iB], vi[jB], -(vi[iB] * vr[jB]));
        accB = fmaf(oBr[u], p, fmaf(-oBi[u], q, accB));
      }
    }
  }
  reduce_store(accA, redA, lane, wid);
  reduce_store(accB, redB, lane, wid);
}

__device__ __forceinline__ float obs_single(const float* __restrict__ stR,
                                            const float* __restrict__ stI,
                                            const float2* __restrict__ hp, int tid) {
  float hr[16], hi_[16];
  #pragma unroll
  for (int i = 0; i < 16; ++i) { hr[i] = rfl(hp[i].x); hi_[i] = rfl(hp[i].y); }
  float acc = 0.f;
  for (int G = tid; G < DIM / 4; G += TCIRC) {
    const int a0 = ef_c(G << 2);
    float vr[4], vi[4];
    #pragma unroll
    for (int k = 0; k < 4; ++k) {
      const int a = a0 ^ ef_c(k);
      vr[k] = stR[a]; vi[k] = stI[a];
    }
    #pragma unroll
    for (int i = 0; i < 4; ++i) {
      float wr = 0.f, wi = 0.f;
      #pragma unroll
      for (int l = 0; l < 4; ++l) {
        wr = fmaf(hr[i * 4 + l], vr[l], fmaf(-hi_[i * 4 + l], vi[l], wr));
        wi = fmaf(hr[i * 4 + l], vi[l], fmaf(hi_[i * 4 + l], vr[l], wi));
      }
      acc = fmaf(vr[i], wr, fmaf(vi[i], wi, acc));
    }
  }
  return acc;
}

__launch_bounds__(TCIRC, 1)
__global__ void circuit_kernel(const float2* __restrict__ Umats,
                               const float* __restrict__ vp,
                               const float* __restrict__ oA,
                               const float* __restrict__ oB,
                               const float* __restrict__ oD,
                               float* __restrict__ out) {
  __shared__ float stR[DIM];                 // 64 KiB
  __shared__ float stI[DIM];                 // 64 KiB
  __shared__ float2 Ush[NGATES * 16];
  __shared__ float2 Hsh[NOBSN * 16];
  __shared__ float  ryc[DEPTHN * NQ];
  __shared__ float  rys[DEPTHN * NQ];
  __shared__ float  red[NOBSN][TCIRC / 64];

  const int b = blockIdx.x;
  const int tid = threadIdx.x;

  for (int i = tid; i < NGATES * 16; i += TCIRC)
    Ush[i] = Umats[b * NGATES * 16 + i];
  for (int i = tid; i < DEPTHN * NQ; i += TCIRC) {
    const float h = 0.5f * vp[i];
    ryc[i] = cosf(h);
    rys[i] = sinf(h);
  }
  if (tid < NOBSN) {
    const int rr[6] = {1, 2, 2, 3, 3, 3};
    const int cc[6] = {0, 0, 1, 0, 1, 2};
    float2 H[16];
    #pragma unroll
    for (int i = 0; i < 16; ++i) H[i] = make_float2(0.f, 0.f);
    for (int m = 0; m < 6; ++m) {
      const float a = oA[tid * 6 + m], bb = oB[tid * 6 + m];
      H[rr[m] * 4 + cc[m]] = make_float2(a, bb);
      H[cc[m] * 4 + rr[m]] = make_float2(a, -bb);
    }
    H[0]  = make_float2(2.f * oD[tid * 4 + 1], 0.f);
    H[5]  = make_float2(2.f * oD[tid * 4 + 2], 0.f);
    H[10] = make_float2(2.f * oD[tid * 4 + 3], 0.f);
    for (int i = 0; i < 16; ++i) Hsh[tid * 16 + i] = H[i];
  }
  __syncthreads();

  // ---- even SU4 layer as product-state init ----
  init_product(stR, stI, Ush, tid);

  // ---- odd SU4 layer: 3 fused pair passes ----
  su4_pair<9>(stR, stI, Ush + 7 * 16, Ush + 8 * 16, tid);   // q1 (12,11) + q3 (10,9)
  su4_pair<5>(stR, stI, Ush + 9 * 16, Ush + 10 * 16, tid);  // q5 (8,7)  + q7 (6,5)
  su4_pair<1>(stR, stI, Ush + 11 * 16, Ush + 12 * 16, tid); // q9 (4,3)  + q11 (2,1)

  // ---- variational depths: 3 RY passes + fused perm+RY(0..3) ----
  #pragma unroll 1
  for (int d = 0; d < DEPTHN; ++d) {
    const float* rc = ryc + d * NQ;
    const float* rs = rys + d * NQ;
    ry4_pass<6>(stR, stI, rc, rs, tid);   // qubits 4,5,6,7
    ry4_pass<2>(stR, stI, rc, rs, tid);   // qubits 8,9,10,11
    ry2_pass(stR, stI, rc, rs, tid);      // qubits 12,13
    perm_ry_pass(stR, stI, rc, rs, tid);  // RY(0..3) + CNOT chain
  }

  // ---- observables: 6 paired + 1 single (read-only) ----
  const int lane = tid & 63, wid = tid >> 6;
  obs_pair<11>(stR, stI, Hsh + 0 * 16, Hsh + 1 * 16, red[0], red[1], lane, wid, tid);
  obs_pair< 9>(stR, stI, Hsh + 2 * 16, Hsh + 3 * 16, red[2], red[3], lane, wid, tid);
  obs_pair< 7>(stR, stI, Hsh + 4 * 16, Hsh + 5 * 16, red[4], red[5], lane, wid, tid);
  obs_pair< 5>(stR, stI, Hsh + 6 * 16, Hsh + 7 * 16, red[6], red[7], lane, wid, tid);
  obs_pair< 3>(stR, stI, Hsh + 8 * 16, Hsh + 9 * 16, red[8], red[9], lane, wid, tid);
  obs_pair< 1>(stR, stI, Hsh + 10 * 16, Hsh + 11 * 16, red[10], red[11], lane, wid, tid);
  reduce_store(obs_single(stR, stI, Hsh + 12 * 16, tid), red[12], lane, wid);

  __syncthreads();
  if (tid < NOBSN) {
    float s = 0.f;
    #pragma unroll
    for (int w = 0; w < TCIRC / 64; ++w) s += red[tid][w];
    out[b * NOBSN + tid] = s;
  }
}

extern "C" void kernel_launch(void* const* d_in, const int* in_sizes, int n_in,
                              void* d_out, int out_size, void* d_ws, size_t ws_size,
                              hipStream_t stream) {
  const float* x  = (const float*)d_in[0];
  const float* W1 = (const float*)d_in[1];
  const float* b1 = (const float*)d_in[2];
  const float* W2 = (const float*)d_in[3];
  const float* b2 = (const float*)d_in[4];
  const float* vp = (const float*)d_in[5];
  const float* oA = (const float*)d_in[6];
  const float* oB = (const float*)d_in[7];
  const float* oD = (const float*)d_in[8];
  float* out = (float*)d_out;

  float2* U = (float2*)d_ws;

  prep_kernel<<<BATCHN, 256, 0, stream>>>(x, W1, b1, W2, b2, U);
  circuit_kernel<<<BATCHN, TCIRC, 0, stream>>>(U, vp, oA, oB, oD, out);
}

// Round 11
// 100.384 us; speedup vs baseline: 1.9888x; 1.1781x over previous
//
#include <hip/hip_runtime.h>
#include <math.h>

#define NQ        14
#define DIM       16384      // 2^14
#define BATCHN    128
#define NGATES    13
#define NGEN      15
#define NOBSN     13
#define DEPTHN    4
#define INDIM     256
#define HIDDIM    256
#define ENCDIM    195
#define TCIRC     1024

// Pauli 2x2 matrices (real, imag parts). Order: I, X, Y, Z.
__constant__ float c_PR[4][2][2] = {
  {{1.f, 0.f}, {0.f, 1.f}},   // I
  {{0.f, 1.f}, {1.f, 0.f}},   // X
  {{0.f, 0.f}, {0.f, 0.f}},   // Y (real part)
  {{1.f, 0.f}, {0.f,-1.f}},   // Z
};
__constant__ float c_PI[4][2][2] = {
  {{0.f, 0.f}, {0.f, 0.f}},
  {{0.f, 0.f}, {0.f, 0.f}},
  {{0.f,-1.f}, {1.f, 0.f}},   // Y (imag part)
  {{0.f, 0.f}, {0.f, 0.f}},
};

__device__ __forceinline__ float rfl(float x) {
  return __int_as_float(__builtin_amdgcn_readfirstlane(__float_as_int(x)));
}

// Bank swizzle (R10-proven): b0^=y5, b1^=y6^y9, b2^=y5^y7, b3^=y7^y8, b4^=y6.
constexpr int ef_c(int y) {
  return y ^ (((y >> 5) & 1) * 5)
           ^ (((y >> 6) & 1) * 18)
           ^ (((y >> 7) & 1) * 12)
           ^ (((y >> 8) & 1) * 8)
           ^ (((y >> 9) & 1) * 2);
}
// CNOT-chain permutation: sigma(y) = y ^ ((y>>1)&8191); inverse = suffix fold.
constexpr int siginv_c(int z) {
  int t = z;
  t ^= t >> 1; t ^= t >> 2; t ^= t >> 4; t ^= t >> 8;
  return t & 16383;
}

// ---- wave-local product-state init: even SU4 layer on |0..0> ----
// Wave w owns amps y with y>>10 == w (ef only permutes bits 0..4).
__device__ __forceinline__ void init_productW(float* __restrict__ stR,
                                              float* __restrict__ stI,
                                              const float2* __restrict__ Ush,
                                              int tid) {
  const int w = tid >> 6, l = tid & 63;
  const int k0 = w >> 2, k1 = w & 3;
  const int k2 = l >> 4, k3 = (l >> 2) & 3, k4 = l & 3;
  const float f0r = rfl(Ush[0 * 16 + k0 * 4].x), f0i = rfl(Ush[0 * 16 + k0 * 4].y);
  const float f1r = rfl(Ush[1 * 16 + k1 * 4].x), f1i = rfl(Ush[1 * 16 + k1 * 4].y);
  const float2 f2 = Ush[2 * 16 + k2 * 4];
  const float2 f3 = Ush[3 * 16 + k3 * 4];
  const float2 f4 = Ush[4 * 16 + k4 * 4];
  float hr = f0r * f1r - f0i * f1i, hi = f0r * f1i + f0i * f1r, tr, ti;
  tr = hr * f2.x - hi * f2.y; ti = hr * f2.y + hi * f2.x; hr = tr; hi = ti;
  tr = hr * f3.x - hi * f3.y; ti = hr * f3.y + hi * f3.x; hr = tr; hi = ti;
  tr = hr * f4.x - hi * f4.y; ti = hr * f4.y + hi * f4.x; hr = tr; hi = ti;
  float c5r[4], c5i[4], c6r[4], c6i[4];
  #pragma unroll
  for (int m = 0; m < 4; ++m) {
    c5r[m] = rfl(Ush[5 * 16 + m * 4].x); c5i[m] = rfl(Ush[5 * 16 + m * 4].y);
    c6r[m] = rfl(Ush[6 * 16 + m * 4].x); c6i[m] = rfl(Ush[6 * 16 + m * 4].y);
  }
  const int a0 = ef_c((w << 10) | (l << 4));
  #pragma unroll
  for (int k = 0; k < 16; ++k) {
    const float pr = c5r[k >> 2] * c6r[k & 3] - c5i[k >> 2] * c6i[k & 3];
    const float pi_ = c5r[k >> 2] * c6i[k & 3] + c5i[k >> 2] * c6r[k & 3];
    const int a = a0 ^ ef_c(k);
    stR[a] = hr * pr - hi * pi_;
    stI[a] = hr * pi_ + hi * pr;
  }
}

// ---- common gate-pair body on 16 in-register amps ----
__device__ __forceinline__ void gate_pair16(const float2* __restrict__ ugA,
                                            const float2* __restrict__ ugB,
                                            float vr[16], float vi[16]) {
  {  // gate A on k-bits (3,2)
    float ur[16], ui_[16];
    #pragma unroll
    for (int i = 0; i < 16; ++i) { ur[i] = rfl(ugA[i].x); ui_[i] = rfl(ugA[i].y); }
    #pragma unroll
    for (int r = 0; r < 4; ++r) {
      float tr[4], ti_[4];
      #pragma unroll
      for (int i = 0; i < 4; ++i) {
        float sr = 0.f, si = 0.f;
        #pragma unroll
        for (int l = 0; l < 4; ++l) {
          const int kl = (l << 2) | r;
          sr = fmaf(ur[i * 4 + l], vr[kl], fmaf(-ui_[i * 4 + l], vi[kl], sr));
          si = fmaf(ur[i * 4 + l], vi[kl], fmaf(ui_[i * 4 + l], vr[kl], si));
        }
        tr[i] = sr; ti_[i] = si;
      }
      #pragma unroll
      for (int i = 0; i < 4; ++i) { vr[(i << 2) | r] = tr[i]; vi[(i << 2) | r] = ti_[i]; }
    }
  }
  {  // gate B on k-bits (1,0)
    float ur[16], ui_[16];
    #pragma unroll
    for (int i = 0; i < 16; ++i) { ur[i] = rfl(ugB[i].x); ui_[i] = rfl(ugB[i].y); }
    #pragma unroll
    for (int r = 0; r < 4; ++r) {
      float tr[4], ti_[4];
      #pragma unroll
      for (int i = 0; i < 4; ++i) {
        float sr = 0.f, si = 0.f;
        #pragma unroll
        for (int l = 0; l < 4; ++l) {
          const int kl = (r << 2) | l;
          sr = fmaf(ur[i * 4 + l], vr[kl], fmaf(-ui_[i * 4 + l], vi[kl], sr));
          si = fmaf(ur[i * 4 + l], vi[kl], fmaf(ui_[i * 4 + l], vr[kl], si));
        }
        tr[i] = sr; ti_[i] = si;
      }
      #pragma unroll
      for (int i = 0; i < 4; ++i) { vr[(r << 2) | i] = tr[i]; vi[(r << 2) | i] = ti_[i]; }
    }
  }
}

// ---- cross-wave SU4 pair pass (window bits 12..9): full-space, barriered ----
template<int SH>
__device__ __forceinline__ void su4_pair(float* __restrict__ stR,
                                         float* __restrict__ stI,
                                         const float2* __restrict__ ugA,
                                         const float2* __restrict__ ugB,
                                         int tid) {
  constexpr int m = (1 << SH) - 1;
  const int a0 = ef_c(((tid & ~m) << 4) | (tid & m));
  float vr[16], vi[16];
  #pragma unroll
  for (int k = 0; k < 16; ++k) {
    const int a = a0 ^ ef_c(k << SH);
    vr[k] = stR[a]; vi[k] = stI[a];
  }
  gate_pair16(ugA, ugB, vr, vi);
  #pragma unroll
  for (int k = 0; k < 16; ++k) {
    const int a = a0 ^ ef_c(k << SH);
    stR[a] = vr[k]; stI[a] = vi[k];
  }
  __syncthreads();
}

// ---- WAVE-LOCAL SU4 pair pass (SH+4 <= 10): NO barrier ----
template<int SH>
__device__ __forceinline__ void su4_pairW(float* __restrict__ stR,
                                          float* __restrict__ stI,
                                          const float2* __restrict__ ugA,
                                          const float2* __restrict__ ugB,
                                          int tid) {
  const int w = tid >> 6, l = tid & 63;
  constexpr int m = (1 << SH) - 1;
  const int a0 = ef_c((w << 10) | ((l & ~m) << 4) | (l & m));
  float vr[16], vi[16];
  #pragma unroll
  for (int k = 0; k < 16; ++k) {
    const int a = a0 ^ ef_c(k << SH);
    vr[k] = stR[a]; vi[k] = stI[a];
  }
  gate_pair16(ugA, ugB, vr, vi);
  #pragma unroll
  for (int k = 0; k < 16; ++k) {
    const int a = a0 ^ ef_c(k << SH);
    stR[a] = vr[k]; stI[a] = vi[k];
  }
}

template<int J>
__device__ __forceinline__ void bfly16(float c, float s, float pr[16], float pi_[16]) {
  #pragma unroll
  for (int i = 0; i < 16; ++i) {
    if ((i & (1 << J)) == 0) {
      const int j = i | (1 << J);
      const float ar = pr[i], ai = pi_[i], br = pr[j], bi = pi_[j];
      pr[i]  = fmaf(c, ar, -(s * br));
      pi_[i] = fmaf(c, ai, -(s * bi));
      pr[j]  = fmaf(s, ar, c * br);
      pi_[j] = fmaf(s, ai, c * bi);
    }
  }
}

// ---- WAVE-LOCAL 4-qubit RY pass (SH in {6,2}): NO barrier ----
template<int SH>
__device__ __forceinline__ void ry4W(float* __restrict__ stR,
                                     float* __restrict__ stI,
                                     const float* __restrict__ rc,
                                     const float* __restrict__ rs, int tid) {
  const float c3 = rfl(rc[10 - SH]), s3 = rfl(rs[10 - SH]);
  const float c2 = rfl(rc[11 - SH]), s2 = rfl(rs[11 - SH]);
  const float c1 = rfl(rc[12 - SH]), s1 = rfl(rs[12 - SH]);
  const float c0 = rfl(rc[13 - SH]), s0 = rfl(rs[13 - SH]);
  const int w = tid >> 6, l = tid & 63;
  constexpr int m = (1 << SH) - 1;
  const int a0 = ef_c((w << 10) | ((l & ~m) << 4) | (l & m));
  float vr[16], vi[16];
  #pragma unroll
  for (int k = 0; k < 16; ++k) {
    const int a = a0 ^ ef_c(k << SH);
    vr[k] = stR[a]; vi[k] = stI[a];
  }
  bfly16<3>(c3, s3, vr, vi);
  bfly16<2>(c2, s2, vr, vi);
  bfly16<1>(c1, s1, vr, vi);
  bfly16<0>(c0, s0, vr, vi);
  #pragma unroll
  for (int k = 0; k < 16; ++k) {
    const int a = a0 ^ ef_c(k << SH);
    stR[a] = vr[k]; stI[a] = vi[k];
  }
}

// ---- WAVE-LOCAL RY pass for qubits 12,13 (bits 1,0): NO barrier ----
__device__ __forceinline__ void ry2W(float* __restrict__ stR,
                                     float* __restrict__ stI,
                                     const float* __restrict__ rc,
                                     const float* __restrict__ rs, int tid) {
  const float c1 = rfl(rc[12]), s1 = rfl(rs[12]);
  const float c0 = rfl(rc[13]), s0 = rfl(rs[13]);
  const int w = tid >> 6, l = tid & 63;
  #pragma unroll
  for (int j = 0; j < 4; ++j) {
    const int a0 = ef_c((w << 10) | ((l + (j << 6)) << 2));
    const int a1 = a0 ^ ef_c(1), a2 = a0 ^ ef_c(2), a3 = a0 ^ ef_c(3);
    float vr[4], vi[4];
    vr[0] = stR[a0]; vr[1] = stR[a1]; vr[2] = stR[a2]; vr[3] = stR[a3];
    vi[0] = stI[a0]; vi[1] = stI[a1]; vi[2] = stI[a2]; vi[3] = stI[a3];
    #pragma unroll
    for (int k = 0; k < 2; ++k) {
      const float ar = vr[k], ai = vi[k], br = vr[k + 2], bi = vi[k + 2];
      vr[k]     = fmaf(c1, ar, -(s1 * br));
      vi[k]     = fmaf(c1, ai, -(s1 * bi));
      vr[k + 2] = fmaf(s1, ar, c1 * br);
      vi[k + 2] = fmaf(s1, ai, c1 * bi);
    }
    #pragma unroll
    for (int k = 0; k < 4; k += 2) {
      const float ar = vr[k], ai = vi[k], br = vr[k + 1], bi = vi[k + 1];
      vr[k]     = fmaf(c0, ar, -(s0 * br));
      vi[k]     = fmaf(c0, ai, -(s0 * bi));
      vr[k + 1] = fmaf(s0, ar, c0 * br);
      vi[k + 1] = fmaf(s0, ai, c0 * bi);
    }
    stR[a0] = vr[0]; stR[a1] = vr[1]; stR[a2] = vr[2]; stR[a3] = vr[3];
    stI[a0] = vi[0]; stI[a1] = vi[1]; stI[a2] = vi[2]; stI[a3] = vi[3];
  }
}

// ---- fused RY(q0..3) + CNOT-chain pass (cross-wave; 3 barriers) ----
__device__ __forceinline__ void perm_ry_pass(float* __restrict__ stR,
                                             float* __restrict__ stI,
                                             const float* __restrict__ rc,
                                             const float* __restrict__ rs,
                                             int tid) {
  const float c0 = rfl(rc[0]), s0 = rfl(rs[0]);
  const float c1 = rfl(rc[1]), s1 = rfl(rs[1]);
  const float c2 = rfl(rc[2]), s2 = rfl(rs[2]);
  const float c3 = rfl(rc[3]), s3 = rfl(rs[3]);
  __syncthreads();   // wave-local writers from prior passes must land
  const int Er = ef_c(tid);
  float pr[16], pi_[16];
  #pragma unroll
  for (int i = 0; i < 16; ++i) {
    const int a = Er ^ ef_c(i << 10);
    pr[i] = stR[a]; pi_[i] = stI[a];
  }
  __syncthreads();
  bfly16<3>(c0, s0, pr, pi_);
  bfly16<2>(c1, s1, pr, pi_);
  bfly16<1>(c2, s2, pr, pi_);
  bfly16<0>(c3, s3, pr, pi_);
  const int Ew = ef_c(siginv_c(tid));
  #pragma unroll
  for (int i = 0; i < 16; ++i) {
    const int a = Ew ^ ef_c(siginv_c(i << 10));
    stR[a] = pr[i]; stI[a] = pi_[i];
  }
  __syncthreads();
}

__device__ __forceinline__ void reduce_store(float a, float* slot, int lane, int wid) {
  #pragma unroll
  for (int off = 32; off > 0; off >>= 1)
    a += __shfl_down(a, off, 64);
  if (lane == 0) slot[wid] = a;
}

// ---- paired observables (R9/R10-proven) ----
template<int SH>
__device__ __forceinline__ void obs_pair(const float* __restrict__ stR,
                                         const float* __restrict__ stI,
                                         const float2* __restrict__ hpA,
                                         const float2* __restrict__ hpB,
                                         float* redA, float* redB,
                                         int lane, int wid, int tid) {
  const int ui[6] = {0, 0, 0, 1, 1, 2};
  const int uj[6] = {1, 2, 3, 2, 3, 3};
  float dA[4], dB[4], oAr[6], oAi[6], oBr[6], oBi[6];
  #pragma unroll
  for (int i = 0; i < 4; ++i) {
    dA[i] = rfl(hpA[i * 5].x);
    dB[i] = rfl(hpB[i * 5].x);
  }
  #pragma unroll
  for (int u = 0; u < 6; ++u) {
    oAr[u] = rfl(2.f * hpA[ui[u] * 4 + uj[u]].x);
    oAi[u] = rfl(2.f * hpA[ui[u] * 4 + uj[u]].y);
    oBr[u] = rfl(2.f * hpB[ui[u] * 4 + uj[u]].x);
    oBi[u] = rfl(2.f * hpB[ui[u] * 4 + uj[u]].y);
  }
  constexpr int m = (1 << SH) - 1;
  float accA = 0.f, accB = 0.f;
  for (int G = tid; G < DIM / 8; G += TCIRC) {
    const int a0 = ef_c(((G & ~m) << 3) | (G & m));
    float vr[8], vi[8];
    #pragma unroll
    for (int k = 0; k < 8; ++k) {
      const int a = a0 ^ ef_c(k << SH);
      vr[k] = stR[a]; vi[k] = stI[a];
    }
    #pragma unroll
    for (int s = 0; s < 2; ++s) {
      #pragma unroll
      for (int i = 0; i < 4; ++i) {
        const int kA = (i << 1) | s, kB = (s << 2) | i;
        accA = fmaf(dA[i], fmaf(vr[kA], vr[kA], vi[kA] * vi[kA]), accA);
        accB = fmaf(dB[i], fmaf(vr[kB], vr[kB], vi[kB] * vi[kB]), accB);
      }
      #pragma unroll
      for (int u = 0; u < 6; ++u) {
        const int iA = (ui[u] << 1) | s, jA = (uj[u] << 1) | s;
        float p = fmaf(vr[iA], vr[jA], vi[iA] * vi[jA]);
        float q = fmaf(vr[iA], vi[jA], -(vi[iA] * vr[jA]));
        accA = fmaf(oAr[u], p, fmaf(-oAi[u], q, accA));
        const int iB = (s << 2) | ui[u], jB = (s << 2) | uj[u];
        p = fmaf(vr[iB], vr[jB], vi[iB] * vi[jB]);
        q = fmaf(vr[iB], vi[jB], -(vi[iB] * vr[jB]));
        accB = fmaf(oBr[u], p, fmaf(-oBi[u], q, accB));
      }
    }
  }
  reduce_store(accA, redA, lane, wid);
  reduce_store(accB, redB, lane, wid);
}

__device__ __forceinline__ float obs_single(const float* __restrict__ stR,
                                            const float* __restrict__ stI,
                                            const float2* __restrict__ hp, int tid) {
  float hr[16], hi_[16];
  #pragma unroll
  for (int i = 0; i < 16; ++i) { hr[i] = rfl(hp[i].x); hi_[i] = rfl(hp[i].y); }
  float acc = 0.f;
  for (int G = tid; G < DIM / 4; G += TCIRC) {
    const int a0 = ef_c(G << 2);
    float vr[4], vi[4];
    #pragma unroll
    for (int k = 0; k < 4; ++k) {
      const int a = a0 ^ ef_c(k);
      vr[k] = stR[a]; vi[k] = stI[a];
    }
    #pragma unroll
    for (int i = 0; i < 4; ++i) {
      float wr = 0.f, wi = 0.f;
      #pragma unroll
      for (int l = 0; l < 4; ++l) {
        wr = fmaf(hr[i * 4 + l], vr[l], fmaf(-hi_[i * 4 + l], vi[l], wr));
        wi = fmaf(hr[i * 4 + l], vi[l], fmaf(hi_[i * 4 + l], vr[l], wi));
      }
      acc = fmaf(vr[i], wr, fmaf(vi[i], wi, acc));
    }
  }
  return acc;
}

// ====== single fused kernel: encoder + U-build (shfl-parallel) + circuit ====
__launch_bounds__(TCIRC, 1)
__global__ void circuit_kernel(const float* __restrict__ x,
                               const float* __restrict__ W1,
                               const float* __restrict__ b1,
                               const float* __restrict__ W2,
                               const float* __restrict__ b2,
                               const float* __restrict__ vp,
                               const float* __restrict__ oA,
                               const float* __restrict__ oB,
                               const float* __restrict__ oD,
                               float* __restrict__ out) {
  __shared__ float stR[DIM];                 // 64 KiB (head: scratch overlay)
  __shared__ float stI[DIM];                 // 64 KiB
  __shared__ float2 Ush[NGATES * 16];
  __shared__ float2 Hsh[NOBSN * 16];
  __shared__ float  ryc[DEPTHN * NQ];
  __shared__ float  rys[DEPTHN * NQ];
  __shared__ float  red[NOBSN][TCIRC / 64];

  const int b = blockIdx.x;
  const int tid = threadIdx.x;

  // ---- head scratch overlaid on the not-yet-initialized state ----
  float* xrow = stR;          // 256
  float* hrow = stR + 256;    // 256
  float* encs = stR + 512;    // 195
  float* part = stR + 1024;   // 1024

  // trig + observable H on disjoint high threads (independent of encoder)
  if (tid >= 960 && tid < 960 + DEPTHN * NQ) {
    const int i = tid - 960;
    const float h = 0.5f * vp[i];
    ryc[i] = cosf(h); rys[i] = sinf(h);
  }
  if (tid >= 832 && tid < 832 + NOBSN) {
    const int o = tid - 832;
    const int rr[6] = {1, 2, 2, 3, 3, 3};
    const int cc[6] = {0, 0, 1, 0, 1, 2};
    float2 H[16];
    #pragma unroll
    for (int i = 0; i < 16; ++i) H[i] = make_float2(0.f, 0.f);
    for (int m = 0; m < 6; ++m) {
      const float a = oA[o * 6 + m], bb = oB[o * 6 + m];
      H[rr[m] * 4 + cc[m]] = make_float2(a, bb);
      H[cc[m] * 4 + rr[m]] = make_float2(a, -bb);
    }
    H[0]  = make_float2(2.f * oD[o * 4 + 1], 0.f);
    H[5]  = make_float2(2.f * oD[o * 4 + 2], 0.f);
    H[10] = make_float2(2.f * oD[o * 4 + 3], 0.f);
    for (int i = 0; i < 16; ++i) Hsh[o * 16 + i] = H[i];
  }
  if (tid < INDIM) xrow[tid] = x[b * INDIM + tid];
  __syncthreads();

  {  // hrow partials: 4 threads per output
    const int o = tid & 255, q = tid >> 8;
    const float* wp = W1 + o * INDIM + q * 64;
    const float* xq = xrow + q * 64;
    float a = 0.f;
    #pragma unroll 8
    for (int k = 0; k < 64; ++k) a = fmaf(wp[k], xq[k], a);
    part[(q << 8) | o] = a;
  }
  __syncthreads();
  if (tid < HIDDIM) {
    const float a = b1[tid] + part[tid] + part[256 + tid] + part[512 + tid] + part[768 + tid];
    hrow[tid] = a / (1.f + expf(-a));
  }
  __syncthreads();
  {  // enc partials
    const int o = tid & 255, q = tid >> 8;
    if (o < ENCDIM) {
      const float* wp = W2 + o * HIDDIM + q * 64;
      const float* hq = hrow + q * 64;
      float a = 0.f;
      #pragma unroll 8
      for (int k = 0; k < 64; ++k) a = fmaf(wp[k], hq[k], a);
      part[(q << 8) | o] = a;
    }
  }
  __syncthreads();
  if (tid < ENCDIM)
    encs[tid] = b2[tid] + part[tid] + part[256 + tid] + part[512 + tid] + part[768 + tid];
  __syncthreads();

  // ---- U-build: 16 lanes per gate, matmuls via shfl (no barriers inside) ----
  if (tid < NGATES * 16) {
    const int g = tid >> 4, e = tid & 15, i = e >> 2, j = e & 3;
    const float* th = encs + g * NGEN;
    float Are = 0.f, Aie = 0.f;
    for (int t = 0; t < NGEN; ++t) {
      const int p = t + 1;
      const int pa = p >> 2, pb = p & 3;
      const float ar = c_PR[pa][i >> 1][j >> 1], ai = c_PI[pa][i >> 1][j >> 1];
      const float br = c_PR[pb][i & 1][j & 1],  bi = c_PI[pb][i & 1][j & 1];
      Are = fmaf(th[t], ar * br - ai * bi, Are);
      Aie = fmaf(th[t], ar * bi + ai * br, Aie);
    }
    // infinity norm: row sums over j, max over i — all within the 16-lane group
    float r = sqrtf(Are * Are + Aie * Aie);
    r += __shfl_xor(r, 1, 16);
    r += __shfl_xor(r, 2, 16);
    float nrm = r;
    nrm = fmaxf(nrm, __shfl_xor(nrm, 4, 16));
    nrm = fmaxf(nrm, __shfl_xor(nrm, 8, 16));
    int sct = 0;
    float scale = 1.f;
    while (nrm * scale > 0.5f && sct < 30) { scale *= 0.5f; ++sct; }
    const float Mre = -Aie * scale, Mie = Are * scale;   // M = i*A*scale
    float Rr = (i == j) ? 1.f : 0.f, Ri = 0.f;
    for (int k = 10; k >= 1; --k) {
      const float inv = 1.f / (float)k;
      float tr = 0.f, ti = 0.f;
      #pragma unroll
      for (int l = 0; l < 4; ++l) {
        const float mr = __shfl(Mre, i * 4 + l, 16), mi = __shfl(Mie, i * 4 + l, 16);
        const float rr2 = __shfl(Rr, l * 4 + j, 16), ri2 = __shfl(Ri, l * 4 + j, 16);
        tr = fmaf(mr, rr2, fmaf(-mi, ri2, tr));
        ti = fmaf(mr, ri2, fmaf(mi, rr2, ti));
      }
      Rr = ((i == j) ? 1.f : 0.f) + inv * tr;
      Ri = inv * ti;
    }
    for (int it = 0; it < sct; ++it) {
      float tr = 0.f, ti = 0.f;
      #pragma unroll
      for (int l = 0; l < 4; ++l) {
        const float ar = __shfl(Rr, i * 4 + l, 16), ai2 = __shfl(Ri, i * 4 + l, 16);
        const float br = __shfl(Rr, l * 4 + j, 16), bi2 = __shfl(Ri, l * 4 + j, 16);
        tr = fmaf(ar, br, fmaf(-ai2, bi2, tr));
        ti = fmaf(ar, bi2, fmaf(ai2, br, ti));
      }
      Rr = tr; Ri = ti;
    }
    Ush[g * 16 + e] = make_float2(Rr, Ri);
  }
  __syncthreads();

  // ---- even SU4 layer as wave-local product-state init ----
  init_productW(stR, stI, Ush, tid);
  __syncthreads();

  // ---- odd SU4 layer: 1 cross-wave + 2 wave-local passes ----
  su4_pair<9>(stR, stI, Ush + 7 * 16, Ush + 8 * 16, tid);    // q1,q3 (bits 12..9)
  su4_pairW<5>(stR, stI, Ush + 9 * 16, Ush + 10 * 16, tid);  // q5,q7 (bits 8..5)
  su4_pairW<1>(stR, stI, Ush + 11 * 16, Ush + 12 * 16, tid); // q9,q11 (bits 4..1)

  // ---- variational depths: 3 wave-local RY passes + fused perm+RY(0..3) ----
  #pragma unroll 1
  for (int d = 0; d < DEPTHN; ++d) {
    const float* rc = ryc + d * NQ;
    const float* rs = rys + d * NQ;
    ry4W<6>(stR, stI, rc, rs, tid);       // qubits 4..7
    ry4W<2>(stR, stI, rc, rs, tid);       // qubits 8..11
    ry2W(stR, stI, rc, rs, tid);          // qubits 12,13
    perm_ry_pass(stR, stI, rc, rs, tid);  // RY(0..3) + CNOT chain
  }

  // ---- observables: 6 paired + 1 single (read-only) ----
  const int lane = tid & 63, wid = tid >> 6;
  obs_pair<11>(stR, stI, Hsh + 0 * 16, Hsh + 1 * 16, red[0], red[1], lane, wid, tid);
  obs_pair< 9>(stR, stI, Hsh + 2 * 16, Hsh + 3 * 16, red[2], red[3], lane, wid, tid);
  obs_pair< 7>(stR, stI, Hsh + 4 * 16, Hsh + 5 * 16, red[4], red[5], lane, wid, tid);
  obs_pair< 5>(stR, stI, Hsh + 6 * 16, Hsh + 7 * 16, red[6], red[7], lane, wid, tid);
  obs_pair< 3>(stR, stI, Hsh + 8 * 16, Hsh + 9 * 16, red[8], red[9], lane, wid, tid);
  obs_pair< 1>(stR, stI, Hsh + 10 * 16, Hsh + 11 * 16, red[10], red[11], lane, wid, tid);
  reduce_store(obs_single(stR, stI, Hsh + 12 * 16, tid), red[12], lane, wid);

  __syncthreads();
  if (tid < NOBSN) {
    float s = 0.f;
    #pragma unroll
    for (int w = 0; w < TCIRC / 64; ++w) s += red[tid][w];
    out[b * NOBSN + tid] = s;
  }
}

extern "C" void kernel_launch(void* const* d_in, const int* in_sizes, int n_in,
                              void* d_out, int out_size, void* d_ws, size_t ws_size,
                              hipStream_t stream) {
  const float* x  = (const float*)d_in[0];
  const float* W1 = (const float*)d_in[1];
  const float* b1 = (const float*)d_in[2];
  const float* W2 = (const float*)d_in[3];
  const float* b2 = (const float*)d_in[4];
  const float* vp = (const float*)d_in[5];
  const float* oA = (const float*)d_in[6];
  const float* oB = (const float*)d_in[7];
  const float* oD = (const float*)d_in[8];
  float* out = (float*)d_out;

  circuit_kernel<<<BATCHN, TCIRC, 0, stream>>>(x, W1, b1, W2, b2, vp, oA, oB, oD, out);
}

// Round 12
// 80.432 us; speedup vs baseline: 2.4821x; 1.2481x over previous
//
#include <hip/hip_runtime.h>
#include <math.h>

#define NQ        14
#define DIM       16384      // 2^14
#define BATCHN    128
#define NGATES    13
#define NGEN      15
#define NOBSN     13
#define DEPTHN    4
#define INDIM     256
#define HIDDIM    256
#define ENCDIM    195
#define TCIRC     1024

// Pauli 2x2 matrices (real, imag parts). Order: I, X, Y, Z.
__constant__ float c_PR[4][2][2] = {
  {{1.f, 0.f}, {0.f, 1.f}},   // I
  {{0.f, 1.f}, {1.f, 0.f}},   // X
  {{0.f, 0.f}, {0.f, 0.f}},   // Y (real part)
  {{1.f, 0.f}, {0.f,-1.f}},   // Z
};
__constant__ float c_PI[4][2][2] = {
  {{0.f, 0.f}, {0.f, 0.f}},
  {{0.f, 0.f}, {0.f, 0.f}},
  {{0.f,-1.f}, {1.f, 0.f}},   // Y (imag part)
  {{0.f, 0.f}, {0.f, 0.f}},
};

__device__ __forceinline__ float rfl(float x) {
  return __int_as_float(__builtin_amdgcn_readfirstlane(__float_as_int(x)));
}

// Bank swizzle (R10/R11-proven): b0^=y5, b1^=y6^y9, b2^=y5^y7, b3^=y7^y8, b4^=y6.
// At float2 (8B) granularity, rank-4 of E low-4 bits over lane-varying y-bits
// holds for every access pattern below -> minimal 4 lanes/bank-pair for b64.
constexpr int ef_c(int y) {
  return y ^ (((y >> 5) & 1) * 5)
           ^ (((y >> 6) & 1) * 18)
           ^ (((y >> 7) & 1) * 12)
           ^ (((y >> 8) & 1) * 8)
           ^ (((y >> 9) & 1) * 2);
}
// CNOT-chain permutation: sigma(y) = y ^ ((y>>1)&8191); inverse = suffix fold.
constexpr int siginv_c(int z) {
  int t = z;
  t ^= t >> 1; t ^= t >> 2; t ^= t >> 4; t ^= t >> 8;
  return t & 16383;
}
// z bits 13..10 -> final y bits 13..10 under siginv (triangular suffix parity).
constexpr int ymap_c(int i) {
  const int p3 = (i >> 3) & 1;
  const int p2 = p3 ^ ((i >> 2) & 1);
  const int p1 = p2 ^ ((i >> 1) & 1);
  const int p0 = p1 ^ (i & 1);
  return (p3 << 3) | (p2 << 2) | (p1 << 1) | p0;
}
// quadratic-form amp index for a 2-qubit pair inside a 4-bit window:
// MODE 0: pair at k bits (3,2); MODE 1: bits (2,1); MODE 2: bits (1,0).
constexpr int qidx(int MODE, int i, int s) {
  return MODE == 0 ? ((i << 2) | s)
       : MODE == 1 ? (((s >> 1) << 3) | (i << 1) | (s & 1))
       : ((s << 2) | i);
}

// <v|H|v> over 16 amps for one obs; H compressed to diag + upper triangle.
template<int MODE>
__device__ __forceinline__ float qform16(const float2* __restrict__ hp,
                                         const float vr[16], const float vi[16]) {
  const int ui[6] = {0, 0, 0, 1, 1, 2};
  const int uj[6] = {1, 2, 3, 2, 3, 3};
  float dH[4], oR[6], oI[6];
  #pragma unroll
  for (int i = 0; i < 4; ++i) dH[i] = rfl(hp[i * 5].x);
  #pragma unroll
  for (int u = 0; u < 6; ++u) {
    oR[u] = rfl(2.f * hp[ui[u] * 4 + uj[u]].x);
    oI[u] = rfl(2.f * hp[ui[u] * 4 + uj[u]].y);
  }
  float acc = 0.f;
  #pragma unroll
  for (int s = 0; s < 4; ++s) {
    #pragma unroll
    for (int i = 0; i < 4; ++i) {
      const int k = qidx(MODE, i, s);
      acc = fmaf(dH[i], fmaf(vr[k], vr[k], vi[k] * vi[k]), acc);
    }
    #pragma unroll
    for (int u = 0; u < 6; ++u) {
      const int a = qidx(MODE, ui[u], s), b2 = qidx(MODE, uj[u], s);
      const float p = fmaf(vr[a], vr[b2], vi[a] * vi[b2]);
      const float q = fmaf(vr[a], vi[b2], -(vi[a] * vr[b2]));
      acc = fmaf(oR[u], p, fmaf(-oI[u], q, acc));
    }
  }
  return acc;
}

// ---- wave-local product-state init: even SU4 layer on |0..0> ----
__device__ __forceinline__ void init_productW(float2* __restrict__ st,
                                              const float2* __restrict__ Ush,
                                              int tid) {
  const int w = tid >> 6, l = tid & 63;
  const int k0 = w >> 2, k1 = w & 3;
  const int k2 = l >> 4, k3 = (l >> 2) & 3, k4 = l & 3;
  const float f0r = rfl(Ush[0 * 16 + k0 * 4].x), f0i = rfl(Ush[0 * 16 + k0 * 4].y);
  const float f1r = rfl(Ush[1 * 16 + k1 * 4].x), f1i = rfl(Ush[1 * 16 + k1 * 4].y);
  const float2 f2 = Ush[2 * 16 + k2 * 4];
  const float2 f3 = Ush[3 * 16 + k3 * 4];
  const float2 f4 = Ush[4 * 16 + k4 * 4];
  float hr = f0r * f1r - f0i * f1i, hi = f0r * f1i + f0i * f1r, tr, ti;
  tr = hr * f2.x - hi * f2.y; ti = hr * f2.y + hi * f2.x; hr = tr; hi = ti;
  tr = hr * f3.x - hi * f3.y; ti = hr * f3.y + hi * f3.x; hr = tr; hi = ti;
  tr = hr * f4.x - hi * f4.y; ti = hr * f4.y + hi * f4.x; hr = tr; hi = ti;
  float c5r[4], c5i[4], c6r[4], c6i[4];
  #pragma unroll
  for (int m = 0; m < 4; ++m) {
    c5r[m] = rfl(Ush[5 * 16 + m * 4].x); c5i[m] = rfl(Ush[5 * 16 + m * 4].y);
    c6r[m] = rfl(Ush[6 * 16 + m * 4].x); c6i[m] = rfl(Ush[6 * 16 + m * 4].y);
  }
  const int a0 = ef_c((w << 10) | (l << 4));
  #pragma unroll
  for (int k = 0; k < 16; ++k) {
    const float pr = c5r[k >> 2] * c6r[k & 3] - c5i[k >> 2] * c6i[k & 3];
    const float pi_ = c5r[k >> 2] * c6i[k & 3] + c5i[k >> 2] * c6r[k & 3];
    st[a0 ^ ef_c(k)] = make_float2(hr * pr - hi * pi_, hr * pi_ + hi * pr);
  }
}

// ---- common gate-pair body on 16 in-register amps ----
__device__ __forceinline__ void gate_pair16(const float2* __restrict__ ugA,
                                            const float2* __restrict__ ugB,
                                            float vr[16], float vi[16]) {
  {  // gate A on k-bits (3,2)
    float ur[16], ui_[16];
    #pragma unroll
    for (int i = 0; i < 16; ++i) { ur[i] = rfl(ugA[i].x); ui_[i] = rfl(ugA[i].y); }
    #pragma unroll
    for (int r = 0; r < 4; ++r) {
      float tr[4], ti_[4];
      #pragma unroll
      for (int i = 0; i < 4; ++i) {
        float sr = 0.f, si = 0.f;
        #pragma unroll
        for (int l = 0; l < 4; ++l) {
          const int kl = (l << 2) | r;
          sr = fmaf(ur[i * 4 + l], vr[kl], fmaf(-ui_[i * 4 + l], vi[kl], sr));
          si = fmaf(ur[i * 4 + l], vi[kl], fmaf(ui_[i * 4 + l], vr[kl], si));
        }
        tr[i] = sr; ti_[i] = si;
      }
      #pragma unroll
      for (int i = 0; i < 4; ++i) { vr[(i << 2) | r] = tr[i]; vi[(i << 2) | r] = ti_[i]; }
    }
  }
  {  // gate B on k-bits (1,0)
    float ur[16], ui_[16];
    #pragma unroll
    for (int i = 0; i < 16; ++i) { ur[i] = rfl(ugB[i].x); ui_[i] = rfl(ugB[i].y); }
    #pragma unroll
    for (int r = 0; r < 4; ++r) {
      float tr[4], ti_[4];
      #pragma unroll
      for (int i = 0; i < 4; ++i) {
        float sr = 0.f, si = 0.f;
        #pragma unroll
        for (int l = 0; l < 4; ++l) {
          const int kl = (r << 2) | l;
          sr = fmaf(ur[i * 4 + l], vr[kl], fmaf(-ui_[i * 4 + l], vi[kl], sr));
          si = fmaf(ur[i * 4 + l], vi[kl], fmaf(ui_[i * 4 + l], vr[kl], si));
        }
        tr[i] = sr; ti_[i] = si;
      }
      #pragma unroll
      for (int i = 0; i < 4; ++i) { vr[(r << 2) | i] = tr[i]; vi[(r << 2) | i] = ti_[i]; }
    }
  }
}

// ---- cross-wave SU4 pair pass (window bits 12..9) ----
template<int SH>
__device__ __forceinline__ void su4_pair(float2* __restrict__ st,
                                         const float2* __restrict__ ugA,
                                         const float2* __restrict__ ugB,
                                         int tid) {
  constexpr int m = (1 << SH) - 1;
  const int a0 = ef_c(((tid & ~m) << 4) | (tid & m));
  float vr[16], vi[16];
  #pragma unroll
  for (int k = 0; k < 16; ++k) {
    const float2 v = st[a0 ^ ef_c(k << SH)];
    vr[k] = v.x; vi[k] = v.y;
  }
  gate_pair16(ugA, ugB, vr, vi);
  #pragma unroll
  for (int k = 0; k < 16; ++k)
    st[a0 ^ ef_c(k << SH)] = make_float2(vr[k], vi[k]);
  __syncthreads();
}

// ---- WAVE-LOCAL SU4 pair pass (SH+4 <= 10): NO barrier ----
template<int SH>
__device__ __forceinline__ void su4_pairW(float2* __restrict__ st,
                                          const float2* __restrict__ ugA,
                                          const float2* __restrict__ ugB,
                                          int tid) {
  const int w = tid >> 6, l = tid & 63;
  constexpr int m = (1 << SH) - 1;
  const int a0 = ef_c((w << 10) | ((l & ~m) << 4) | (l & m));
  float vr[16], vi[16];
  #pragma unroll
  for (int k = 0; k < 16; ++k) {
    const float2 v = st[a0 ^ ef_c(k << SH)];
    vr[k] = v.x; vi[k] = v.y;
  }
  gate_pair16(ugA, ugB, vr, vi);
  #pragma unroll
  for (int k = 0; k < 16; ++k)
    st[a0 ^ ef_c(k << SH)] = make_float2(vr[k], vi[k]);
}

template<int J>
__device__ __forceinline__ void bfly16(float c, float s, float pr[16], float pi_[16]) {
  #pragma unroll
  for (int i = 0; i < 16; ++i) {
    if ((i & (1 << J)) == 0) {
      const int j = i | (1 << J);
      const float ar = pr[i], ai = pi_[i], br = pr[j], bi = pi_[j];
      pr[i]  = fmaf(c, ar, -(s * br));
      pi_[i] = fmaf(c, ai, -(s * bi));
      pr[j]  = fmaf(s, ar, c * br);
      pi_[j] = fmaf(s, ai, c * bi);
    }
  }
}

// ---- WAVE-LOCAL 4-qubit RY pass (SH in {6,2}): NO barrier ----
template<int SH>
__device__ __forceinline__ void ry4W(float2* __restrict__ st,
                                     const float* __restrict__ rc,
                                     const float* __restrict__ rs, int tid) {
  const float c3 = rfl(rc[10 - SH]), s3 = rfl(rs[10 - SH]);
  const float c2 = rfl(rc[11 - SH]), s2 = rfl(rs[11 - SH]);
  const float c1 = rfl(rc[12 - SH]), s1 = rfl(rs[12 - SH]);
  const float c0 = rfl(rc[13 - SH]), s0 = rfl(rs[13 - SH]);
  const int w = tid >> 6, l = tid & 63;
  constexpr int m = (1 << SH) - 1;
  const int a0 = ef_c((w << 10) | ((l & ~m) << 4) | (l & m));
  float vr[16], vi[16];
  #pragma unroll
  for (int k = 0; k < 16; ++k) {
    const float2 v = st[a0 ^ ef_c(k << SH)];
    vr[k] = v.x; vi[k] = v.y;
  }
  bfly16<3>(c3, s3, vr, vi);
  bfly16<2>(c2, s2, vr, vi);
  bfly16<1>(c1, s1, vr, vi);
  bfly16<0>(c0, s0, vr, vi);
  #pragma unroll
  for (int k = 0; k < 16; ++k)
    st[a0 ^ ef_c(k << SH)] = make_float2(vr[k], vi[k]);
}

// ---- WAVE-LOCAL RY pass for qubits 12,13 (bits 1,0): NO barrier ----
__device__ __forceinline__ void ry2W(float2* __restrict__ st,
                                     const float* __restrict__ rc,
                                     const float* __restrict__ rs, int tid) {
  const float c1 = rfl(rc[12]), s1 = rfl(rs[12]);
  const float c0 = rfl(rc[13]), s0 = rfl(rs[13]);
  const int w = tid >> 6, l = tid & 63;
  #pragma unroll
  for (int j = 0; j < 4; ++j) {
    const int a0 = ef_c((w << 10) | ((l + (j << 6)) << 2));
    float vr[4], vi[4];
    #pragma unroll
    for (int k = 0; k < 4; ++k) {
      const float2 v = st[a0 ^ ef_c(k)];
      vr[k] = v.x; vi[k] = v.y;
    }
    #pragma unroll
    for (int k = 0; k < 2; ++k) {
      const float ar = vr[k], ai = vi[k], br = vr[k + 2], bi = vi[k + 2];
      vr[k]     = fmaf(c1, ar, -(s1 * br));
      vi[k]     = fmaf(c1, ai, -(s1 * bi));
      vr[k + 2] = fmaf(s1, ar, c1 * br);
      vi[k + 2] = fmaf(s1, ai, c1 * bi);
    }
    #pragma unroll
    for (int k = 0; k < 4; k += 2) {
      const float ar = vr[k], ai = vi[k], br = vr[k + 1], bi = vi[k + 1];
      vr[k]     = fmaf(c0, ar, -(s0 * br));
      vi[k]     = fmaf(c0, ai, -(s0 * bi));
      vr[k + 1] = fmaf(s0, ar, c0 * br);
      vi[k + 1] = fmaf(s0, ai, c0 * bi);
    }
    #pragma unroll
    for (int k = 0; k < 4; ++k)
      st[a0 ^ ef_c(k)] = make_float2(vr[k], vi[k]);
  }
}

__device__ __forceinline__ void reduce_store(float a, float* slot, int lane, int wid) {
  #pragma unroll
  for (int off = 32; off > 0; off >>= 1)
    a += __shfl_down(a, off, 64);
  if (lane == 0) slot[wid] = a;
}

// ---- fused RY(q0..3) + CNOT-chain pass. FINAL: also obs0,obs1 in-register.
// Registers hold psi'(z), z = tid | i<<10; final y bits 13..10 = ymap(i),
// and z-parity == y10, so obs pairs with y10 as SPECTATOR (obs0: bits 13,12;
// obs1: bits 12,11) are register-local. obs2 (pair 11,10) is NOT (y10 flips).
template<bool FINAL>
__device__ __forceinline__ void perm_ry_pass(float2* __restrict__ st,
                                             const float* __restrict__ rc,
                                             const float* __restrict__ rs,
                                             int tid,
                                             const float2* __restrict__ Hsh,
                                             float (*red)[TCIRC / 64],
                                             int lane, int wid) {
  const float c0 = rfl(rc[0]), s0 = rfl(rs[0]);
  const float c1 = rfl(rc[1]), s1 = rfl(rs[1]);
  const float c2 = rfl(rc[2]), s2 = rfl(rs[2]);
  const float c3 = rfl(rc[3]), s3 = rfl(rs[3]);
  __syncthreads();   // wave-local writers from prior passes must land
  const int Er = ef_c(tid);
  float pr[16], pi_[16];
  #pragma unroll
  for (int i = 0; i < 16; ++i) {
    const float2 v = st[Er ^ ef_c(i << 10)];
    pr[i] = v.x; pi_[i] = v.y;
  }
  __syncthreads();
  bfly16<3>(c0, s0, pr, pi_);
  bfly16<2>(c1, s1, pr, pi_);
  bfly16<1>(c2, s2, pr, pi_);
  bfly16<0>(c3, s3, pr, pi_);
  if (FINAL) {
    // remap register index z-bits -> y-bits (compile-time permutation)
    float wr[16], wi[16];
    #pragma unroll
    for (int i = 0; i < 16; ++i) { wr[ymap_c(i)] = pr[i]; wi[ymap_c(i)] = pi_[i]; }
    reduce_store(qform16<0>(Hsh + 0 * 16, wr, wi), red[0], lane, wid);  // y13,y12
    reduce_store(qform16<1>(Hsh + 1 * 16, wr, wi), red[1], lane, wid);  // y12,y11
  }
  const int Ew = ef_c(siginv_c(tid));
  #pragma unroll
  for (int i = 0; i < 16; ++i)
    st[Ew ^ ef_c(siginv_c(i << 10))] = make_float2(pr[i], pi_[i]);
  __syncthreads();
}

// ---- obs window pass: 4-bit window bits SH+3..SH, serves up to 3 obs ----
template<int SH, int NOB>
__device__ __forceinline__ void obs_tri(const float2* __restrict__ st,
                                        const float2* __restrict__ Hsh, int obase,
                                        float (*red)[TCIRC / 64],
                                        int lane, int wid, int tid) {
  constexpr int m = (1 << SH) - 1;
  const int a0 = ef_c(((tid & ~m) << 4) | (tid & m));
  float vr[16], vi[16];
  #pragma unroll
  for (int k = 0; k < 16; ++k) {
    const float2 v = st[a0 ^ ef_c(k << SH)];
    vr[k] = v.x; vi[k] = v.y;
  }
  if (NOB == 3) {
    reduce_store(qform16<0>(Hsh + (obase + 0) * 16, vr, vi), red[obase + 0], lane, wid);
    reduce_store(qform16<1>(Hsh + (obase + 1) * 16, vr, vi), red[obase + 1], lane, wid);
    reduce_store(qform16<2>(Hsh + (obase + 2) * 16, vr, vi), red[obase + 2], lane, wid);
  } else {  // NOB==2: MODE1 and MODE2 only (used at SH=0 for obs11, obs12)
    reduce_store(qform16<1>(Hsh + (obase + 0) * 16, vr, vi), red[obase + 0], lane, wid);
    reduce_store(qform16<2>(Hsh + (obase + 1) * 16, vr, vi), red[obase + 1], lane, wid);
  }
}

// ====== single fused kernel: encoder + U-build (shfl-parallel) + circuit ====
__launch_bounds__(TCIRC, 1)
__global__ void circuit_kernel(const float* __restrict__ x,
                               const float* __restrict__ W1,
                               const float* __restrict__ b1,
                               const float* __restrict__ W2,
                               const float* __restrict__ b2,
                               const float* __restrict__ vp,
                               const float* __restrict__ oA,
                               const float* __restrict__ oB,
                               const float* __restrict__ oD,
                               float* __restrict__ out) {
  __shared__ float2 st[DIM];                 // 128 KiB (head: scratch overlay)
  __shared__ float2 Ush[NGATES * 16];
  __shared__ float2 Hsh[NOBSN * 16];
  __shared__ float  ryc[DEPTHN * NQ];
  __shared__ float  rys[DEPTHN * NQ];
  __shared__ float  red[NOBSN][TCIRC / 64];

  const int b = blockIdx.x;
  const int tid = threadIdx.x;

  // ---- head scratch overlaid on the not-yet-initialized state ----
  float* base = (float*)st;
  float* xrow = base;          // 256
  float* hrow = base + 256;    // 256
  float* encs = base + 512;    // 195
  float* part = base + 1024;   // 1024

  // trig + observable H on disjoint high threads (independent of encoder)
  if (tid >= 960 && tid < 960 + DEPTHN * NQ) {
    const int i = tid - 960;
    const float h = 0.5f * vp[i];
    ryc[i] = cosf(h); rys[i] = sinf(h);
  }
  if (tid >= 832 && tid < 832 + NOBSN) {
    const int o = tid - 832;
    const int rr[6] = {1, 2, 2, 3, 3, 3};
    const int cc[6] = {0, 0, 1, 0, 1, 2};
    float2 H[16];
    #pragma unroll
    for (int i = 0; i < 16; ++i) H[i] = make_float2(0.f, 0.f);
    for (int m = 0; m < 6; ++m) {
      const float a = oA[o * 6 + m], bb = oB[o * 6 + m];
      H[rr[m] * 4 + cc[m]] = make_float2(a, bb);
      H[cc[m] * 4 + rr[m]] = make_float2(a, -bb);
    }
    H[0]  = make_float2(2.f * oD[o * 4 + 1], 0.f);
    H[5]  = make_float2(2.f * oD[o * 4 + 2], 0.f);
    H[10] = make_float2(2.f * oD[o * 4 + 3], 0.f);
    for (int i = 0; i < 16; ++i) Hsh[o * 16 + i] = H[i];
  }
  if (tid < INDIM) xrow[tid] = x[b * INDIM + tid];
  __syncthreads();

  {  // hrow partials: 4 threads per output, float4 loads
    const int o = tid & 255, q = tid >> 8;
    const float4* wp = (const float4*)(W1 + o * INDIM + q * 64);
    const float4* xq = (const float4*)(xrow + q * 64);
    float a = 0.f;
    #pragma unroll 4
    for (int k = 0; k < 16; ++k) {
      const float4 wv = wp[k], xv = xq[k];
      a = fmaf(wv.x, xv.x, fmaf(wv.y, xv.y, fmaf(wv.z, xv.z, fmaf(wv.w, xv.w, a))));
    }
    part[(q << 8) | o] = a;
  }
  __syncthreads();
  if (tid < HIDDIM) {
    const float a = b1[tid] + part[tid] + part[256 + tid] + part[512 + tid] + part[768 + tid];
    hrow[tid] = a / (1.f + expf(-a));
  }
  __syncthreads();
  {  // enc partials
    const int o = tid & 255, q = tid >> 8;
    if (o < ENCDIM) {
      const float4* wp = (const float4*)(W2 + o * HIDDIM + q * 64);
      const float4* hq = (const float4*)(hrow + q * 64);
      float a = 0.f;
      #pragma unroll 4
      for (int k = 0; k < 16; ++k) {
        const float4 wv = wp[k], hv = hq[k];
        a = fmaf(wv.x, hv.x, fmaf(wv.y, hv.y, fmaf(wv.z, hv.z, fmaf(wv.w, hv.w, a))));
      }
      part[(q << 8) | o] = a;
    }
  }
  __syncthreads();
  if (tid < ENCDIM)
    encs[tid] = b2[tid] + part[tid] + part[256 + tid] + part[512 + tid] + part[768 + tid];
  __syncthreads();

  // ---- U-build: 16 lanes per gate, matmuls via shfl (no barriers inside) ----
  if (tid < NGATES * 16) {
    const int g = tid >> 4, e = tid & 15, i = e >> 2, j = e & 3;
    const float* th = encs + g * NGEN;
    float Are = 0.f, Aie = 0.f;
    for (int t = 0; t < NGEN; ++t) {
      const int p = t + 1;
      const int pa = p >> 2, pb = p & 3;
      const float ar = c_PR[pa][i >> 1][j >> 1], ai = c_PI[pa][i >> 1][j >> 1];
      const float br = c_PR[pb][i & 1][j & 1],  bi = c_PI[pb][i & 1][j & 1];
      Are = fmaf(th[t], ar * br - ai * bi, Are);
      Aie = fmaf(th[t], ar * bi + ai * br, Aie);
    }
    float r = sqrtf(Are * Are + Aie * Aie);
    r += __shfl_xor(r, 1, 16);
    r += __shfl_xor(r, 2, 16);
    float nrm = r;
    nrm = fmaxf(nrm, __shfl_xor(nrm, 4, 16));
    nrm = fmaxf(nrm, __shfl_xor(nrm, 8, 16));
    int sct = 0;
    float scale = 1.f;
    while (nrm * scale > 0.5f && sct < 30) { scale *= 0.5f; ++sct; }
    const float Mre = -Aie * scale, Mie = Are * scale;   // M = i*A*scale
    float Rr = (i == j) ? 1.f : 0.f, Ri = 0.f;
    for (int k = 10; k >= 1; --k) {
      const float inv = 1.f / (float)k;
      float tr = 0.f, ti = 0.f;
      #pragma unroll
      for (int l = 0; l < 4; ++l) {
        const float mr = __shfl(Mre, i * 4 + l, 16), mi = __shfl(Mie, i * 4 + l, 16);
        const float rr2 = __shfl(Rr, l * 4 + j, 16), ri2 = __shfl(Ri, l * 4 + j, 16);
        tr = fmaf(mr, rr2, fmaf(-mi, ri2, tr));
        ti = fmaf(mr, ri2, fmaf(mi, rr2, ti));
      }
      Rr = ((i == j) ? 1.f : 0.f) + inv * tr;
      Ri = inv * ti;
    }
    for (int it = 0; it < sct; ++it) {
      float tr = 0.f, ti = 0.f;
      #pragma unroll
      for (int l = 0; l < 4; ++l) {
        const float ar = __shfl(Rr, i * 4 + l, 16), ai2 = __shfl(Ri, i * 4 + l, 16);
        const float br = __shfl(Rr, l * 4 + j, 16), bi2 = __shfl(Ri, l * 4 + j, 16);
        tr = fmaf(ar, br, fmaf(-ai2, bi2, tr));
        ti = fmaf(ar, bi2, fmaf(ai2, br, ti));
      }
      Rr = tr; Ri = ti;
    }
    Ush[g * 16 + e] = make_float2(Rr, Ri);
  }
  __syncthreads();

  // ---- even SU4 layer as wave-local product-state init ----
  init_productW(st, Ush, tid);
  __syncthreads();

  // ---- odd SU4 layer: 1 cross-wave + 2 wave-local passes ----
  su4_pair<9>(st, Ush + 7 * 16, Ush + 8 * 16, tid);    // q1,q3 (bits 12..9)
  su4_pairW<5>(st, Ush + 9 * 16, Ush + 10 * 16, tid);  // q5,q7 (bits 8..5)
  su4_pairW<1>(st, Ush + 11 * 16, Ush + 12 * 16, tid); // q9,q11 (bits 4..1)

  // ---- variational depths ----
  const int lane = tid & 63, wid = tid >> 6;
  #pragma unroll 1
  for (int d = 0; d < DEPTHN - 1; ++d) {
    const float* rc = ryc + d * NQ;
    const float* rs = rys + d * NQ;
    ry4W<6>(st, rc, rs, tid);                              // qubits 4..7
    ry4W<2>(st, rc, rs, tid);                              // qubits 8..11
    ry2W(st, rc, rs, tid);                                 // qubits 12,13
    perm_ry_pass<false>(st, rc, rs, tid, Hsh, red, lane, wid);
  }
  {  // final depth: perm pass also computes obs0, obs1 in-register
    const float* rc = ryc + (DEPTHN - 1) * NQ;
    const float* rs = rys + (DEPTHN - 1) * NQ;
    ry4W<6>(st, rc, rs, tid);
    ry4W<2>(st, rc, rs, tid);
    ry2W(st, rc, rs, tid);
    perm_ry_pass<true>(st, rc, rs, tid, Hsh, red, lane, wid);
  }

  // ---- remaining observables: 4 read-only window passes ----
  obs_tri<8, 3>(st, Hsh, 2, red, lane, wid, tid);   // obs2 (11,10), obs3, obs4
  obs_tri<5, 3>(st, Hsh, 5, red, lane, wid, tid);   // obs5, obs6, obs7
  obs_tri<2, 3>(st, Hsh, 8, red, lane, wid, tid);   // obs8, obs9, obs10
  obs_tri<0, 2>(st, Hsh, 11, red, lane, wid, tid);  // obs11 (2,1), obs12 (1,0)

  __syncthreads();
  if (tid < NOBSN) {
    float s = 0.f;
    #pragma unroll
    for (int w = 0; w < TCIRC / 64; ++w) s += red[tid][w];
    out[b * NOBSN + tid] = s;
  }
}

extern "C" void kernel_launch(void* const* d_in, const int* in_sizes, int n_in,
                              void* d_out, int out_size, void* d_ws, size_t ws_size,
                              hipStream_t stream) {
  const float* x  = (const float*)d_in[0];
  const float* W1 = (const float*)d_in[1];
  const float* b1 = (const float*)d_in[2];
  const float* W2 = (const float*)d_in[3];
  const float* b2 = (const float*)d_in[4];
  const float* vp = (const float*)d_in[5];
  const float* oA = (const float*)d_in[6];
  const float* oB = (const float*)d_in[7];
  const float* oD = (const float*)d_in[8];
  float* out = (float*)d_out;

  circuit_kernel<<<BATCHN, TCIRC, 0, stream>>>(x, W1, b1, W2, b2, vp, oA, oB, oD, out);
}

// Round 13
// 74.017 us; speedup vs baseline: 2.6973x; 1.0867x over previous
//
#include <hip/hip_runtime.h>
#include <math.h>

#define NQ        14
#define DIM       16384      // 2^14
#define BATCHN    128
#define NGATES    13
#define NGEN      15
#define NOBSN     13
#define DEPTHN    4
#define INDIM     256
#define HIDDIM    256
#define ENCDIM    195
#define TCIRC     1024

// Pauli 2x2 matrices (real, imag parts). Order: I, X, Y, Z.
__constant__ float c_PR[4][2][2] = {
  {{1.f, 0.f}, {0.f, 1.f}},   // I
  {{0.f, 1.f}, {1.f, 0.f}},   // X
  {{0.f, 0.f}, {0.f, 0.f}},   // Y (real part)
  {{1.f, 0.f}, {0.f,-1.f}},   // Z
};
__constant__ float c_PI[4][2][2] = {
  {{0.f, 0.f}, {0.f, 0.f}},
  {{0.f, 0.f}, {0.f, 0.f}},
  {{0.f,-1.f}, {1.f, 0.f}},   // Y (imag part)
  {{0.f, 0.f}, {0.f, 0.f}},
};

__device__ __forceinline__ float rfl(float x) {
  return __int_as_float(__builtin_amdgcn_readfirstlane(__float_as_int(x)));
}

// DPP quad-perm cross-lane (VALU pipe — NOT ds_swizzle). 0xB1 = xor-1, 0x4E = xor-2.
template<int CTRL>
__device__ __forceinline__ float fdpp(float v) {
  return __int_as_float(__builtin_amdgcn_mov_dpp(__float_as_int(v), CTRL, 0xF, 0xF, true));
}

// Bank swizzle (R10-12-proven): b0^=y5, b1^=y6^y9, b2^=y5^y7, b3^=y7^y8, b4^=y6.
constexpr int ef_c(int y) {
  return y ^ (((y >> 5) & 1) * 5)
           ^ (((y >> 6) & 1) * 18)
           ^ (((y >> 7) & 1) * 12)
           ^ (((y >> 8) & 1) * 8)
           ^ (((y >> 9) & 1) * 2);
}
// CNOT-chain permutation: sigma(y) = y ^ ((y>>1)&8191); inverse = suffix fold.
constexpr int siginv_c(int z) {
  int t = z;
  t ^= t >> 1; t ^= t >> 2; t ^= t >> 4; t ^= t >> 8;
  return t & 16383;
}
// z bits 13..10 -> final y bits 13..10 under siginv (triangular suffix parity).
constexpr int ymap_c(int i) {
  const int p3 = (i >> 3) & 1;
  const int p2 = p3 ^ ((i >> 2) & 1);
  const int p1 = p2 ^ ((i >> 1) & 1);
  const int p0 = p1 ^ (i & 1);
  return (p3 << 3) | (p2 << 2) | (p1 << 1) | p0;
}
// quadratic-form amp index for a 2-qubit pair inside a 4-bit window:
// MODE 0: pair at k bits (3,2); MODE 1: bits (2,1); MODE 2: bits (1,0).
constexpr int qidx(int MODE, int i, int s) {
  return MODE == 0 ? ((i << 2) | s)
       : MODE == 1 ? (((s >> 1) << 3) | (i << 1) | (s & 1))
       : ((s << 2) | i);
}

// <v|H|v> over 16 amps for one obs; H compressed to diag + upper triangle.
template<int MODE>
__device__ __forceinline__ float qform16(const float2* __restrict__ hp,
                                         const float vr[16], const float vi[16]) {
  const int ui[6] = {0, 0, 0, 1, 1, 2};
  const int uj[6] = {1, 2, 3, 2, 3, 3};
  float dH[4], oR[6], oI[6];
  #pragma unroll
  for (int i = 0; i < 4; ++i) dH[i] = rfl(hp[i * 5].x);
  #pragma unroll
  for (int u = 0; u < 6; ++u) {
    oR[u] = rfl(2.f * hp[ui[u] * 4 + uj[u]].x);
    oI[u] = rfl(2.f * hp[ui[u] * 4 + uj[u]].y);
  }
  float acc = 0.f;
  #pragma unroll
  for (int s = 0; s < 4; ++s) {
    #pragma unroll
    for (int i = 0; i < 4; ++i) {
      const int k = qidx(MODE, i, s);
      acc = fmaf(dH[i], fmaf(vr[k], vr[k], vi[k] * vi[k]), acc);
    }
    #pragma unroll
    for (int u = 0; u < 6; ++u) {
      const int a = qidx(MODE, ui[u], s), b2 = qidx(MODE, uj[u], s);
      const float p = fmaf(vr[a], vr[b2], vi[a] * vi[b2]);
      const float q = fmaf(vr[a], vi[b2], -(vi[a] * vr[b2]));
      acc = fmaf(oR[u], p, fmaf(-oI[u], q, acc));
    }
  }
  return acc;
}

// ---- common gate-pair body on 16 in-register amps ----
__device__ __forceinline__ void gate_pair16(const float2* __restrict__ ugA,
                                            const float2* __restrict__ ugB,
                                            float vr[16], float vi[16]) {
  {  // gate A on k-bits (3,2)
    float ur[16], ui_[16];
    #pragma unroll
    for (int i = 0; i < 16; ++i) { ur[i] = rfl(ugA[i].x); ui_[i] = rfl(ugA[i].y); }
    #pragma unroll
    for (int r = 0; r < 4; ++r) {
      float tr[4], ti_[4];
      #pragma unroll
      for (int i = 0; i < 4; ++i) {
        float sr = 0.f, si = 0.f;
        #pragma unroll
        for (int l = 0; l < 4; ++l) {
          const int kl = (l << 2) | r;
          sr = fmaf(ur[i * 4 + l], vr[kl], fmaf(-ui_[i * 4 + l], vi[kl], sr));
          si = fmaf(ur[i * 4 + l], vi[kl], fmaf(ui_[i * 4 + l], vr[kl], si));
        }
        tr[i] = sr; ti_[i] = si;
      }
      #pragma unroll
      for (int i = 0; i < 4; ++i) { vr[(i << 2) | r] = tr[i]; vi[(i << 2) | r] = ti_[i]; }
    }
  }
  {  // gate B on k-bits (1,0)
    float ur[16], ui_[16];
    #pragma unroll
    for (int i = 0; i < 16; ++i) { ur[i] = rfl(ugB[i].x); ui_[i] = rfl(ugB[i].y); }
    #pragma unroll
    for (int r = 0; r < 4; ++r) {
      float tr[4], ti_[4];
      #pragma unroll
      for (int i = 0; i < 4; ++i) {
        float sr = 0.f, si = 0.f;
        #pragma unroll
        for (int l = 0; l < 4; ++l) {
          const int kl = (r << 2) | l;
          sr = fmaf(ur[i * 4 + l], vr[kl], fmaf(-ui_[i * 4 + l], vi[kl], sr));
          si = fmaf(ur[i * 4 + l], vi[kl], fmaf(ui_[i * 4 + l], vr[kl], si));
        }
        tr[i] = sr; ti_[i] = si;
      }
      #pragma unroll
      for (int i = 0; i < 4; ++i) { vr[(r << 2) | i] = tr[i]; vi[(r << 2) | i] = ti_[i]; }
    }
  }
}

// ---- FUSED init + pair9: even layer is a product state, so the pair9 thread
// computes its 16 input amps (window bits 12..9) in closed form — no init
// pass, no gather, one barrier. Thread fixed bits: y13=t9, y8..0=tid bits 8..0.
__device__ __forceinline__ void init_pair9(float2* __restrict__ st,
                                           const float2* __restrict__ Ush,
                                           int tid) {
  const int t9 = (tid >> 9) & 1, t8 = (tid >> 8) & 1;   // wave-uniform
  const int t76 = (tid >> 6) & 3;                        // wave-uniform
  const int t54 = (tid >> 4) & 3, t32 = (tid >> 2) & 3, t10 = tid & 3;
  float f0r[2], f0i[2];                 // f0[(t9<<1)|k3]
  #pragma unroll
  for (int k3 = 0; k3 < 2; ++k3) {
    f0r[k3] = rfl(Ush[0 * 16 + ((t9 << 1) | k3) * 4].x);
    f0i[k3] = rfl(Ush[0 * 16 + ((t9 << 1) | k3) * 4].y);
  }
  float f1r[4], f1i[4];                 // f1[k2k1]
  #pragma unroll
  for (int j = 0; j < 4; ++j) {
    f1r[j] = rfl(Ush[1 * 16 + j * 4].x);
    f1i[j] = rfl(Ush[1 * 16 + j * 4].y);
  }
  float f2r[2], f2i[2];                 // f2[(k0<<1)|t8]
  #pragma unroll
  for (int k0 = 0; k0 < 2; ++k0) {
    f2r[k0] = rfl(Ush[2 * 16 + ((k0 << 1) | t8) * 4].x);
    f2i[k0] = rfl(Ush[2 * 16 + ((k0 << 1) | t8) * 4].y);
  }
  // C = f3[t76]*f4[t54]*f5[t32]*f6[t10]
  const float f3r = rfl(Ush[3 * 16 + t76 * 4].x), f3i = rfl(Ush[3 * 16 + t76 * 4].y);
  const float2 f4 = Ush[4 * 16 + t54 * 4];
  const float2 f5 = Ush[5 * 16 + t32 * 4];
  const float2 f6 = Ush[6 * 16 + t10 * 4];
  float cr = f3r * f4.x - f3i * f4.y, ci = f3r * f4.y + f3i * f4.x, tr, ti;
  tr = cr * f5.x - ci * f5.y; ti = cr * f5.y + ci * f5.x; cr = tr; ci = ti;
  tr = cr * f6.x - ci * f6.y; ti = cr * f6.y + ci * f6.x; cr = tr; ci = ti;
  float g2r[2], g2i[2];                 // f2[k0]*C
  #pragma unroll
  for (int k0 = 0; k0 < 2; ++k0) {
    g2r[k0] = f2r[k0] * cr - f2i[k0] * ci;
    g2i[k0] = f2r[k0] * ci + f2i[k0] * cr;
  }
  float vr[16], vi[16];
  #pragma unroll
  for (int k = 0; k < 16; ++k) {
    const int k3 = k >> 3, k21 = (k >> 1) & 3, k0 = k & 1;
    const float hr2 = f0r[k3] * f1r[k21] - f0i[k3] * f1i[k21];
    const float hi2 = f0r[k3] * f1i[k21] + f0i[k3] * f1r[k21];
    vr[k] = hr2 * g2r[k0] - hi2 * g2i[k0];
    vi[k] = hr2 * g2i[k0] + hi2 * g2r[k0];
  }
  gate_pair16(Ush + 7 * 16, Ush + 8 * 16, vr, vi);   // q1 (bits 12,11), q3 (10,9)
  constexpr int m = (1 << 9) - 1;
  const int a0 = ef_c(((tid & ~m) << 4) | (tid & m));
  #pragma unroll
  for (int k = 0; k < 16; ++k)
    st[a0 ^ ef_c(k << 9)] = make_float2(vr[k], vi[k]);
  __syncthreads();
}

// ---- WAVE-LOCAL SU4 pair pass (SH+4 <= 10): NO barrier ----
template<int SH>
__device__ __forceinline__ void su4_pairW(float2* __restrict__ st,
                                          const float2* __restrict__ ugA,
                                          const float2* __restrict__ ugB,
                                          int tid) {
  const int w = tid >> 6, l = tid & 63;
  constexpr int m = (1 << SH) - 1;
  const int a0 = ef_c((w << 10) | ((l & ~m) << 4) | (l & m));
  float vr[16], vi[16];
  #pragma unroll
  for (int k = 0; k < 16; ++k) {
    const float2 v = st[a0 ^ ef_c(k << SH)];
    vr[k] = v.x; vi[k] = v.y;
  }
  gate_pair16(ugA, ugB, vr, vi);
  #pragma unroll
  for (int k = 0; k < 16; ++k)
    st[a0 ^ ef_c(k << SH)] = make_float2(vr[k], vi[k]);
}

template<int J>
__device__ __forceinline__ void bfly16(float c, float s, float pr[16], float pi_[16]) {
  #pragma unroll
  for (int i = 0; i < 16; ++i) {
    if ((i & (1 << J)) == 0) {
      const int j = i | (1 << J);
      const float ar = pr[i], ai = pi_[i], br = pr[j], bi = pi_[j];
      pr[i]  = fmaf(c, ar, -(s * br));
      pi_[i] = fmaf(c, ai, -(s * bi));
      pr[j]  = fmaf(s, ar, c * br);
      pi_[j] = fmaf(s, ai, c * bi);
    }
  }
}

// ---- WAVE-LOCAL 4-qubit RY pass at SH=6 (qubits 4..7): NO barrier ----
__device__ __forceinline__ void ry4W6(float2* __restrict__ st,
                                      const float* __restrict__ rc,
                                      const float* __restrict__ rs, int tid) {
  const float c3 = rfl(rc[4]), s3 = rfl(rs[4]);
  const float c2 = rfl(rc[5]), s2 = rfl(rs[5]);
  const float c1 = rfl(rc[6]), s1 = rfl(rs[6]);
  const float c0 = rfl(rc[7]), s0 = rfl(rs[7]);
  const int w = tid >> 6, l = tid & 63;
  const int a0 = ef_c((w << 10) | l);   // SH=6: (l&~63)<<4 == 0
  float vr[16], vi[16];
  #pragma unroll
  for (int k = 0; k < 16; ++k) {
    const float2 v = st[a0 ^ ef_c(k << 6)];
    vr[k] = v.x; vi[k] = v.y;
  }
  bfly16<3>(c3, s3, vr, vi);
  bfly16<2>(c2, s2, vr, vi);
  bfly16<1>(c1, s1, vr, vi);
  bfly16<0>(c0, s0, vr, vi);
  #pragma unroll
  for (int k = 0; k < 16; ++k)
    st[a0 ^ ef_c(k << 6)] = make_float2(vr[k], vi[k]);
}

// ---- WAVE-LOCAL RY pass at SH=2 (qubits 8..11) + DPP butterflies for
// qubits 12,13 (y-bits 1,0 = lane bits 1,0, quad-aligned): replaces ry2W.
__device__ __forceinline__ void ry4W2d(float2* __restrict__ st,
                                       const float* __restrict__ rc,
                                       const float* __restrict__ rs, int tid) {
  const float c3 = rfl(rc[8]),  s3 = rfl(rs[8]);
  const float c2 = rfl(rc[9]),  s2 = rfl(rs[9]);
  const float c1 = rfl(rc[10]), s1 = rfl(rs[10]);
  const float c0 = rfl(rc[11]), s0 = rfl(rs[11]);
  const float cA = rfl(rc[12]), sA = rfl(rs[12]);   // qubit 12 -> y bit 1
  const float cB = rfl(rc[13]), sB = rfl(rs[13]);   // qubit 13 -> y bit 0
  const int w = tid >> 6, l = tid & 63;
  const int a0 = ef_c((w << 10) | ((l & ~3) << 4) | (l & 3));
  float vr[16], vi[16];
  #pragma unroll
  for (int k = 0; k < 16; ++k) {
    const float2 v = st[a0 ^ ef_c(k << 2)];
    vr[k] = v.x; vi[k] = v.y;
  }
  bfly16<3>(c3, s3, vr, vi);
  bfly16<2>(c2, s2, vr, vi);
  bfly16<1>(c1, s1, vr, vi);
  bfly16<0>(c0, s0, vr, vi);
  // qubit 13 (y bit 0): partner lane l^1 (quad_perm 0xB1); even lane: -s
  {
    const float se = (l & 1) ? sB : -sB;
    #pragma unroll
    for (int k = 0; k < 16; ++k) {
      const float pr = fdpp<0xB1>(vr[k]), pi_ = fdpp<0xB1>(vi[k]);
      vr[k] = fmaf(cB, vr[k], se * pr);
      vi[k] = fmaf(cB, vi[k], se * pi_);
    }
  }
  // qubit 12 (y bit 1): partner lane l^2 (quad_perm 0x4E)
  {
    const float se = (l & 2) ? sA : -sA;
    #pragma unroll
    for (int k = 0; k < 16; ++k) {
      const float pr = fdpp<0x4E>(vr[k]), pi_ = fdpp<0x4E>(vi[k]);
      vr[k] = fmaf(cA, vr[k], se * pr);
      vi[k] = fmaf(cA, vi[k], se * pi_);
    }
  }
  #pragma unroll
  for (int k = 0; k < 16; ++k)
    st[a0 ^ ef_c(k << 2)] = make_float2(vr[k], vi[k]);
}

__device__ __forceinline__ void reduce_store(float a, float* slot, int lane, int wid) {
  #pragma unroll
  for (int off = 32; off > 0; off >>= 1)
    a += __shfl_down(a, off, 64);
  if (lane == 0) slot[wid] = a;
}

// ---- fused RY(q0..3) + CNOT-chain pass. FINAL: also obs0,obs1 in-register.
template<bool FINAL>
__device__ __forceinline__ void perm_ry_pass(float2* __restrict__ st,
                                             const float* __restrict__ rc,
                                             const float* __restrict__ rs,
                                             int tid,
                                             const float2* __restrict__ Hsh,
                                             float (*red)[TCIRC / 64],
                                             int lane, int wid) {
  const float c0 = rfl(rc[0]), s0 = rfl(rs[0]);
  const float c1 = rfl(rc[1]), s1 = rfl(rs[1]);
  const float c2 = rfl(rc[2]), s2 = rfl(rs[2]);
  const float c3 = rfl(rc[3]), s3 = rfl(rs[3]);
  __syncthreads();   // wave-local writers from prior passes must land
  const int Er = ef_c(tid);
  float pr[16], pi_[16];
  #pragma unroll
  for (int i = 0; i < 16; ++i) {
    const float2 v = st[Er ^ ef_c(i << 10)];
    pr[i] = v.x; pi_[i] = v.y;
  }
  __syncthreads();
  bfly16<3>(c0, s0, pr, pi_);
  bfly16<2>(c1, s1, pr, pi_);
  bfly16<1>(c2, s2, pr, pi_);
  bfly16<0>(c3, s3, pr, pi_);
  if (FINAL) {
    float wr[16], wi[16];
    #pragma unroll
    for (int i = 0; i < 16; ++i) { wr[ymap_c(i)] = pr[i]; wi[ymap_c(i)] = pi_[i]; }
    reduce_store(qform16<0>(Hsh + 0 * 16, wr, wi), red[0], lane, wid);  // y13,y12
    reduce_store(qform16<1>(Hsh + 1 * 16, wr, wi), red[1], lane, wid);  // y12,y11
  }
  const int Ew = ef_c(siginv_c(tid));
  #pragma unroll
  for (int i = 0; i < 16; ++i)
    st[Ew ^ ef_c(siginv_c(i << 10))] = make_float2(pr[i], pi_[i]);
  __syncthreads();
}

// ---- obs window pass: 4-bit window bits SH+3..SH, serves up to 3 obs ----
template<int SH, int NOB>
__device__ __forceinline__ void obs_tri(const float2* __restrict__ st,
                                        const float2* __restrict__ Hsh, int obase,
                                        float (*red)[TCIRC / 64],
                                        int lane, int wid, int tid) {
  constexpr int m = (1 << SH) - 1;
  const int a0 = ef_c(((tid & ~m) << 4) | (tid & m));
  float vr[16], vi[16];
  #pragma unroll
  for (int k = 0; k < 16; ++k) {
    const float2 v = st[a0 ^ ef_c(k << SH)];
    vr[k] = v.x; vi[k] = v.y;
  }
  if (NOB == 3) {
    reduce_store(qform16<0>(Hsh + (obase + 0) * 16, vr, vi), red[obase + 0], lane, wid);
    reduce_store(qform16<1>(Hsh + (obase + 1) * 16, vr, vi), red[obase + 1], lane, wid);
    reduce_store(qform16<2>(Hsh + (obase + 2) * 16, vr, vi), red[obase + 2], lane, wid);
  } else {  // NOB==2: MODE1 and MODE2 only (used at SH=0 for obs11, obs12)
    reduce_store(qform16<1>(Hsh + (obase + 0) * 16, vr, vi), red[obase + 0], lane, wid);
    reduce_store(qform16<2>(Hsh + (obase + 1) * 16, vr, vi), red[obase + 1], lane, wid);
  }
}

// ====== single fused kernel: encoder + U-build (shfl-parallel) + circuit ====
__launch_bounds__(TCIRC, 1)
__global__ void circuit_kernel(const float* __restrict__ x,
                               const float* __restrict__ W1,
                               const float* __restrict__ b1,
                               const float* __restrict__ W2,
                               const float* __restrict__ b2,
                               const float* __restrict__ vp,
                               const float* __restrict__ oA,
                               const float* __restrict__ oB,
                               const float* __restrict__ oD,
                               float* __restrict__ out) {
  __shared__ float2 st[DIM];                 // 128 KiB (head: scratch overlay)
  __shared__ float2 Ush[NGATES * 16];
  __shared__ float2 Hsh[NOBSN * 16];
  __shared__ float  ryc[DEPTHN * NQ];
  __shared__ float  rys[DEPTHN * NQ];
  __shared__ float  red[NOBSN][TCIRC / 64];

  const int b = blockIdx.x;
  const int tid = threadIdx.x;

  // ---- head scratch overlaid on the not-yet-initialized state ----
  float* base = (float*)st;
  float* xrow = base;          // 256
  float* hrow = base + 256;    // 256
  float* encs = base + 512;    // 195
  float* part = base + 1024;   // 1024

  // trig + observable H on disjoint high threads (independent of encoder)
  if (tid >= 960 && tid < 960 + DEPTHN * NQ) {
    const int i = tid - 960;
    const float h = 0.5f * vp[i];
    ryc[i] = cosf(h); rys[i] = sinf(h);
  }
  if (tid >= 832 && tid < 832 + NOBSN) {
    const int o = tid - 832;
    const int rr[6] = {1, 2, 2, 3, 3, 3};
    const int cc[6] = {0, 0, 1, 0, 1, 2};
    float2 H[16];
    #pragma unroll
    for (int i = 0; i < 16; ++i) H[i] = make_float2(0.f, 0.f);
    for (int m = 0; m < 6; ++m) {
      const float a = oA[o * 6 + m], bb = oB[o * 6 + m];
      H[rr[m] * 4 + cc[m]] = make_float2(a, bb);
      H[cc[m] * 4 + rr[m]] = make_float2(a, -bb);
    }
    H[0]  = make_float2(2.f * oD[o * 4 + 1], 0.f);
    H[5]  = make_float2(2.f * oD[o * 4 + 2], 0.f);
    H[10] = make_float2(2.f * oD[o * 4 + 3], 0.f);
    for (int i = 0; i < 16; ++i) Hsh[o * 16 + i] = H[i];
  }
  if (tid < INDIM) xrow[tid] = x[b * INDIM + tid];
  __syncthreads();

  {  // hrow partials: 4 threads per output, float4 loads
    const int o = tid & 255, q = tid >> 8;
    const float4* wp = (const float4*)(W1 + o * INDIM + q * 64);
    const float4* xq = (const float4*)(xrow + q * 64);
    float a = 0.f;
    #pragma unroll 4
    for (int k = 0; k < 16; ++k) {
      const float4 wv = wp[k], xv = xq[k];
      a = fmaf(wv.x, xv.x, fmaf(wv.y, xv.y, fmaf(wv.z, xv.z, fmaf(wv.w, xv.w, a))));
    }
    part[(q << 8) | o] = a;
  }
  __syncthreads();
  if (tid < HIDDIM) {
    const float a = b1[tid] + part[tid] + part[256 + tid] + part[512 + tid] + part[768 + tid];
    hrow[tid] = a / (1.f + expf(-a));
  }
  __syncthreads();
  {  // enc partials
    const int o = tid & 255, q = tid >> 8;
    if (o < ENCDIM) {
      const float4* wp = (const float4*)(W2 + o * HIDDIM + q * 64);
      const float4* hq = (const float4*)(hrow + q * 64);
      float a = 0.f;
      #pragma unroll 4
      for (int k = 0; k < 16; ++k) {
        const float4 wv = wp[k], hv = hq[k];
        a = fmaf(wv.x, hv.x, fmaf(wv.y, hv.y, fmaf(wv.z, hv.z, fmaf(wv.w, hv.w, a))));
      }
      part[(q << 8) | o] = a;
    }
  }
  __syncthreads();
  if (tid < ENCDIM)
    encs[tid] = b2[tid] + part[tid] + part[256 + tid] + part[512 + tid] + part[768 + tid];
  __syncthreads();

  // ---- U-build: 16 lanes per gate, matmuls via shfl (no barriers inside) ----
  if (tid < NGATES * 16) {
    const int g = tid >> 4, e = tid & 15, i = e >> 2, j = e & 3;
    const float* th = encs + g * NGEN;
    float Are = 0.f, Aie = 0.f;
    for (int t = 0; t < NGEN; ++t) {
      const int p = t + 1;
      const int pa = p >> 2, pb = p & 3;
      const float ar = c_PR[pa][i >> 1][j >> 1], ai = c_PI[pa][i >> 1][j >> 1];
      const float br = c_PR[pb][i & 1][j & 1],  bi = c_PI[pb][i & 1][j & 1];
      Are = fmaf(th[t], ar * br - ai * bi, Are);
      Aie = fmaf(th[t], ar * bi + ai * br, Aie);
    }
    float r = sqrtf(Are * Are + Aie * Aie);
    r += __shfl_xor(r, 1, 16);
    r += __shfl_xor(r, 2, 16);
    float nrm = r;
    nrm = fmaxf(nrm, __shfl_xor(nrm, 4, 16));
    nrm = fmaxf(nrm, __shfl_xor(nrm, 8, 16));
    int sct = 0;
    float scale = 1.f;
    while (nrm * scale > 0.5f && sct < 30) { scale *= 0.5f; ++sct; }
    const float Mre = -Aie * scale, Mie = Are * scale;   // M = i*A*scale
    float Rr = (i == j) ? 1.f : 0.f, Ri = 0.f;
    for (int k = 10; k >= 1; --k) {
      const float inv = 1.f / (float)k;
      float tr = 0.f, ti = 0.f;
      #pragma unroll
      for (int l = 0; l < 4; ++l) {
        const float mr = __shfl(Mre, i * 4 + l, 16), mi = __shfl(Mie, i * 4 + l, 16);
        const float rr2 = __shfl(Rr, l * 4 + j, 16), ri2 = __shfl(Ri, l * 4 + j, 16);
        tr = fmaf(mr, rr2, fmaf(-mi, ri2, tr));
        ti = fmaf(mr, ri2, fmaf(mi, rr2, ti));
      }
      Rr = ((i == j) ? 1.f : 0.f) + inv * tr;
      Ri = inv * ti;
    }
    for (int it = 0; it < sct; ++it) {
      float tr = 0.f, ti = 0.f;
      #pragma unroll
      for (int l = 0; l < 4; ++l) {
        const float ar = __shfl(Rr, i * 4 + l, 16), ai2 = __shfl(Ri, i * 4 + l, 16);
        const float br = __shfl(Rr, l * 4 + j, 16), bi2 = __shfl(Ri, l * 4 + j, 16);
        tr = fmaf(ar, br, fmaf(-ai2, bi2, tr));
        ti = fmaf(ar, bi2, fmaf(ai2, br, ti));
      }
      Rr = tr; Ri = ti;
    }
    Ush[g * 16 + e] = make_float2(Rr, Ri);
  }
  __syncthreads();

  // ---- fused: even-layer product state + odd gates q1,q3 (one pass, 0 reads)
  init_pair9(st, Ush, tid);

  // ---- remaining odd layer: 2 wave-local passes ----
  su4_pairW<5>(st, Ush + 9 * 16, Ush + 10 * 16, tid);  // q5,q7 (bits 8..5)
  su4_pairW<1>(st, Ush + 11 * 16, Ush + 12 * 16, tid); // q9,q11 (bits 4..1)

  // ---- variational depths: 2 wave-local RY passes + fused perm+RY(0..3) ----
  const int lane = tid & 63, wid = tid >> 6;
  #pragma unroll 1
  for (int d = 0; d < DEPTHN - 1; ++d) {
    const float* rc = ryc + d * NQ;
    const float* rs = rys + d * NQ;
    ry4W6(st, rc, rs, tid);                                // qubits 4..7
    ry4W2d(st, rc, rs, tid);                               // qubits 8..13 (DPP)
    perm_ry_pass<false>(st, rc, rs, tid, Hsh, red, lane, wid);
  }
  {  // final depth: perm pass also computes obs0, obs1 in-register
    const float* rc = ryc + (DEPTHN - 1) * NQ;
    const float* rs = rys + (DEPTHN - 1) * NQ;
    ry4W6(st, rc, rs, tid);
    ry4W2d(st, rc, rs, tid);
    perm_ry_pass<true>(st, rc, rs, tid, Hsh, red, lane, wid);
  }

  // ---- remaining observables: 4 read-only window passes ----
  obs_tri<8, 3>(st, Hsh, 2, red, lane, wid, tid);   // obs2 (11,10), obs3, obs4
  obs_tri<5, 3>(st, Hsh, 5, red, lane, wid, tid);   // obs5, obs6, obs7
  obs_tri<2, 3>(st, Hsh, 8, red, lane, wid, tid);   // obs8, obs9, obs10
  obs_tri<0, 2>(st, Hsh, 11, red, lane, wid, tid);  // obs11 (2,1), obs12 (1,0)

  __syncthreads();
  if (tid < NOBSN) {
    float s = 0.f;
    #pragma unroll
    for (int w = 0; w < TCIRC / 64; ++w) s += red[tid][w];
    out[b * NOBSN + tid] = s;
  }
}

extern "C" void kernel_launch(void* const* d_in, const int* in_sizes, int n_in,
                              void* d_out, int out_size, void* d_ws, size_t ws_size,
                              hipStream_t stream) {
  const float* x  = (const float*)d_in[0];
  const float* W1 = (const float*)d_in[1];
  const float* b1 = (const float*)d_in[2];
  const float* W2 = (const float*)d_in[3];
  const float* b2 = (const float*)d_in[4];
  const float* vp = (const float*)d_in[5];
  const float* oA = (const float*)d_in[6];
  const float* oB = (const float*)d_in[7];
  const float* oD = (const float*)d_in[8];
  float* out = (float*)d_out;

  circuit_kernel<<<BATCHN, TCIRC, 0, stream>>>(x, W1, b1, W2, b2, vp, oA, oB, oD, out);
}

// Round 15
// 73.707 us; speedup vs baseline: 2.7086x; 1.0042x over previous
//
#include <hip/hip_runtime.h>
#include <math.h>

#define NQ        14
#define DIM       16384      // 2^14
#define BATCHN    128
#define NGATES    13
#define NGEN      15
#define NOBSN     13
#define DEPTHN    4
#define INDIM     256
#define HIDDIM    256
#define ENCDIM    195
#define TCIRC     1024

// Pauli 2x2 matrices (real, imag parts). Order: I, X, Y, Z.
__constant__ float c_PR[4][2][2] = {
  {{1.f, 0.f}, {0.f, 1.f}},   // I
  {{0.f, 1.f}, {1.f, 0.f}},   // X
  {{0.f, 0.f}, {0.f, 0.f}},   // Y (real part)
  {{1.f, 0.f}, {0.f,-1.f}},   // Z
};
__constant__ float c_PI[4][2][2] = {
  {{0.f, 0.f}, {0.f, 0.f}},
  {{0.f, 0.f}, {0.f, 0.f}},
  {{0.f,-1.f}, {1.f, 0.f}},   // Y (imag part)
  {{0.f, 0.f}, {0.f, 0.f}},
};

__device__ __forceinline__ float rfl(float x) {
  return __int_as_float(__builtin_amdgcn_readfirstlane(__float_as_int(x)));
}

// DPP cross-lane (VALU pipe — NOT ds_swizzle).
// 0xB1 = quad xor1, 0x4E = quad xor2, 0x141 = row half-mirror (xor7),
// 0x140 = row mirror (xor15).
template<int CTRL>
__device__ __forceinline__ float fdpp(float v) {
  return __int_as_float(__builtin_amdgcn_mov_dpp(__float_as_int(v), CTRL, 0xF, 0xF, true));
}

// Bank swizzle (R10-13-proven): b0^=y5, b1^=y6^y9, b2^=y5^y7, b3^=y7^y8, b4^=y6.
constexpr int ef_c(int y) {
  return y ^ (((y >> 5) & 1) * 5)
           ^ (((y >> 6) & 1) * 18)
           ^ (((y >> 7) & 1) * 12)
           ^ (((y >> 8) & 1) * 8)
           ^ (((y >> 9) & 1) * 2);
}
// CNOT-chain permutation: sigma(y) = y ^ ((y>>1)&8191); inverse = suffix fold.
constexpr int siginv_c(int z) {
  int t = z;
  t ^= t >> 1; t ^= t >> 2; t ^= t >> 4; t ^= t >> 8;
  return t & 16383;
}
// inverse of the z-bits-13..10 -> y-bits-13..10 map: yinv(j) = j ^ (j>>1).
// NOTE (R14 post-mortem): parity(yinv(j)) == j0 == y10, and the register set's
// low y-bits depend on parity(i) — so ONLY obs with y10 fixed inside their
// pairs (obs0: y13,y12; obs1: y12,y11) are register-local in the FINAL pass.
// obs2 (y11,y10) is NOT (y10 flips) — it must go through LDS.
constexpr int yinv_c(int j) { return (j ^ (j >> 1)) & 15; }

// quadratic-form amp index for a 2-qubit pair inside a 4-bit window:
// MODE 0: pair at k bits (3,2); MODE 1: bits (2,1); MODE 2: bits (1,0).
constexpr int qidx(int MODE, int i, int s) {
  return MODE == 0 ? ((i << 2) | s)
       : MODE == 1 ? (((s >> 1) << 3) | (i << 1) | (s & 1))
       : ((s << 2) | i);
}

// <v|H|v> over 16 amps for one obs; H compressed to diag + upper triangle.
// YM: compose the yinv register-index permutation into the index map
// (FINAL perm pass; avoids materializing a 32-reg copy -> no spill).
template<int MODE, bool YM>
__device__ __forceinline__ float qform16(const float2* __restrict__ hp,
                                         const float vr[16], const float vi[16]) {
  const int ui[6] = {0, 0, 0, 1, 1, 2};
  const int uj[6] = {1, 2, 3, 2, 3, 3};
  float dH[4], oR[6], oI[6];
  #pragma unroll
  for (int i = 0; i < 4; ++i) dH[i] = rfl(hp[i * 5].x);
  #pragma unroll
  for (int u = 0; u < 6; ++u) {
    oR[u] = rfl(2.f * hp[ui[u] * 4 + uj[u]].x);
    oI[u] = rfl(2.f * hp[ui[u] * 4 + uj[u]].y);
  }
  float acc = 0.f;
  #pragma unroll
  for (int s = 0; s < 4; ++s) {
    #pragma unroll
    for (int i = 0; i < 4; ++i) {
      const int k0 = qidx(MODE, i, s);
      const int k = YM ? yinv_c(k0) : k0;
      acc = fmaf(dH[i], fmaf(vr[k], vr[k], vi[k] * vi[k]), acc);
    }
    #pragma unroll
    for (int u = 0; u < 6; ++u) {
      const int a0 = qidx(MODE, ui[u], s), b0 = qidx(MODE, uj[u], s);
      const int a = YM ? yinv_c(a0) : a0, b2 = YM ? yinv_c(b0) : b0;
      const float p = fmaf(vr[a], vr[b2], vi[a] * vi[b2]);
      const float q = fmaf(vr[a], vi[b2], -(vi[a] * vr[b2]));
      acc = fmaf(oR[u], p, fmaf(-oI[u], q, acc));
    }
  }
  return acc;
}

// ---- common gate-pair body on 16 in-register amps ----
__device__ __forceinline__ void gate_pair16(const float2* __restrict__ ugA,
                                            const float2* __restrict__ ugB,
                                            float vr[16], float vi[16]) {
  {  // gate A on k-bits (3,2)
    float ur[16], ui_[16];
    #pragma unroll
    for (int i = 0; i < 16; ++i) { ur[i] = rfl(ugA[i].x); ui_[i] = rfl(ugA[i].y); }
    #pragma unroll
    for (int r = 0; r < 4; ++r) {
      float tr[4], ti_[4];
      #pragma unroll
      for (int i = 0; i < 4; ++i) {
        float sr = 0.f, si = 0.f;
        #pragma unroll
        for (int l = 0; l < 4; ++l) {
          const int kl = (l << 2) | r;
          sr = fmaf(ur[i * 4 + l], vr[kl], fmaf(-ui_[i * 4 + l], vi[kl], sr));
          si = fmaf(ur[i * 4 + l], vi[kl], fmaf(ui_[i * 4 + l], vr[kl], si));
        }
        tr[i] = sr; ti_[i] = si;
      }
      #pragma unroll
      for (int i = 0; i < 4; ++i) { vr[(i << 2) | r] = tr[i]; vi[(i << 2) | r] = ti_[i]; }
    }
  }
  {  // gate B on k-bits (1,0)
    float ur[16], ui_[16];
    #pragma unroll
    for (int i = 0; i < 16; ++i) { ur[i] = rfl(ugB[i].x); ui_[i] = rfl(ugB[i].y); }
    #pragma unroll
    for (int r = 0; r < 4; ++r) {
      float tr[4], ti_[4];
      #pragma unroll
      for (int i = 0; i < 4; ++i) {
        float sr = 0.f, si = 0.f;
        #pragma unroll
        for (int l = 0; l < 4; ++l) {
          const int kl = (r << 2) | l;
          sr = fmaf(ur[i * 4 + l], vr[kl], fmaf(-ui_[i * 4 + l], vi[kl], sr));
          si = fmaf(ur[i * 4 + l], vi[kl], fmaf(ui_[i * 4 + l], vr[kl], si));
        }
        tr[i] = sr; ti_[i] = si;
      }
      #pragma unroll
      for (int i = 0; i < 4; ++i) { vr[(r << 2) | i] = tr[i]; vi[(r << 2) | i] = ti_[i]; }
    }
  }
}

// ---- FUSED init + pair9 (R13-proven): closed-form product state + q1,q3 ----
__device__ __forceinline__ void init_pair9(float2* __restrict__ st,
                                           const float2* __restrict__ Ush,
                                           int tid) {
  const int t9 = (tid >> 9) & 1, t8 = (tid >> 8) & 1;   // wave-uniform
  const int t76 = (tid >> 6) & 3;                        // wave-uniform
  const int t54 = (tid >> 4) & 3, t32 = (tid >> 2) & 3, t10 = tid & 3;
  float f0r[2], f0i[2];
  #pragma unroll
  for (int k3 = 0; k3 < 2; ++k3) {
    f0r[k3] = rfl(Ush[0 * 16 + ((t9 << 1) | k3) * 4].x);
    f0i[k3] = rfl(Ush[0 * 16 + ((t9 << 1) | k3) * 4].y);
  }
  float f1r[4], f1i[4];
  #pragma unroll
  for (int j = 0; j < 4; ++j) {
    f1r[j] = rfl(Ush[1 * 16 + j * 4].x);
    f1i[j] = rfl(Ush[1 * 16 + j * 4].y);
  }
  float f2r[2], f2i[2];
  #pragma unroll
  for (int k0 = 0; k0 < 2; ++k0) {
    f2r[k0] = rfl(Ush[2 * 16 + ((k0 << 1) | t8) * 4].x);
    f2i[k0] = rfl(Ush[2 * 16 + ((k0 << 1) | t8) * 4].y);
  }
  const float f3r = rfl(Ush[3 * 16 + t76 * 4].x), f3i = rfl(Ush[3 * 16 + t76 * 4].y);
  const float2 f4 = Ush[4 * 16 + t54 * 4];
  const float2 f5 = Ush[5 * 16 + t32 * 4];
  const float2 f6 = Ush[6 * 16 + t10 * 4];
  float cr = f3r * f4.x - f3i * f4.y, ci = f3r * f4.y + f3i * f4.x, tr, ti;
  tr = cr * f5.x - ci * f5.y; ti = cr * f5.y + ci * f5.x; cr = tr; ci = ti;
  tr = cr * f6.x - ci * f6.y; ti = cr * f6.y + ci * f6.x; cr = tr; ci = ti;
  float g2r[2], g2i[2];
  #pragma unroll
  for (int k0 = 0; k0 < 2; ++k0) {
    g2r[k0] = f2r[k0] * cr - f2i[k0] * ci;
    g2i[k0] = f2r[k0] * ci + f2i[k0] * cr;
  }
  float vr[16], vi[16];
  #pragma unroll
  for (int k = 0; k < 16; ++k) {
    const int k3 = k >> 3, k21 = (k >> 1) & 3, k0 = k & 1;
    const float hr2 = f0r[k3] * f1r[k21] - f0i[k3] * f1i[k21];
    const float hi2 = f0r[k3] * f1i[k21] + f0i[k3] * f1r[k21];
    vr[k] = hr2 * g2r[k0] - hi2 * g2i[k0];
    vi[k] = hr2 * g2i[k0] + hi2 * g2r[k0];
  }
  gate_pair16(Ush + 7 * 16, Ush + 8 * 16, vr, vi);   // q1 (bits 12,11), q3 (10,9)
  constexpr int m = (1 << 9) - 1;
  const int a0 = ef_c(((tid & ~m) << 4) | (tid & m));
  #pragma unroll
  for (int k = 0; k < 16; ++k)
    st[a0 ^ ef_c(k << 9)] = make_float2(vr[k], vi[k]);
  __syncthreads();
}

// ---- WAVE-LOCAL SU4 pair pass (SH+4 <= 10): NO barrier ----
template<int SH>
__device__ __forceinline__ void su4_pairW(float2* __restrict__ st,
                                          const float2* __restrict__ ugA,
                                          const float2* __restrict__ ugB,
                                          int tid) {
  const int w = tid >> 6, l = tid & 63;
  constexpr int m = (1 << SH) - 1;
  const int a0 = ef_c((w << 10) | ((l & ~m) << 4) | (l & m));
  float vr[16], vi[16];
  #pragma unroll
  for (int k = 0; k < 16; ++k) {
    const float2 v = st[a0 ^ ef_c(k << SH)];
    vr[k] = v.x; vi[k] = v.y;
  }
  gate_pair16(ugA, ugB, vr, vi);
  #pragma unroll
  for (int k = 0; k < 16; ++k)
    st[a0 ^ ef_c(k << SH)] = make_float2(vr[k], vi[k]);
}

template<int J>
__device__ __forceinline__ void bfly16(float c, float s, float pr[16], float pi_[16]) {
  #pragma unroll
  for (int i = 0; i < 16; ++i) {
    if ((i & (1 << J)) == 0) {
      const int j = i | (1 << J);
      const float ar = pr[i], ai = pi_[i], br = pr[j], bi = pi_[j];
      pr[i]  = fmaf(c, ar, -(s * br));
      pi_[i] = fmaf(c, ai, -(s * bi));
      pr[j]  = fmaf(s, ar, c * br);
      pi_[j] = fmaf(s, ai, c * bi);
    }
  }
}

// ---- WAVE-LOCAL 4-qubit RY pass at SH=6 (qubits 4..7): NO barrier ----
__device__ __forceinline__ void ry4W6(float2* __restrict__ st,
                                      const float* __restrict__ rc,
                                      const float* __restrict__ rs, int tid) {
  const float c3 = rfl(rc[4]), s3 = rfl(rs[4]);
  const float c2 = rfl(rc[5]), s2 = rfl(rs[5]);
  const float c1 = rfl(rc[6]), s1 = rfl(rs[6]);
  const float c0 = rfl(rc[7]), s0 = rfl(rs[7]);
  const int w = tid >> 6, l = tid & 63;
  const int a0 = ef_c((w << 10) | l);   // SH=6: (l&~63)<<4 == 0
  float vr[16], vi[16];
  #pragma unroll
  for (int k = 0; k < 16; ++k) {
    const float2 v = st[a0 ^ ef_c(k << 6)];
    vr[k] = v.x; vi[k] = v.y;
  }
  bfly16<3>(c3, s3, vr, vi);
  bfly16<2>(c2, s2, vr, vi);
  bfly16<1>(c1, s1, vr, vi);
  bfly16<0>(c0, s0, vr, vi);
  #pragma unroll
  for (int k = 0; k < 16; ++k)
    st[a0 ^ ef_c(k << 6)] = make_float2(vr[k], vi[k]);
}

// ---- WAVE-LOCAL RY pass at SH=2 (qubits 8..11) + DPP butterflies for
// qubits 12,13 (y-bits 1,0 = lane bits 1,0, quad-aligned). R13-proven.
__device__ __forceinline__ void ry4W2d(float2* __restrict__ st,
                                       const float* __restrict__ rc,
                                       const float* __restrict__ rs, int tid) {
  const float c3 = rfl(rc[8]),  s3 = rfl(rs[8]);
  const float c2 = rfl(rc[9]),  s2 = rfl(rs[9]);
  const float c1 = rfl(rc[10]), s1 = rfl(rs[10]);
  const float c0 = rfl(rc[11]), s0 = rfl(rs[11]);
  const float cA = rfl(rc[12]), sA = rfl(rs[12]);   // qubit 12 -> y bit 1
  const float cB = rfl(rc[13]), sB = rfl(rs[13]);   // qubit 13 -> y bit 0
  const int w = tid >> 6, l = tid & 63;
  const int a0 = ef_c((w << 10) | ((l & ~3) << 4) | (l & 3));
  float vr[16], vi[16];
  #pragma unroll
  for (int k = 0; k < 16; ++k) {
    const float2 v = st[a0 ^ ef_c(k << 2)];
    vr[k] = v.x; vi[k] = v.y;
  }
  bfly16<3>(c3, s3, vr, vi);
  bfly16<2>(c2, s2, vr, vi);
  bfly16<1>(c1, s1, vr, vi);
  bfly16<0>(c0, s0, vr, vi);
  {
    const float se = (l & 1) ? sB : -sB;
    #pragma unroll
    for (int k = 0; k < 16; ++k) {
      const float pr = fdpp<0xB1>(vr[k]), pi_ = fdpp<0xB1>(vi[k]);
      vr[k] = fmaf(cB, vr[k], se * pr);
      vi[k] = fmaf(cB, vi[k], se * pi_);
    }
  }
  {
    const float se = (l & 2) ? sA : -sA;
    #pragma unroll
    for (int k = 0; k < 16; ++k) {
      const float pr = fdpp<0x4E>(vr[k]), pi_ = fdpp<0x4E>(vi[k]);
      vr[k] = fmaf(cA, vr[k], se * pr);
      vi[k] = fmaf(cA, vi[k], se * pi_);
    }
  }
  #pragma unroll
  for (int k = 0; k < 16; ++k)
    st[a0 ^ ef_c(k << 2)] = make_float2(vr[k], vi[k]);
}

// ---- block reduce: 4 DPP (VALU) + 2 shfl_xor stages; xor masks {1,2,7,15,16,32}
// span all 64 lanes (group-generated). Saves 4 LDS-pipe ops per reduce.
__device__ __forceinline__ void reduce_store(float a, float* slot, int lane, int wid) {
  a += fdpp<0xB1>(a);    // xor 1
  a += fdpp<0x4E>(a);    // xor 2
  a += fdpp<0x141>(a);   // half-mirror = xor 7
  a += fdpp<0x140>(a);   // mirror = xor 15
  a += __shfl_xor(a, 16, 64);
  a += __shfl_xor(a, 32, 64);
  if (lane == 0) slot[wid] = a;
}

// ---- fused RY(q0..3) + CNOT-chain pass.
// FINAL: obs0, obs1 ONLY (both have y10 fixed inside pairs -> register-local;
// obs2 flips y10 -> must go through LDS: R14's bug). YM index map, no copy.
template<bool FINAL>
__device__ __forceinline__ void perm_ry_pass(float2* __restrict__ st,
                                             const float* __restrict__ rc,
                                             const float* __restrict__ rs,
                                             int tid,
                                             const float2* __restrict__ Hsh,
                                             float (*red)[TCIRC / 64],
                                             int lane, int wid) {
  const float c0 = rfl(rc[0]), s0 = rfl(rs[0]);
  const float c1 = rfl(rc[1]), s1 = rfl(rs[1]);
  const float c2 = rfl(rc[2]), s2 = rfl(rs[2]);
  const float c3 = rfl(rc[3]), s3 = rfl(rs[3]);
  __syncthreads();   // wave-local writers from prior passes must land
  const int Er = ef_c(tid);
  float pr[16], pi_[16];
  #pragma unroll
  for (int i = 0; i < 16; ++i) {
    const float2 v = st[Er ^ ef_c(i << 10)];
    pr[i] = v.x; pi_[i] = v.y;
  }
  __syncthreads();
  bfly16<3>(c0, s0, pr, pi_);
  bfly16<2>(c1, s1, pr, pi_);
  bfly16<1>(c2, s2, pr, pi_);
  bfly16<0>(c3, s3, pr, pi_);
  const int Ew = ef_c(siginv_c(tid));
  #pragma unroll
  for (int i = 0; i < 16; ++i)
    st[Ew ^ ef_c(siginv_c(i << 10))] = make_float2(pr[i], pi_[i]);
  if (FINAL) {
    reduce_store(qform16<0, true>(Hsh + 0 * 16, pr, pi_), red[0], lane, wid); // y13,y12
    reduce_store(qform16<1, true>(Hsh + 1 * 16, pr, pi_), red[1], lane, wid); // y12,y11
  }
  __syncthreads();
}

// ---- obs window pass: 4-bit window bits SH+3..SH (R12-proven tiling) ----
// NOB==3: MODE0/1/2 at obase..obase+2. NOB==2: MODE1, MODE2 (SH=0: obs11,12).
template<int SH, int NOB>
__device__ __forceinline__ void obs_tri(const float2* __restrict__ st,
                                        const float2* __restrict__ Hsh, int obase,
                                        float (*red)[TCIRC / 64],
                                        int lane, int wid, int tid) {
  constexpr int m = (1 << SH) - 1;
  const int a0 = ef_c(((tid & ~m) << 4) | (tid & m));
  float vr[16], vi[16];
  #pragma unroll
  for (int k = 0; k < 16; ++k) {
    const float2 v = st[a0 ^ ef_c(k << SH)];
    vr[k] = v.x; vi[k] = v.y;
  }
  if (NOB == 3) {
    reduce_store(qform16<0, false>(Hsh + (obase + 0) * 16, vr, vi), red[obase + 0], lane, wid);
    reduce_store(qform16<1, false>(Hsh + (obase + 1) * 16, vr, vi), red[obase + 1], lane, wid);
    reduce_store(qform16<2, false>(Hsh + (obase + 2) * 16, vr, vi), red[obase + 2], lane, wid);
  } else {
    reduce_store(qform16<1, false>(Hsh + (obase + 0) * 16, vr, vi), red[obase + 0], lane, wid);
    reduce_store(qform16<2, false>(Hsh + (obase + 1) * 16, vr, vi), red[obase + 1], lane, wid);
  }
}

// ====== single fused kernel: encoder + U-build (shfl-parallel) + circuit ====
__launch_bounds__(TCIRC, 1)
__global__ void circuit_kernel(const float* __restrict__ x,
                               const float* __restrict__ W1,
                               const float* __restrict__ b1,
                               const float* __restrict__ W2,
                               const float* __restrict__ b2,
                               const float* __restrict__ vp,
                               const float* __restrict__ oA,
                               const float* __restrict__ oB,
                               const float* __restrict__ oD,
                               float* __restrict__ out) {
  __shared__ float2 st[DIM];                 // 128 KiB (head: scratch overlay)
  __shared__ float2 Ush[NGATES * 16];
  __shared__ float2 Hsh[NOBSN * 16];
  __shared__ float  ryc[DEPTHN * NQ];
  __shared__ float  rys[DEPTHN * NQ];
  __shared__ float  red[NOBSN][TCIRC / 64];

  const int b = blockIdx.x;
  const int tid = threadIdx.x;

  // ---- head scratch overlaid on the not-yet-initialized state ----
  float* base = (float*)st;
  float* xrow = base;          // 256
  float* hrow = base + 256;    // 256
  float* encs = base + 512;    // 195
  float* part = base + 1024;   // 1024

  // trig + observable H on disjoint high threads (independent of encoder)
  if (tid >= 960 && tid < 960 + DEPTHN * NQ) {
    const int i = tid - 960;
    const float h = 0.5f * vp[i];
    ryc[i] = cosf(h); rys[i] = sinf(h);
  }
  if (tid >= 832 && tid < 832 + NOBSN) {
    const int o = tid - 832;
    const int rr[6] = {1, 2, 2, 3, 3, 3};
    const int cc[6] = {0, 0, 1, 0, 1, 2};
    float2 H[16];
    #pragma unroll
    for (int i = 0; i < 16; ++i) H[i] = make_float2(0.f, 0.f);
    for (int m = 0; m < 6; ++m) {
      const float a = oA[o * 6 + m], bb = oB[o * 6 + m];
      H[rr[m] * 4 + cc[m]] = make_float2(a, bb);
      H[cc[m] * 4 + rr[m]] = make_float2(a, -bb);
    }
    H[0]  = make_float2(2.f * oD[o * 4 + 1], 0.f);
    H[5]  = make_float2(2.f * oD[o * 4 + 2], 0.f);
    H[10] = make_float2(2.f * oD[o * 4 + 3], 0.f);
    for (int i = 0; i < 16; ++i) Hsh[o * 16 + i] = H[i];
  }
  if (tid < INDIM) xrow[tid] = x[b * INDIM + tid];
  __syncthreads();

  {  // hrow partials: 4 threads per output, float4 loads
    const int o = tid & 255, q = tid >> 8;
    const float4* wp = (const float4*)(W1 + o * INDIM + q * 64);
    const float4* xq = (const float4*)(xrow + q * 64);
    float a = 0.f;
    #pragma unroll 4
    for (int k = 0; k < 16; ++k) {
      const float4 wv = wp[k], xv = xq[k];
      a = fmaf(wv.x, xv.x, fmaf(wv.y, xv.y, fmaf(wv.z, xv.z, fmaf(wv.w, xv.w, a))));
    }
    part[(q << 8) | o] = a;
  }
  __syncthreads();
  if (tid < HIDDIM) {
    const float a = b1[tid] + part[tid] + part[256 + tid] + part[512 + tid] + part[768 + tid];
    hrow[tid] = a / (1.f + expf(-a));
  }
  __syncthreads();
  {  // enc partials
    const int o = tid & 255, q = tid >> 8;
    if (o < ENCDIM) {
      const float4* wp = (const float4*)(W2 + o * HIDDIM + q * 64);
      const float4* hq = (const float4*)(hrow + q * 64);
      float a = 0.f;
      #pragma unroll 4
      for (int k = 0; k < 16; ++k) {
        const float4 wv = wp[k], hv = hq[k];
        a = fmaf(wv.x, hv.x, fmaf(wv.y, hv.y, fmaf(wv.z, hv.z, fmaf(wv.w, hv.w, a))));
      }
      part[(q << 8) | o] = a;
    }
  }
  __syncthreads();
  if (tid < ENCDIM)
    encs[tid] = b2[tid] + part[tid] + part[256 + tid] + part[512 + tid] + part[768 + tid];
  __syncthreads();

  // ---- U-build: 16 lanes per gate, matmuls via shfl (no barriers inside) ----
  if (tid < NGATES * 16) {
    const int g = tid >> 4, e = tid & 15, i = e >> 2, j = e & 3;
    const float* th = encs + g * NGEN;
    float Are = 0.f, Aie = 0.f;
    for (int t = 0; t < NGEN; ++t) {
      const int p = t + 1;
      const int pa = p >> 2, pb = p & 3;
      const float ar = c_PR[pa][i >> 1][j >> 1], ai = c_PI[pa][i >> 1][j >> 1];
      const float br = c_PR[pb][i & 1][j & 1],  bi = c_PI[pb][i & 1][j & 1];
      Are = fmaf(th[t], ar * br - ai * bi, Are);
      Aie = fmaf(th[t], ar * bi + ai * br, Aie);
    }
    float r = sqrtf(Are * Are + Aie * Aie);
    r += __shfl_xor(r, 1, 16);
    r += __shfl_xor(r, 2, 16);
    float nrm = r;
    nrm = fmaxf(nrm, __shfl_xor(nrm, 4, 16));
    nrm = fmaxf(nrm, __shfl_xor(nrm, 8, 16));
    int sct = 0;
    float scale = 1.f;
    while (nrm * scale > 0.5f && sct < 30) { scale *= 0.5f; ++sct; }
    const float Mre = -Aie * scale, Mie = Are * scale;   // M = i*A*scale
    float Rr = (i == j) ? 1.f : 0.f, Ri = 0.f;
    for (int k = 10; k >= 1; --k) {
      const float inv = 1.f / (float)k;
      float tr = 0.f, ti = 0.f;
      #pragma unroll
      for (int l = 0; l < 4; ++l) {
        const float mr = __shfl(Mre, i * 4 + l, 16), mi = __shfl(Mie, i * 4 + l, 16);
        const float rr2 = __shfl(Rr, l * 4 + j, 16), ri2 = __shfl(Ri, l * 4 + j, 16);
        tr = fmaf(mr, rr2, fmaf(-mi, ri2, tr));
        ti = fmaf(mr, ri2, fmaf(mi, rr2, ti));
      }
      Rr = ((i == j) ? 1.f : 0.f) + inv * tr;
      Ri = inv * ti;
    }
    for (int it = 0; it < sct; ++it) {
      float tr = 0.f, ti = 0.f;
      #pragma unroll
      for (int l = 0; l < 4; ++l) {
        const float ar = __shfl(Rr, i * 4 + l, 16), ai2 = __shfl(Ri, i * 4 + l, 16);
        const float br = __shfl(Rr, l * 4 + j, 16), bi2 = __shfl(Ri, l * 4 + j, 16);
        tr = fmaf(ar, br, fmaf(-ai2, bi2, tr));
        ti = fmaf(ar, bi2, fmaf(ai2, br, ti));
      }
      Rr = tr; Ri = ti;
    }
    Ush[g * 16 + e] = make_float2(Rr, Ri);
  }
  __syncthreads();

  // ---- fused: even-layer product state + odd gates q1,q3 (one pass, 0 reads)
  init_pair9(st, Ush, tid);

  // ---- remaining odd layer: 2 wave-local passes ----
  su4_pairW<5>(st, Ush + 9 * 16, Ush + 10 * 16, tid);  // q5,q7 (bits 8..5)
  su4_pairW<1>(st, Ush + 11 * 16, Ush + 12 * 16, tid); // q9,q11 (bits 4..1)

  // ---- variational depths: 2 wave-local RY passes + fused perm+RY(0..3) ----
  const int lane = tid & 63, wid = tid >> 6;
  #pragma unroll 1
  for (int d = 0; d < DEPTHN - 1; ++d) {
    const float* rc = ryc + d * NQ;
    const float* rs = rys + d * NQ;
    ry4W6(st, rc, rs, tid);                                // qubits 4..7
    ry4W2d(st, rc, rs, tid);                               // qubits 8..13 (DPP)
    perm_ry_pass<false>(st, rc, rs, tid, Hsh, red, lane, wid);
  }
  {  // final depth: perm pass also computes obs0, obs1 in-register
    const float* rc = ryc + (DEPTHN - 1) * NQ;
    const float* rs = rys + (DEPTHN - 1) * NQ;
    ry4W6(st, rc, rs, tid);
    ry4W2d(st, rc, rs, tid);
    perm_ry_pass<true>(st, rc, rs, tid, Hsh, red, lane, wid);
  }

  // ---- remaining observables: 4 read-only window passes (R12-proven tiling)
  obs_tri<8, 3>(st, Hsh, 2, red, lane, wid, tid);   // obs2 (11,10), obs3, obs4
  obs_tri<5, 3>(st, Hsh, 5, red, lane, wid, tid);   // obs5 (8,7),  obs6, obs7
  obs_tri<2, 3>(st, Hsh, 8, red, lane, wid, tid);   // obs8 (5,4),  obs9, obs10
  obs_tri<0, 2>(st, Hsh, 11, red, lane, wid, tid);  // obs11 (2,1), obs12 (1,0)

  __syncthreads();
  if (tid < NOBSN) {
    float s = 0.f;
    #pragma unroll
    for (int w = 0; w < TCIRC / 64; ++w) s += red[tid][w];
    out[b * NOBSN + tid] = s;
  }
}

extern "C" void kernel_launch(void* const* d_in, const int* in_sizes, int n_in,
                              void* d_out, int out_size, void* d_ws, size_t ws_size,
                              hipStream_t stream) {
  const float* x  = (const float*)d_in[0];
  const float* W1 = (const float*)d_in[1];
  const float* b1 = (const float*)d_in[2];
  const float* W2 = (const float*)d_in[3];
  const float* b2 = (const float*)d_in[4];
  const float* vp = (const float*)d_in[5];
  const float* oA = (const float*)d_in[6];
  const float* oB = (const float*)d_in[7];
  const float* oD = (const float*)d_in[8];
  float* out = (float*)d_out;

  circuit_kernel<<<BATCHN, TCIRC, 0, stream>>>(x, W1, b1, W2, b2, vp, oA, oB, oD, out);
}